// Round 6
// baseline (321.251 us; speedup 1.0000x reference)
//
#include <hip/hip_runtime.h>
#include <math.h>

// GPT-2 block forward. bf16 MFMA GEMMs + bf16 MFMA flash attention (32x32, in-reg softmax,
// double-buffered K/V pipeline). B=2, T=2048, C=1024, H=16, Dh=64. M = B*T = 4096.
constexpr int TDIM = 2048;
constexpr int BDIM = 2;
constexpr int CDIM = 1024;
constexpr int HEADS = 16;
constexpr int DH = 64;
constexpr int MDIM = BDIM * TDIM; // 4096

typedef short bf16x8 __attribute__((ext_vector_type(8)));
typedef float f32x4 __attribute__((ext_vector_type(4)));
typedef float f32x16 __attribute__((ext_vector_type(16)));

__device__ __forceinline__ float b2f(unsigned short u) {
    union { float f; unsigned int i; } v; v.i = ((unsigned int)u) << 16; return v.f;
}
__device__ __forceinline__ unsigned short f2b(float f) {
    union { float f; unsigned int i; } v; v.f = f;
    unsigned int r = (v.i + 0x7FFFu + ((v.i >> 16) & 1u)) >> 16;
    return (unsigned short)r;
}
// HW packed f32x2 -> bf16x2 (RNE), single instruction; no builtin on gfx950.
__device__ __forceinline__ unsigned int cvtpk(float lo, float hi) {
    unsigned int r;
    asm("v_cvt_pk_bf16_f32 %0, %1, %2" : "=v"(r) : "v"(lo), "v"(hi));
    return r;
}
__device__ __forceinline__ float gelu_f(float x) {
    const float c0 = 0.7978845608028654f; // sqrt(2/pi)
    float x3 = x * x * x;
    float t = tanhf(c0 * (x + 0.044715f * x3));
    return 0.5f * x * (1.0f + t);
}
__device__ __forceinline__ void async_copy16(const void* g, void* l) {
    __builtin_amdgcn_global_load_lds(
        (const __attribute__((address_space(1))) unsigned int*)g,
        (__attribute__((address_space(3))) unsigned int*)l, 16, 0, 0);
}

// ---------------- weight transpose + cast: W[K][N] f32 -> Wt[N][K] bf16 ----------------
__global__ __launch_bounds__(256) void transpose_cast(
    const float* __restrict__ W, unsigned short* __restrict__ Wt, int K, int N) {
    __shared__ float tile[32][33];
    int n0 = blockIdx.x * 32, k0 = blockIdx.y * 32;
    int tx = threadIdx.x & 31, ty = threadIdx.x >> 5; // 32 x 8
#pragma unroll
    for (int i = 0; i < 32; i += 8)
        tile[ty + i][tx] = W[(size_t)(k0 + ty + i) * N + n0 + tx];
    __syncthreads();
#pragma unroll
    for (int i = 0; i < 32; i += 8)
        Wt[(size_t)(n0 + ty + i) * K + k0 + tx] = f2b(tile[tx][ty + i]);
}

// ---------------- LayerNorm: f32 in -> bf16 out, one block per row of 1024 ----------------
__global__ __launch_bounds__(256) void ln_kernel(
    const float* __restrict__ x, const float* __restrict__ w,
    const float* __restrict__ b, unsigned short* __restrict__ out) {
    int row = blockIdx.x;
    int tid = threadIdx.x;
    const float* xr = x + (size_t)row * CDIM;
    float4 v = *(const float4*)(xr + tid * 4);
    float s  = v.x + v.y + v.z + v.w;
    float ss = v.x * v.x + v.y * v.y + v.z * v.z + v.w * v.w;
#pragma unroll
    for (int off = 32; off >= 1; off >>= 1) {
        s  += __shfl_xor(s, off);
        ss += __shfl_xor(ss, off);
    }
    __shared__ float rs[4], rss[4];
    int wave = tid >> 6;
    if ((tid & 63) == 0) { rs[wave] = s; rss[wave] = ss; }
    __syncthreads();
    s  = rs[0] + rs[1] + rs[2] + rs[3];
    ss = rss[0] + rss[1] + rss[2] + rss[3];
    float mean = s * (1.0f / CDIM);
    float var  = ss * (1.0f / CDIM) - mean * mean;
    float rstd = rsqrtf(var + 1e-5f);
    float4 wv = *(const float4*)(w + tid * 4);
    float4 bv = *(const float4*)(b + tid * 4);
    ushort4 o;
    o.x = f2b((v.x - mean) * rstd * wv.x + bv.x);
    o.y = f2b((v.y - mean) * rstd * wv.y + bv.y);
    o.z = f2b((v.z - mean) * rstd * wv.z + bv.z);
    o.w = f2b((v.w - mean) * rstd * wv.w + bv.w);
    *(ushort4*)(out + (size_t)row * CDIM + tid * 4) = o;
}

// ---------------- bf16 MFMA GEMM: C = A[M,K] @ Wt[N,K]^T (+bias, +res, +gelu) ----------
// 128x128 tile, BK=64, 256 threads (4 waves, 2x2), 64x64 per wave, 4x4 frags of 16x16.
template <int MODE>
__global__ __launch_bounds__(256) void gemm_bf16(
    const unsigned short* __restrict__ A, const unsigned short* __restrict__ Wt,
    const float* __restrict__ bias, const float* __restrict__ res,
    void* __restrict__ Cout, int M, int N, int K) {
    __shared__ __align__(16) short As[128 * 64];
    __shared__ __align__(16) short Bs[128 * 64];
    const int tid = threadIdx.x;
    const int lane = tid & 63, w = tid >> 6;
    const int wr = w >> 1, wc = w & 1;
    const int row0 = blockIdx.y * 128, col0 = blockIdx.x * 128;

    const int sr = lane >> 3;                   // 0..7: row within 8-row group
    const int sc = 8 * ((lane & 7) ^ sr);       // element col, pre-swizzled source
    const unsigned short* gA = A  + (size_t)(row0 + w * 8 + sr) * K + sc;
    const unsigned short* gB = Wt + (size_t)(col0 + w * 8 + sr) * K + sc;
    short* ldsA = As + (w * 8) * 64;            // wave-uniform dst base
    short* ldsB = Bs + (w * 8) * 64;

    f32x4 acc[4][4] = {};
    const int h = lane >> 4;                    // 0..3
    const int r15 = lane & 15;

    for (int k0 = 0; k0 < K; k0 += 64) {
        __syncthreads();
#pragma unroll
        for (int i = 0; i < 4; ++i) {
            async_copy16(gA + (size_t)i * 32 * K + k0, ldsA + i * 32 * 64);
            async_copy16(gB + (size_t)i * 32 * K + k0, ldsB + i * 32 * 64);
        }
        __syncthreads();
#pragma unroll
        for (int ks = 0; ks < 2; ++ks) {
            bf16x8 af[4], bfr[4];
#pragma unroll
            for (int i = 0; i < 4; ++i) {
                int ra = wr * 64 + i * 16 + r15;
                int offa = ra * 128 + ((ks * 64 + h * 16) ^ ((ra & 7) << 4));
                af[i] = *(const bf16x8*)((const char*)As + offa);
                int rb = wc * 64 + i * 16 + r15;
                int offb = rb * 128 + ((ks * 64 + h * 16) ^ ((rb & 7) << 4));
                bfr[i] = *(const bf16x8*)((const char*)Bs + offb);
            }
#pragma unroll
            for (int i = 0; i < 4; ++i)
#pragma unroll
                for (int j = 0; j < 4; ++j)
                    acc[i][j] = __builtin_amdgcn_mfma_f32_16x16x32_bf16(
                        af[i], bfr[j], acc[i][j], 0, 0, 0);
        }
    }

#pragma unroll
    for (int i = 0; i < 4; ++i) {
#pragma unroll
        for (int j = 0; j < 4; ++j) {
            int c = col0 + wc * 64 + j * 16 + r15;
            float bv = bias[c];
#pragma unroll
            for (int q = 0; q < 4; ++q) {
                int rr = row0 + wr * 64 + i * 16 + h * 4 + q;
                float v = acc[i][j][q] + bv;
                if (MODE == 2) v = gelu_f(v);
                if (MODE == 1) v += res[(size_t)rr * N + c];
                if (MODE == 1) ((float*)Cout)[(size_t)rr * N + c] = v;
                else ((unsigned short*)Cout)[(size_t)rr * N + c] = f2b(v);
            }
        }
    }
}

// ---------------- MFMA flash attention, 32x32 swapped-QK^T, in-register softmax --------
// grid = (B*H, T/128), block = 256 (4 waves). qy = 15 - blockIdx.y (LPT: longest first).
// Wave w owns q rows [q0 + 32w, q0 + 32w + 32). Per lane: q = q0 + 32w + (lane&31) FIXED.
// DOUBLE-BUFFERED pipeline: per tile t, issue K global_load_lds(t+1) + V global->reg
// loads(t+1) BEFORE compute(t); Vt ds_writes after compute; ONE __syncthreads per tile
// (its implicit vmcnt/lgkm drain orders everything). Stage targets buf c^1 while all
// waves read buf c -> race-free; end barrier protects overwrite of buf c next iter.
__global__ __launch_bounds__(256) void attn_mfma(
    const unsigned short* __restrict__ qkv, unsigned short* __restrict__ y) {
    const int bh = blockIdx.x;
    const int b = bh >> 4, hh = bh & 15;
    const int qy = (int)gridDim.y - 1 - blockIdx.y;
    const int q0 = qy * 128;
    const int tid = threadIdx.x;
    const int lane = tid & 63, w = tid >> 6;
    const int hi = lane >> 5, q31 = lane & 31;

    const float SC  = 0.1803368801111244f;  // 0.125 * log2(e)
    const float THR = 44.0f;                // ~8 in log2 domain after scaling

    // LDS (34816 B): Ks(c) at c*8192, Vt(c) at 16384 + c*8192 (32 KB for 2x2 buffers);
    // Os[128][68] f32 aliases everything for the epilogue (after final barrier).
    __shared__ __align__(16) char smem[128 * 68 * 4];
    float (*Os)[68] = (float (*)[68])smem;

    const size_t base = (size_t)b * TDIM * (3 * CDIM);
    const unsigned short* qb = qkv + base + hh * DH;
    const unsigned short* kb = qkv + base + CDIM + hh * DH;
    const unsigned short* vb = qkv + base + 2 * CDIM + hh * DH;

    const int gq = q0 + w * 32 + q31;       // this lane's q row (global, within T)
    const int qmin_w = q0 + w * 32;
    const int qmax_w = qmin_w + 31;

    // Q B-frags: qf[ks] elem j = Q[gq][16*ks + 8*hi + j]
    bf16x8 qf[4];
#pragma unroll
    for (int ks = 0; ks < 4; ++ks)
        qf[ks] = *(const bf16x8*)(qb + (size_t)gq * (3 * CDIM) + ks * 16 + hi * 8);

    // staging geometry
    const int sr = lane >> 3;
    const int scK = 8 * ((lane & 7) ^ sr);  // pre-swizzled source col (elems)
    const int rV = tid >> 3;                // 0..31 kv row (+32)
    const int dblk = (tid & 7) * 8;

    f32x16 oacc[2] = {};                    // O^T: oacc[j2][r] = O[q][d=32*j2+(r&3)+8*(r>>2)+4*hi]
    float m = -1e30f, l = 0.f;

    bf16x8 vregA, vregB;                    // in-flight V tile (rows rV, rV+32)

    const int NT = 2 * qy + 2;

    // ---- prologue: stage tile 0 into buffer 0 ----
    {
        short* Ks0 = (short*)smem;
#pragma unroll
        for (int i = 0; i < 2; ++i) {
            int rowbase = w * 16 + i * 8;
            async_copy16(kb + (size_t)(rowbase + sr) * (3 * CDIM) + scK, Ks0 + rowbase * 64);
        }
        vregA = *(const bf16x8*)(vb + (size_t)(rV) * (3 * CDIM) + dblk);
        vregB = *(const bf16x8*)(vb + (size_t)(rV + 32) * (3 * CDIM) + dblk);
        char* Vt0 = smem + 16384;
#pragma unroll
        for (int j = 0; j < 8; ++j) {
            int d = dblk + j;
            int swz = ((d ^ (d >> 3)) & 7) << 4;
            *(short*)(Vt0 + d * 128 + ((2 * rV) ^ swz)) = vregA[j];
            *(short*)(Vt0 + d * 128 + ((2 * (rV + 32)) ^ swz)) = vregB[j];
        }
    }
    __syncthreads();  // drains vmcnt (K tile 0 in LDS) + lgkm (Vt writes visible)

    for (int kt = 0; kt < NT; ++kt) {
        const int c = kt & 1;
        short* Ksc = (short*)(smem + c * 8192);
        const char* Vtc = smem + 16384 + c * 8192;
        const bool pre = (kt + 1 < NT);

        // --- issue next tile's loads (K -> LDS buf c^1, V -> regs) ---
        if (pre) {
            const int kv1 = (kt + 1) * 64;
            short* Ksn = (short*)(smem + (c ^ 1) * 8192);
#pragma unroll
            for (int i = 0; i < 2; ++i) {
                int rowbase = w * 16 + i * 8;
                async_copy16(kb + (size_t)(kv1 + rowbase + sr) * (3 * CDIM) + scK,
                             Ksn + rowbase * 64);
            }
            vregA = *(const bf16x8*)(vb + (size_t)(kv1 + rV) * (3 * CDIM) + dblk);
            vregB = *(const bf16x8*)(vb + (size_t)(kv1 + rV + 32) * (3 * CDIM) + dblk);
        }

        // --- compute tile kt from buffer c ---
        const int kv0 = kt * 64;
#pragma unroll
        for (int sub = 0; sub < 2; ++sub) {
            const int kvs = kv0 + sub * 32;
            if (kvs > qmax_w) break;        // wave-uniform

            // S^T subtile: rows kv (reg-mapped), col q (lane)
            f32x16 sacc = {};
            __builtin_amdgcn_s_setprio(1);
#pragma unroll
            for (int ks = 0; ks < 4; ++ks) {
                int row = sub * 32 + q31;
                int off = row * 128 + ((32 * ks + 16 * hi) ^ ((row & 7) << 4));
                bf16x8 kf = *(const bf16x8*)((const char*)Ksc + off);
                sacc = __builtin_amdgcn_mfma_f32_32x32x16_bf16(kf, qf[ks], sacc, 0, 0, 0);
            }
            __builtin_amdgcn_s_setprio(0);

            // causal mask in raw domain (p[r]: kv = kvs + (r&3)+8*(r>>2)+4*hi)
            float p[16];
            if (kvs + 31 > qmin_w) {
#pragma unroll
                for (int r = 0; r < 16; ++r) {
                    int kvg = kvs + (r & 3) + 8 * (r >> 2) + 4 * hi;
                    p[r] = (kvg > gq) ? -1e30f : sacc[r];
                }
            } else {
#pragma unroll
                for (int r = 0; r < 16; ++r) p[r] = sacc[r];
            }

            // row max (raw domain)
            float t8[8];
#pragma unroll
            for (int r = 0; r < 8; ++r) t8[r] = fmaxf(p[r], p[r + 8]);
#pragma unroll
            for (int r = 0; r < 4; ++r) t8[r] = fmaxf(t8[r], t8[r + 4]);
            float pm = fmaxf(fmaxf(t8[0], t8[1]), fmaxf(t8[2], t8[3]));
            pm = fmaxf(pm, __shfl_xor(pm, 32));

            // defer-max: only rescale when the max moved materially
            if (!__all(pm <= m + THR)) {
                float mnew = fmaxf(m, pm);
                float sf = exp2f((m - mnew) * SC);
                m = mnew;
                l *= sf;
                oacc[0] *= sf;
                oacc[1] *= sf;
            }
            float mc = m * SC;
#pragma unroll
            for (int r = 0; r < 16; ++r) p[r] = exp2f(fmaf(p[r], SC, -mc));
#pragma unroll
            for (int r = 0; r < 8; ++r) t8[r] = p[r] + p[r + 8];
#pragma unroll
            for (int r = 0; r < 4; ++r) t8[r] = t8[r] + t8[r + 4];
            float rsum = (t8[0] + t8[1]) + (t8[2] + t8[3]);
            rsum += __shfl_xor(rsum, 32);
            l += rsum;

            // pack P -> PV B-frags (HW cvt_pk + half-swap)
            bf16x8 pa[2];
#pragma unroll
            for (int k2 = 0; k2 < 2; ++k2) {
                unsigned int A0 = cvtpk(p[8 * k2 + 0], p[8 * k2 + 1]);
                unsigned int A1 = cvtpk(p[8 * k2 + 2], p[8 * k2 + 3]);
                unsigned int B0 = cvtpk(p[8 * k2 + 4], p[8 * k2 + 5]);
                unsigned int B1 = cvtpk(p[8 * k2 + 6], p[8 * k2 + 7]);
                unsigned int sA0 = __shfl_xor((int)A0, 32);
                unsigned int sA1 = __shfl_xor((int)A1, 32);
                unsigned int sB0 = __shfl_xor((int)B0, 32);
                unsigned int sB1 = __shfl_xor((int)B1, 32);
                union { int i[4]; bf16x8 h; } u;
                u.i[0] = hi ? (int)sB0 : (int)A0;
                u.i[1] = hi ? (int)sB1 : (int)A1;
                u.i[2] = hi ? (int)B0 : (int)sA0;
                u.i[3] = hi ? (int)B1 : (int)sA1;
                pa[k2] = u.h;
            }

            // O^T += V^T @ P^T
            __builtin_amdgcn_s_setprio(1);
#pragma unroll
            for (int j2 = 0; j2 < 2; ++j2) {
                int row = 32 * j2 + q31;    // d row
                int swz = ((row ^ (row >> 3)) & 7) << 4;
#pragma unroll
                for (int k2 = 0; k2 < 2; ++k2) {
                    int off = row * 128 + ((64 * sub + 32 * k2 + 16 * hi) ^ swz);
                    bf16x8 vf = *(const bf16x8*)(Vtc + off);
                    oacc[j2] = __builtin_amdgcn_mfma_f32_32x32x16_bf16(vf, pa[k2], oacc[j2], 0, 0, 0);
                }
            }
            __builtin_amdgcn_s_setprio(0);
        }

        // --- write next tile's Vt (buf c^1) from in-flight regs ---
        if (pre) {
            char* Vtn = smem + 16384 + (c ^ 1) * 8192;
#pragma unroll
            for (int j = 0; j < 8; ++j) {
                int d = dblk + j;
                int swz = ((d ^ (d >> 3)) & 7) << 4;
                *(short*)(Vtn + d * 128 + ((2 * rV) ^ swz)) = vregA[j];
                *(short*)(Vtn + d * 128 + ((2 * (rV + 32)) ^ swz)) = vregB[j];
            }
        }
        __syncthreads();  // drains vmcnt (K t+1 staged) + lgkm (Vt t+1 visible); gates overwrite
    }

    // --- epilogue: transpose O^T through LDS, coalesced bf16 store ---
    float invl = 1.0f / l;
#pragma unroll
    for (int j2 = 0; j2 < 2; ++j2)
#pragma unroll
        for (int g = 0; g < 4; ++g) {
            float4 v4 = make_float4(oacc[j2][4 * g + 0] * invl, oacc[j2][4 * g + 1] * invl,
                                    oacc[j2][4 * g + 2] * invl, oacc[j2][4 * g + 3] * invl);
            *(float4*)&Os[w * 32 + q31][32 * j2 + 8 * g + 4 * hi] = v4;
        }
    __syncthreads();
#pragma unroll
    for (int it = 0; it < 8; ++it) {
        int row = w * 32 + it * 4 + (lane >> 4);
        int col = (lane & 15) * 4;
        float4 v = *(const float4*)&Os[row][col];
        ushort4 o;
        o.x = f2b(v.x); o.y = f2b(v.y); o.z = f2b(v.z); o.w = f2b(v.w);
        *(ushort4*)(y + (size_t)(b * TDIM + q0 + row) * CDIM + hh * DH + col) = o;
    }
}

// ---------------- launch ----------------
extern "C" void kernel_launch(void* const* d_in, const int* in_sizes, int n_in,
                              void* d_out, int out_size, void* d_ws, size_t ws_size,
                              hipStream_t stream) {
    const float* x      = (const float*)d_in[0];
    const float* ln1_w  = (const float*)d_in[1];
    const float* ln1_b  = (const float*)d_in[2];
    const float* W_attn = (const float*)d_in[3];
    const float* b_attn = (const float*)d_in[4];
    const float* W_o    = (const float*)d_in[5];
    const float* b_o    = (const float*)d_in[6];
    const float* ln2_w  = (const float*)d_in[7];
    const float* ln2_b  = (const float*)d_in[8];
    const float* W_fc   = (const float*)d_in[9];
    const float* b_fc   = (const float*)d_in[10];
    const float* W_proj = (const float*)d_in[11];
    const float* b_proj = (const float*)d_in[12];
    float* out = (float*)d_out;

    char* ws = (char*)d_ws;
    const size_t MB = 1024 * 1024;
    unsigned short* h_bf    = (unsigned short*)(ws);             // 8 MB  [4096,1024]
    unsigned short* big     = (unsigned short*)(ws + 8 * MB);    // 32 MB qkv / fcact
    unsigned short* Wt_attn = (unsigned short*)(ws + 40 * MB);   // 6 MB  [3072,1024]
    unsigned short* Wt_o    = (unsigned short*)(ws + 46 * MB);   // 2 MB  [1024,1024]
    unsigned short* Wt_fc   = (unsigned short*)(ws + 48 * MB);   // 8 MB  [4096,1024]
    unsigned short* Wt_proj = (unsigned short*)(ws + 56 * MB);   // 8 MB  [1024,4096]
    float* x1 = out;

    // 0. weight transpose + cast (W[K][N] -> Wt[N][K] bf16)
    hipLaunchKernelGGL(transpose_cast, dim3(96, 32),  dim3(256), 0, stream, W_attn, Wt_attn, CDIM, 3 * CDIM);
    hipLaunchKernelGGL(transpose_cast, dim3(32, 32),  dim3(256), 0, stream, W_o,    Wt_o,    CDIM, CDIM);
    hipLaunchKernelGGL(transpose_cast, dim3(128, 32), dim3(256), 0, stream, W_fc,   Wt_fc,   CDIM, 4 * CDIM);
    hipLaunchKernelGGL(transpose_cast, dim3(32, 128), dim3(256), 0, stream, W_proj, Wt_proj, 4 * CDIM, CDIM);

    // 1. h = LN1(x)  (bf16)
    hipLaunchKernelGGL(ln_kernel, dim3(MDIM), dim3(256), 0, stream, x, ln1_w, ln1_b, h_bf);
    // 2. qkv = h @ W_attn + b_attn  -> bf16 [4096, 3072]
    hipLaunchKernelGGL((gemm_bf16<0>), dim3(3 * CDIM / 128, MDIM / 128), dim3(256), 0,
                       stream, h_bf, Wt_attn, b_attn, nullptr, big, MDIM, 3 * CDIM, CDIM);
    // 3. y = attention(qkv) -> h_bf (bf16)
    hipLaunchKernelGGL(attn_mfma, dim3(BDIM * HEADS, TDIM / 128), dim3(256), 0, stream,
                       big, h_bf);
    // 4. x1 = x + y @ W_o + b_o  (f32)
    hipLaunchKernelGGL((gemm_bf16<1>), dim3(CDIM / 128, MDIM / 128), dim3(256), 0,
                       stream, h_bf, Wt_o, b_o, x, x1, MDIM, CDIM, CDIM);
    // 5. h = LN2(x1) (bf16)
    hipLaunchKernelGGL(ln_kernel, dim3(MDIM), dim3(256), 0, stream, x1, ln2_w, ln2_b, h_bf);
    // 6. fcact = gelu(h @ W_fc + b_fc) -> bf16 [4096, 4096]
    hipLaunchKernelGGL((gemm_bf16<2>), dim3(4 * CDIM / 128, MDIM / 128), dim3(256), 0,
                       stream, h_bf, Wt_fc, b_fc, nullptr, big, MDIM, 4 * CDIM, CDIM);
    // 7. out = x1 + fcact @ W_proj + b_proj (f32)
    hipLaunchKernelGGL((gemm_bf16<1>), dim3(CDIM / 128, MDIM / 128), dim3(256), 0,
                       stream, big, Wt_proj, b_proj, x1, out, MDIM, CDIM, 4 * CDIM);
}

// Round 7
// 292.284 us; speedup vs baseline: 1.0991x; 1.0991x over previous
//
#include <hip/hip_runtime.h>
#include <math.h>

// GPT-2 block forward. bf16 MFMA GEMMs + bf16 MFMA flash attention (32x32, in-reg softmax,
// split-KV wave pairs, double-buffered K/V). B=2, T=2048, C=1024, H=16, Dh=64.
constexpr int TDIM = 2048;
constexpr int BDIM = 2;
constexpr int CDIM = 1024;
constexpr int HEADS = 16;
constexpr int DH = 64;
constexpr int MDIM = BDIM * TDIM; // 4096

typedef short bf16x8 __attribute__((ext_vector_type(8)));
typedef float f32x4 __attribute__((ext_vector_type(4)));
typedef float f32x16 __attribute__((ext_vector_type(16)));

__device__ __forceinline__ float b2f(unsigned short u) {
    union { float f; unsigned int i; } v; v.i = ((unsigned int)u) << 16; return v.f;
}
__device__ __forceinline__ unsigned short f2b(float f) {
    union { float f; unsigned int i; } v; v.f = f;
    unsigned int r = (v.i + 0x7FFFu + ((v.i >> 16) & 1u)) >> 16;
    return (unsigned short)r;
}
// HW packed f32x2 -> bf16x2 (RNE), single instruction; no builtin on gfx950.
__device__ __forceinline__ unsigned int cvtpk(float lo, float hi) {
    unsigned int r;
    asm("v_cvt_pk_bf16_f32 %0, %1, %2" : "=v"(r) : "v"(lo), "v"(hi));
    return r;
}
__device__ __forceinline__ float gelu_f(float x) {
    const float c0 = 0.7978845608028654f; // sqrt(2/pi)
    float x3 = x * x * x;
    float t = tanhf(c0 * (x + 0.044715f * x3));
    return 0.5f * x * (1.0f + t);
}
__device__ __forceinline__ void async_copy16(const void* g, void* l) {
    __builtin_amdgcn_global_load_lds(
        (const __attribute__((address_space(1))) unsigned int*)g,
        (__attribute__((address_space(3))) unsigned int*)l, 16, 0, 0);
}

// ---------------- weight transpose + cast: W[K][N] f32 -> Wt[N][K] bf16 ----------------
__global__ __launch_bounds__(256) void transpose_cast(
    const float* __restrict__ W, unsigned short* __restrict__ Wt, int K, int N) {
    __shared__ float tile[32][33];
    int n0 = blockIdx.x * 32, k0 = blockIdx.y * 32;
    int tx = threadIdx.x & 31, ty = threadIdx.x >> 5; // 32 x 8
#pragma unroll
    for (int i = 0; i < 32; i += 8)
        tile[ty + i][tx] = W[(size_t)(k0 + ty + i) * N + n0 + tx];
    __syncthreads();
#pragma unroll
    for (int i = 0; i < 32; i += 8)
        Wt[(size_t)(n0 + ty + i) * K + k0 + tx] = f2b(tile[tx][ty + i]);
}

// ---------------- LayerNorm: f32 in -> bf16 out, one block per row of 1024 ----------------
__global__ __launch_bounds__(256) void ln_kernel(
    const float* __restrict__ x, const float* __restrict__ w,
    const float* __restrict__ b, unsigned short* __restrict__ out) {
    int row = blockIdx.x;
    int tid = threadIdx.x;
    const float* xr = x + (size_t)row * CDIM;
    float4 v = *(const float4*)(xr + tid * 4);
    float s  = v.x + v.y + v.z + v.w;
    float ss = v.x * v.x + v.y * v.y + v.z * v.z + v.w * v.w;
#pragma unroll
    for (int off = 32; off >= 1; off >>= 1) {
        s  += __shfl_xor(s, off);
        ss += __shfl_xor(ss, off);
    }
    __shared__ float rs[4], rss[4];
    int wave = tid >> 6;
    if ((tid & 63) == 0) { rs[wave] = s; rss[wave] = ss; }
    __syncthreads();
    s  = rs[0] + rs[1] + rs[2] + rs[3];
    ss = rss[0] + rss[1] + rss[2] + rss[3];
    float mean = s * (1.0f / CDIM);
    float var  = ss * (1.0f / CDIM) - mean * mean;
    float rstd = rsqrtf(var + 1e-5f);
    float4 wv = *(const float4*)(w + tid * 4);
    float4 bv = *(const float4*)(b + tid * 4);
    ushort4 o;
    o.x = f2b((v.x - mean) * rstd * wv.x + bv.x);
    o.y = f2b((v.y - mean) * rstd * wv.y + bv.y);
    o.z = f2b((v.z - mean) * rstd * wv.z + bv.z);
    o.w = f2b((v.w - mean) * rstd * wv.w + bv.w);
    *(ushort4*)(out + (size_t)row * CDIM + tid * 4) = o;
}

// ---------------- bf16 MFMA GEMM: C = A[M,K] @ Wt[N,K]^T (+bias, +res, +gelu) ----------
// 128x128 tile, BK=64, 256 threads (4 waves, 2x2), 64x64 per wave, 4x4 frags of 16x16.
template <int MODE>
__global__ __launch_bounds__(256) void gemm_bf16(
    const unsigned short* __restrict__ A, const unsigned short* __restrict__ Wt,
    const float* __restrict__ bias, const float* __restrict__ res,
    void* __restrict__ Cout, int M, int N, int K) {
    __shared__ __align__(16) short As[128 * 64];
    __shared__ __align__(16) short Bs[128 * 64];
    const int tid = threadIdx.x;
    const int lane = tid & 63, w = tid >> 6;
    const int wr = w >> 1, wc = w & 1;
    const int row0 = blockIdx.y * 128, col0 = blockIdx.x * 128;

    const int sr = lane >> 3;                   // 0..7: row within 8-row group
    const int sc = 8 * ((lane & 7) ^ sr);       // element col, pre-swizzled source
    const unsigned short* gA = A  + (size_t)(row0 + w * 8 + sr) * K + sc;
    const unsigned short* gB = Wt + (size_t)(col0 + w * 8 + sr) * K + sc;
    short* ldsA = As + (w * 8) * 64;            // wave-uniform dst base
    short* ldsB = Bs + (w * 8) * 64;

    f32x4 acc[4][4] = {};
    const int h = lane >> 4;                    // 0..3
    const int r15 = lane & 15;

    for (int k0 = 0; k0 < K; k0 += 64) {
        __syncthreads();
#pragma unroll
        for (int i = 0; i < 4; ++i) {
            async_copy16(gA + (size_t)i * 32 * K + k0, ldsA + i * 32 * 64);
            async_copy16(gB + (size_t)i * 32 * K + k0, ldsB + i * 32 * 64);
        }
        __syncthreads();
#pragma unroll
        for (int ks = 0; ks < 2; ++ks) {
            bf16x8 af[4], bfr[4];
#pragma unroll
            for (int i = 0; i < 4; ++i) {
                int ra = wr * 64 + i * 16 + r15;
                int offa = ra * 128 + ((ks * 64 + h * 16) ^ ((ra & 7) << 4));
                af[i] = *(const bf16x8*)((const char*)As + offa);
                int rb = wc * 64 + i * 16 + r15;
                int offb = rb * 128 + ((ks * 64 + h * 16) ^ ((rb & 7) << 4));
                bfr[i] = *(const bf16x8*)((const char*)Bs + offb);
            }
#pragma unroll
            for (int i = 0; i < 4; ++i)
#pragma unroll
                for (int j = 0; j < 4; ++j)
                    acc[i][j] = __builtin_amdgcn_mfma_f32_16x16x32_bf16(
                        af[i], bfr[j], acc[i][j], 0, 0, 0);
        }
    }

#pragma unroll
    for (int i = 0; i < 4; ++i) {
#pragma unroll
        for (int j = 0; j < 4; ++j) {
            int c = col0 + wc * 64 + j * 16 + r15;
            float bv = bias[c];
#pragma unroll
            for (int q = 0; q < 4; ++q) {
                int rr = row0 + wr * 64 + i * 16 + h * 4 + q;
                float v = acc[i][j][q] + bv;
                if (MODE == 2) v = gelu_f(v);
                if (MODE == 1) v += res[(size_t)rr * N + c];
                if (MODE == 1) ((float*)Cout)[(size_t)rr * N + c] = v;
                else ((unsigned short*)Cout)[(size_t)rr * N + c] = f2b(v);
            }
        }
    }
}

// ---------------- MFMA flash attention, split-KV wave pairs ----------------------------
// grid = (B*H, 16), block = 512 (8 waves). qy remap: by<8 ? 15-by : by-8 (pairs i,i+256
// likely co-resident carry complementary work). Wave w: q-group p=w&3 (rows q0+32p..+31),
// kv-half = w>>2 (half 0: even 32-kv subtiles, half 1: odd). Pair shares staged K/V;
// each keeps private (m,l,O^T) = exact flash pass over its kv subset; merged via LDS.
// S^T = mfma(K,Q) (lane q fixed); softmax exp2-domain + defer-max; PV O^T = mfma(V^T,P^T).
__global__ __launch_bounds__(512, 4) void attn_mfma(
    const unsigned short* __restrict__ qkv, unsigned short* __restrict__ y) {
    const int bh = blockIdx.x;
    const int b = bh >> 4, hh = bh & 15;
    const int by = blockIdx.y;
    const int qy = (by < 8) ? (15 - by) : (by - 8);
    const int q0 = qy * 128;
    const int tid = threadIdx.x;
    const int lane = tid & 63, w = tid >> 6;
    const int p = w & 3, half = w >> 2;
    const int hi = lane >> 5, q31 = lane & 31;

    const float SC  = 0.1803368801111244f;  // 0.125 * log2(e)
    const float THR = 44.0f;                // ~8 in log2 domain after scaling

    // LDS: Ks(c) at c*8192 [0,16K), Vt(c) at 16384+c*8192 [16K,32K);
    // Os[128][68] f32 aliases [0,34816) after final barrier; ml at [34816,36864).
    __shared__ __align__(16) char smem[36864];
    float (*Os)[68] = (float (*)[68])smem;
    float* mlm = (float*)(smem + 34816);          // [2][4][32]
    float* mll = (float*)(smem + 34816 + 1024);

    const size_t base = (size_t)b * TDIM * (3 * CDIM);
    const unsigned short* qb = qkv + base + hh * DH;
    const unsigned short* kb = qkv + base + CDIM + hh * DH;
    const unsigned short* vb = qkv + base + 2 * CDIM + hh * DH;

    const int gq = q0 + p * 32 + q31;       // this lane's q row
    const int qmin_w = q0 + p * 32;
    const int qmax_w = qmin_w + 31;

    // Q B-frags: qf[ks] elem j = Q[gq][16*ks + 8*hi + j]
    bf16x8 qf[4];
#pragma unroll
    for (int ks = 0; ks < 4; ++ks)
        qf[ks] = *(const bf16x8*)(qb + (size_t)gq * (3 * CDIM) + ks * 16 + hi * 8);

    // staging geometry: K = 8 waves x 8 rows (1 inst each); V = 512 thr x 1 row-chunk
    const int sr = lane >> 3;
    const int scK = 8 * ((lane & 7) ^ sr);  // pre-swizzled source col (elems)
    const int rV = tid >> 3;                // 0..63 kv row
    const int dblk = (tid & 7) * 8;

    f32x16 oacc[2] = {};                    // O^T: oacc[j2][r] = O[q][d=32*j2+(r&3)+8*(r>>2)+4*hi]
    float m = -1e30f, l = 0.f;
    bf16x8 vreg;

    const int NT = 2 * qy + 2;

    // ---- prologue: stage tile 0 into buffer 0 ----
    {
        short* Ks0 = (short*)smem;
        int rowbase = w * 8;
        async_copy16(kb + (size_t)(rowbase + sr) * (3 * CDIM) + scK, Ks0 + rowbase * 64);
        vreg = *(const bf16x8*)(vb + (size_t)rV * (3 * CDIM) + dblk);
        char* Vt0 = smem + 16384;
#pragma unroll
        for (int j = 0; j < 8; ++j) {
            int d = dblk + j;
            int swz = ((d ^ (d >> 3)) & 7) << 4;
            *(short*)(Vt0 + d * 128 + ((2 * rV) ^ swz)) = vreg[j];
        }
    }
    __syncthreads();  // drains vmcnt (K tile 0 in LDS) + lgkm (Vt writes visible)

    for (int kt = 0; kt < NT; ++kt) {
        const int c = kt & 1;
        const char* Ksc = smem + c * 8192;
        const char* Vtc = smem + 16384 + c * 8192;
        const bool pre = (kt + 1 < NT);

        // --- issue next tile's loads (K -> LDS buf c^1, V -> regs) ---
        if (pre) {
            const int kv1 = (kt + 1) * 64;
            short* Ksn = (short*)(smem + (c ^ 1) * 8192);
            int rowbase = w * 8;
            async_copy16(kb + (size_t)(kv1 + rowbase + sr) * (3 * CDIM) + scK,
                         Ksn + rowbase * 64);
            vreg = *(const bf16x8*)(vb + (size_t)(kv1 + rV) * (3 * CDIM) + dblk);
        }

        // --- compute this wave's 32-kv subtile of tile kt ---
        const int kvs = kt * 64 + half * 32;
        if (kvs <= qmax_w) {
            // S^T subtile: rows kv (reg-mapped), col q (lane)
            f32x16 sacc = {};
            __builtin_amdgcn_s_setprio(1);
#pragma unroll
            for (int ks = 0; ks < 4; ++ks) {
                int row = half * 32 + q31;
                int off = row * 128 + ((32 * ks + 16 * hi) ^ ((row & 7) << 4));
                bf16x8 kf = *(const bf16x8*)(Ksc + off);
                sacc = __builtin_amdgcn_mfma_f32_32x32x16_bf16(kf, qf[ks], sacc, 0, 0, 0);
            }
            __builtin_amdgcn_s_setprio(0);

            // causal mask in raw domain (p_[r]: kv = kvs + (r&3)+8*(r>>2)+4*hi)
            float p_[16];
            if (kvs + 31 > qmin_w) {
#pragma unroll
                for (int r = 0; r < 16; ++r) {
                    int kvg = kvs + (r & 3) + 8 * (r >> 2) + 4 * hi;
                    p_[r] = (kvg > gq) ? -1e30f : sacc[r];
                }
            } else {
#pragma unroll
                for (int r = 0; r < 16; ++r) p_[r] = sacc[r];
            }

            // row max (raw domain)
            float t8[8];
#pragma unroll
            for (int r = 0; r < 8; ++r) t8[r] = fmaxf(p_[r], p_[r + 8]);
#pragma unroll
            for (int r = 0; r < 4; ++r) t8[r] = fmaxf(t8[r], t8[r + 4]);
            float pm = fmaxf(fmaxf(t8[0], t8[1]), fmaxf(t8[2], t8[3]));
            pm = fmaxf(pm, __shfl_xor(pm, 32));

            // defer-max: only rescale when the max moved materially
            if (!__all(pm <= m + THR)) {
                float mnew = fmaxf(m, pm);
                float sf = exp2f((m - mnew) * SC);
                m = mnew;
                l *= sf;
                oacc[0] *= sf;
                oacc[1] *= sf;
            }
            float mc = m * SC;
#pragma unroll
            for (int r = 0; r < 16; ++r) p_[r] = exp2f(fmaf(p_[r], SC, -mc));
#pragma unroll
            for (int r = 0; r < 8; ++r) t8[r] = p_[r] + p_[r + 8];
#pragma unroll
            for (int r = 0; r < 4; ++r) t8[r] = t8[r] + t8[r + 4];
            float rsum = (t8[0] + t8[1]) + (t8[2] + t8[3]);
            rsum += __shfl_xor(rsum, 32);
            l += rsum;

            // pack P -> PV B-frags (HW cvt_pk + half-swap)
            bf16x8 pa[2];
#pragma unroll
            for (int k2 = 0; k2 < 2; ++k2) {
                unsigned int A0 = cvtpk(p_[8 * k2 + 0], p_[8 * k2 + 1]);
                unsigned int A1 = cvtpk(p_[8 * k2 + 2], p_[8 * k2 + 3]);
                unsigned int B0 = cvtpk(p_[8 * k2 + 4], p_[8 * k2 + 5]);
                unsigned int B1 = cvtpk(p_[8 * k2 + 6], p_[8 * k2 + 7]);
                unsigned int sA0 = __shfl_xor((int)A0, 32);
                unsigned int sA1 = __shfl_xor((int)A1, 32);
                unsigned int sB0 = __shfl_xor((int)B0, 32);
                unsigned int sB1 = __shfl_xor((int)B1, 32);
                union { int i[4]; bf16x8 h; } u;
                u.i[0] = hi ? (int)sB0 : (int)A0;
                u.i[1] = hi ? (int)sB1 : (int)A1;
                u.i[2] = hi ? (int)B0 : (int)sA0;
                u.i[3] = hi ? (int)B1 : (int)sA1;
                pa[k2] = u.h;
            }

            // O^T += V^T @ P^T
            __builtin_amdgcn_s_setprio(1);
#pragma unroll
            for (int j2 = 0; j2 < 2; ++j2) {
                int row = 32 * j2 + q31;    // d row
                int swz = ((row ^ (row >> 3)) & 7) << 4;
#pragma unroll
                for (int k2 = 0; k2 < 2; ++k2) {
                    int off = row * 128 + ((64 * half + 32 * k2 + 16 * hi) ^ swz);
                    bf16x8 vf = *(const bf16x8*)(Vtc + off);
                    oacc[j2] = __builtin_amdgcn_mfma_f32_32x32x16_bf16(vf, pa[k2], oacc[j2], 0, 0, 0);
                }
            }
            __builtin_amdgcn_s_setprio(0);
        }

        // --- write next tile's Vt (buf c^1) from in-flight regs ---
        if (pre) {
            char* Vtn = smem + 16384 + (c ^ 1) * 8192;
#pragma unroll
            for (int j = 0; j < 8; ++j) {
                int d = dblk + j;
                int swz = ((d ^ (d >> 3)) & 7) << 4;
                *(short*)(Vtn + d * 128 + ((2 * rV) ^ swz)) = vreg[j];
            }
        }
        __syncthreads();  // drains vmcnt + lgkm; gates buffer reuse
    }

    // ---- merge kv-half partials (exact flash merge) ----
    mlm[(half * 4 + p) * 32 + q31] = m;
    mll[(half * 4 + p) * 32 + q31] = l;
    __syncthreads();
    float mo = mlm[((half ^ 1) * 4 + p) * 32 + q31];
    float lo = mll[((half ^ 1) * 4 + p) * 32 + q31];
    float M  = fmaxf(m, mo);
    float sf  = exp2f((m - M) * SC);
    float sfo = exp2f((mo - M) * SC);
    float invl = 1.0f / (l * sf + lo * sfo);

    if (half == 1) {
#pragma unroll
        for (int j2 = 0; j2 < 2; ++j2)
#pragma unroll
            for (int g = 0; g < 4; ++g) {
                float4 v4 = make_float4(oacc[j2][4 * g + 0] * sf, oacc[j2][4 * g + 1] * sf,
                                        oacc[j2][4 * g + 2] * sf, oacc[j2][4 * g + 3] * sf);
                *(float4*)&Os[p * 32 + q31][32 * j2 + 8 * g + 4 * hi] = v4;
            }
    }
    __syncthreads();
    if (half == 0) {
#pragma unroll
        for (int j2 = 0; j2 < 2; ++j2)
#pragma unroll
            for (int g = 0; g < 4; ++g) {
                float4 t = *(const float4*)&Os[p * 32 + q31][32 * j2 + 8 * g + 4 * hi];
                float4 v4;
                v4.x = (oacc[j2][4 * g + 0] * sf + t.x) * invl;
                v4.y = (oacc[j2][4 * g + 1] * sf + t.y) * invl;
                v4.z = (oacc[j2][4 * g + 2] * sf + t.z) * invl;
                v4.w = (oacc[j2][4 * g + 3] * sf + t.w) * invl;
                *(float4*)&Os[p * 32 + q31][32 * j2 + 8 * g + 4 * hi] = v4;
            }
    }
    __syncthreads();

    // ---- coalesced bf16 store: 512 threads x 4 passes over 128 rows ----
    const int r0 = tid >> 4;          // 0..31
    const int c4 = (tid & 15) * 4;
#pragma unroll
    for (int pass = 0; pass < 4; ++pass) {
        int row = pass * 32 + r0;
        float4 v = *(const float4*)&Os[row][c4];
        ushort4 o;
        o.x = f2b(v.x); o.y = f2b(v.y); o.z = f2b(v.z); o.w = f2b(v.w);
        *(ushort4*)(y + (size_t)(b * TDIM + q0 + row) * CDIM + hh * DH + c4) = o;
    }
}

// ---------------- launch ----------------
extern "C" void kernel_launch(void* const* d_in, const int* in_sizes, int n_in,
                              void* d_out, int out_size, void* d_ws, size_t ws_size,
                              hipStream_t stream) {
    const float* x      = (const float*)d_in[0];
    const float* ln1_w  = (const float*)d_in[1];
    const float* ln1_b  = (const float*)d_in[2];
    const float* W_attn = (const float*)d_in[3];
    const float* b_attn = (const float*)d_in[4];
    const float* W_o    = (const float*)d_in[5];
    const float* b_o    = (const float*)d_in[6];
    const float* ln2_w  = (const float*)d_in[7];
    const float* ln2_b  = (const float*)d_in[8];
    const float* W_fc   = (const float*)d_in[9];
    const float* b_fc   = (const float*)d_in[10];
    const float* W_proj = (const float*)d_in[11];
    const float* b_proj = (const float*)d_in[12];
    float* out = (float*)d_out;

    char* ws = (char*)d_ws;
    const size_t MB = 1024 * 1024;
    unsigned short* h_bf    = (unsigned short*)(ws);             // 8 MB  [4096,1024]
    unsigned short* big     = (unsigned short*)(ws + 8 * MB);    // 32 MB qkv / fcact
    unsigned short* Wt_attn = (unsigned short*)(ws + 40 * MB);   // 6 MB  [3072,1024]
    unsigned short* Wt_o    = (unsigned short*)(ws + 46 * MB);   // 2 MB  [1024,1024]
    unsigned short* Wt_fc   = (unsigned short*)(ws + 48 * MB);   // 8 MB  [4096,1024]
    unsigned short* Wt_proj = (unsigned short*)(ws + 56 * MB);   // 8 MB  [1024,4096]
    float* x1 = out;

    // 0. weight transpose + cast (W[K][N] -> Wt[N][K] bf16)
    hipLaunchKernelGGL(transpose_cast, dim3(96, 32),  dim3(256), 0, stream, W_attn, Wt_attn, CDIM, 3 * CDIM);
    hipLaunchKernelGGL(transpose_cast, dim3(32, 32),  dim3(256), 0, stream, W_o,    Wt_o,    CDIM, CDIM);
    hipLaunchKernelGGL(transpose_cast, dim3(128, 32), dim3(256), 0, stream, W_fc,   Wt_fc,   CDIM, 4 * CDIM);
    hipLaunchKernelGGL(transpose_cast, dim3(32, 128), dim3(256), 0, stream, W_proj, Wt_proj, 4 * CDIM, CDIM);

    // 1. h = LN1(x)  (bf16)
    hipLaunchKernelGGL(ln_kernel, dim3(MDIM), dim3(256), 0, stream, x, ln1_w, ln1_b, h_bf);
    // 2. qkv = h @ W_attn + b_attn  -> bf16 [4096, 3072]
    hipLaunchKernelGGL((gemm_bf16<0>), dim3(3 * CDIM / 128, MDIM / 128), dim3(256), 0,
                       stream, h_bf, Wt_attn, b_attn, nullptr, big, MDIM, 3 * CDIM, CDIM);
    // 3. y = attention(qkv) -> h_bf (bf16)
    hipLaunchKernelGGL(attn_mfma, dim3(BDIM * HEADS, TDIM / 128), dim3(512), 0, stream,
                       big, h_bf);
    // 4. x1 = x + y @ W_o + b_o  (f32)
    hipLaunchKernelGGL((gemm_bf16<1>), dim3(CDIM / 128, MDIM / 128), dim3(256), 0,
                       stream, h_bf, Wt_o, b_o, x, x1, MDIM, CDIM, CDIM);
    // 5. h = LN2(x1) (bf16)
    hipLaunchKernelGGL(ln_kernel, dim3(MDIM), dim3(256), 0, stream, x1, ln2_w, ln2_b, h_bf);
    // 6. fcact = gelu(h @ W_fc + b_fc) -> bf16 [4096, 4096]
    hipLaunchKernelGGL((gemm_bf16<2>), dim3(4 * CDIM / 128, MDIM / 128), dim3(256), 0,
                       stream, h_bf, Wt_fc, b_fc, nullptr, big, MDIM, 4 * CDIM, CDIM);
    // 7. out = x1 + fcact @ W_proj + b_proj (f32)
    hipLaunchKernelGGL((gemm_bf16<1>), dim3(CDIM / 128, MDIM / 128), dim3(256), 0,
                       stream, big, Wt_proj, b_proj, x1, out, MDIM, CDIM, 4 * CDIM);
}

// Round 8
// 272.792 us; speedup vs baseline: 1.1776x; 1.0715x over previous
//
#include <hip/hip_runtime.h>
#include <math.h>

// GPT-2 block forward. bf16 MFMA GEMMs (tile-width templated) + bf16 MFMA flash attention
// (32x32 swapped-QK^T, split-KV wave pairs, double-buffered K/V).
// B=2, T=2048, C=1024, H=16, Dh=64. M = B*T = 4096.
constexpr int TDIM = 2048;
constexpr int BDIM = 2;
constexpr int CDIM = 1024;
constexpr int HEADS = 16;
constexpr int DH = 64;
constexpr int MDIM = BDIM * TDIM; // 4096

typedef short bf16x8 __attribute__((ext_vector_type(8)));
typedef float f32x4 __attribute__((ext_vector_type(4)));
typedef float f32x16 __attribute__((ext_vector_type(16)));

__device__ __forceinline__ float b2f(unsigned short u) {
    union { float f; unsigned int i; } v; v.i = ((unsigned int)u) << 16; return v.f;
}
__device__ __forceinline__ unsigned short f2b(float f) {
    union { float f; unsigned int i; } v; v.f = f;
    unsigned int r = (v.i + 0x7FFFu + ((v.i >> 16) & 1u)) >> 16;
    return (unsigned short)r;
}
// HW packed f32x2 -> bf16x2 (RNE), single instruction; no builtin on gfx950.
__device__ __forceinline__ unsigned int cvtpk(float lo, float hi) {
    unsigned int r;
    asm("v_cvt_pk_bf16_f32 %0, %1, %2" : "=v"(r) : "v"(lo), "v"(hi));
    return r;
}
__device__ __forceinline__ float gelu_f(float x) {
    const float c0 = 0.7978845608028654f; // sqrt(2/pi)
    float x3 = x * x * x;
    float t = tanhf(c0 * (x + 0.044715f * x3));
    return 0.5f * x * (1.0f + t);
}
__device__ __forceinline__ void async_copy16(const void* g, void* l) {
    __builtin_amdgcn_global_load_lds(
        (const __attribute__((address_space(1))) unsigned int*)g,
        (__attribute__((address_space(3))) unsigned int*)l, 16, 0, 0);
}

// ---------------- weight transpose + cast: W[K][N] f32 -> Wt[N][K] bf16 ----------------
__global__ __launch_bounds__(256) void transpose_cast(
    const float* __restrict__ W, unsigned short* __restrict__ Wt, int K, int N) {
    __shared__ float tile[32][33];
    int n0 = blockIdx.x * 32, k0 = blockIdx.y * 32;
    int tx = threadIdx.x & 31, ty = threadIdx.x >> 5; // 32 x 8
#pragma unroll
    for (int i = 0; i < 32; i += 8)
        tile[ty + i][tx] = W[(size_t)(k0 + ty + i) * N + n0 + tx];
    __syncthreads();
#pragma unroll
    for (int i = 0; i < 32; i += 8)
        Wt[(size_t)(n0 + ty + i) * K + k0 + tx] = f2b(tile[tx][ty + i]);
}

// ---------------- LayerNorm: f32 in -> bf16 out, one block per row of 1024 ----------------
__global__ __launch_bounds__(256) void ln_kernel(
    const float* __restrict__ x, const float* __restrict__ w,
    const float* __restrict__ b, unsigned short* __restrict__ out) {
    int row = blockIdx.x;
    int tid = threadIdx.x;
    const float* xr = x + (size_t)row * CDIM;
    float4 v = *(const float4*)(xr + tid * 4);
    float s  = v.x + v.y + v.z + v.w;
    float ss = v.x * v.x + v.y * v.y + v.z * v.z + v.w * v.w;
#pragma unroll
    for (int off = 32; off >= 1; off >>= 1) {
        s  += __shfl_xor(s, off);
        ss += __shfl_xor(ss, off);
    }
    __shared__ float rs[4], rss[4];
    int wave = tid >> 6;
    if ((tid & 63) == 0) { rs[wave] = s; rss[wave] = ss; }
    __syncthreads();
    s  = rs[0] + rs[1] + rs[2] + rs[3];
    ss = rss[0] + rss[1] + rss[2] + rss[3];
    float mean = s * (1.0f / CDIM);
    float var  = ss * (1.0f / CDIM) - mean * mean;
    float rstd = rsqrtf(var + 1e-5f);
    float4 wv = *(const float4*)(w + tid * 4);
    float4 bv = *(const float4*)(b + tid * 4);
    ushort4 o;
    o.x = f2b((v.x - mean) * rstd * wv.x + bv.x);
    o.y = f2b((v.y - mean) * rstd * wv.y + bv.y);
    o.z = f2b((v.z - mean) * rstd * wv.z + bv.z);
    o.w = f2b((v.w - mean) * rstd * wv.w + bv.w);
    *(ushort4*)(out + (size_t)row * CDIM + tid * 4) = o;
}

// ---------------- bf16 MFMA GEMM: C = A[M,K] @ Wt[N,K]^T (+bias, +res, +gelu) ----------
// 128 x BN tile, BK=64, 256 threads (4 waves, 2x2), wave tile 64 x BN/2.
// BN=128: exact prior verified geometry. BN=64: for N-narrow GEMMs (2x grid -> 2 blk/CU).
template <int MODE, int BN>
__global__ __launch_bounds__(256) void gemm_bf16(
    const unsigned short* __restrict__ A, const unsigned short* __restrict__ Wt,
    const float* __restrict__ bias, const float* __restrict__ res,
    void* __restrict__ Cout, int M, int N, int K) {
    constexpr int JF = BN / 32;                 // B-frags per wave (4 or 2)
    __shared__ __align__(16) short As[128 * 64];
    __shared__ __align__(16) short Bs[BN * 64];
    const int tid = threadIdx.x;
    const int lane = tid & 63, w = tid >> 6;
    const int wr = w >> 1, wc = w & 1;
    const int row0 = blockIdx.y * 128, col0 = blockIdx.x * BN;

    const int sr = lane >> 3;                   // 0..7: row within 8-row group
    const int sc = 8 * ((lane & 7) ^ sr);       // element col, pre-swizzled source
    const unsigned short* gA = A  + (size_t)(row0 + w * 8 + sr) * K + sc;
    const unsigned short* gB = Wt + (size_t)(col0 + w * 8 + sr) * K + sc;
    short* ldsA = As + (w * 8) * 64;            // wave-uniform dst base
    short* ldsB = Bs + (w * 8) * 64;

    f32x4 acc[4][JF] = {};
    const int h = lane >> 4;                    // 0..3
    const int r15 = lane & 15;

    for (int k0 = 0; k0 < K; k0 += 64) {
        __syncthreads();
#pragma unroll
        for (int i = 0; i < 4; ++i)
            async_copy16(gA + (size_t)i * 32 * K + k0, ldsA + i * 32 * 64);
#pragma unroll
        for (int i = 0; i < JF; ++i)
            async_copy16(gB + (size_t)i * 32 * K + k0, ldsB + i * 32 * 64);
        __syncthreads();
#pragma unroll
        for (int ks = 0; ks < 2; ++ks) {
            bf16x8 af[4], bfr[JF];
#pragma unroll
            for (int i = 0; i < 4; ++i) {
                int ra = wr * 64 + i * 16 + r15;
                int offa = ra * 128 + ((ks * 64 + h * 16) ^ ((ra & 7) << 4));
                af[i] = *(const bf16x8*)((const char*)As + offa);
            }
#pragma unroll
            for (int j = 0; j < JF; ++j) {
                int rb = wc * (BN / 2) + j * 16 + r15;
                int offb = rb * 128 + ((ks * 64 + h * 16) ^ ((rb & 7) << 4));
                bfr[j] = *(const bf16x8*)((const char*)Bs + offb);
            }
#pragma unroll
            for (int i = 0; i < 4; ++i)
#pragma unroll
                for (int j = 0; j < JF; ++j)
                    acc[i][j] = __builtin_amdgcn_mfma_f32_16x16x32_bf16(
                        af[i], bfr[j], acc[i][j], 0, 0, 0);
        }
    }

#pragma unroll
    for (int i = 0; i < 4; ++i) {
#pragma unroll
        for (int j = 0; j < JF; ++j) {
            int c = col0 + wc * (BN / 2) + j * 16 + r15;
            float bv = bias[c];
#pragma unroll
            for (int q = 0; q < 4; ++q) {
                int rr = row0 + wr * 64 + i * 16 + h * 4 + q;
                float v = acc[i][j][q] + bv;
                if (MODE == 2) v = gelu_f(v);
                if (MODE == 1) v += res[(size_t)rr * N + c];
                if (MODE == 1) ((float*)Cout)[(size_t)rr * N + c] = v;
                else ((unsigned short*)Cout)[(size_t)rr * N + c] = f2b(v);
            }
        }
    }
}

// ---------------- MFMA flash attention, split-KV wave pairs ----------------------------
// grid = (B*H, 16), block = 512 (8 waves). qy remap: by<8 ? 15-by : by-8.
// Wave w: q-group p=w&3 (rows q0+32p..+31), kv-half = w>>2. Pair shares staged K/V;
// each keeps private (m,l,O^T) = exact flash pass over its kv subset; merged via LDS.
__global__ __launch_bounds__(512, 4) void attn_mfma(
    const unsigned short* __restrict__ qkv, unsigned short* __restrict__ y) {
    const int bh = blockIdx.x;
    const int b = bh >> 4, hh = bh & 15;
    const int by = blockIdx.y;
    const int qy = (by < 8) ? (15 - by) : (by - 8);
    const int q0 = qy * 128;
    const int tid = threadIdx.x;
    const int lane = tid & 63, w = tid >> 6;
    const int p = w & 3, half = w >> 2;
    const int hi = lane >> 5, q31 = lane & 31;

    const float SC  = 0.1803368801111244f;  // 0.125 * log2(e)
    const float THR = 44.0f;                // ~8 in log2 domain after scaling

    __shared__ __align__(16) char smem[36864];
    float (*Os)[68] = (float (*)[68])smem;
    float* mlm = (float*)(smem + 34816);          // [2][4][32]
    float* mll = (float*)(smem + 34816 + 1024);

    const size_t base = (size_t)b * TDIM * (3 * CDIM);
    const unsigned short* qb = qkv + base + hh * DH;
    const unsigned short* kb = qkv + base + CDIM + hh * DH;
    const unsigned short* vb = qkv + base + 2 * CDIM + hh * DH;

    const int gq = q0 + p * 32 + q31;       // this lane's q row
    const int qmin_w = q0 + p * 32;
    const int qmax_w = qmin_w + 31;

    bf16x8 qf[4];
#pragma unroll
    for (int ks = 0; ks < 4; ++ks)
        qf[ks] = *(const bf16x8*)(qb + (size_t)gq * (3 * CDIM) + ks * 16 + hi * 8);

    const int sr = lane >> 3;
    const int scK = 8 * ((lane & 7) ^ sr);  // pre-swizzled source col (elems)
    const int rV = tid >> 3;                // 0..63 kv row
    const int dblk = (tid & 7) * 8;

    f32x16 oacc[2] = {};
    float m = -1e30f, l = 0.f;
    bf16x8 vreg;

    const int NT = 2 * qy + 2;

    // ---- prologue: stage tile 0 into buffer 0 ----
    {
        short* Ks0 = (short*)smem;
        int rowbase = w * 8;
        async_copy16(kb + (size_t)(rowbase + sr) * (3 * CDIM) + scK, Ks0 + rowbase * 64);
        vreg = *(const bf16x8*)(vb + (size_t)rV * (3 * CDIM) + dblk);
        char* Vt0 = smem + 16384;
#pragma unroll
        for (int j = 0; j < 8; ++j) {
            int d = dblk + j;
            int swz = ((d ^ (d >> 3)) & 7) << 4;
            *(short*)(Vt0 + d * 128 + ((2 * rV) ^ swz)) = vreg[j];
        }
    }
    __syncthreads();

    for (int kt = 0; kt < NT; ++kt) {
        const int c = kt & 1;
        const char* Ksc = smem + c * 8192;
        const char* Vtc = smem + 16384 + c * 8192;
        const bool pre = (kt + 1 < NT);

        if (pre) {
            const int kv1 = (kt + 1) * 64;
            short* Ksn = (short*)(smem + (c ^ 1) * 8192);
            int rowbase = w * 8;
            async_copy16(kb + (size_t)(kv1 + rowbase + sr) * (3 * CDIM) + scK,
                         Ksn + rowbase * 64);
            vreg = *(const bf16x8*)(vb + (size_t)(kv1 + rV) * (3 * CDIM) + dblk);
        }

        const int kvs = kt * 64 + half * 32;
        if (kvs <= qmax_w) {
            f32x16 sacc = {};
            __builtin_amdgcn_s_setprio(1);
#pragma unroll
            for (int ks = 0; ks < 4; ++ks) {
                int row = half * 32 + q31;
                int off = row * 128 + ((32 * ks + 16 * hi) ^ ((row & 7) << 4));
                bf16x8 kf = *(const bf16x8*)(Ksc + off);
                sacc = __builtin_amdgcn_mfma_f32_32x32x16_bf16(kf, qf[ks], sacc, 0, 0, 0);
            }
            __builtin_amdgcn_s_setprio(0);

            float p_[16];
            if (kvs + 31 > qmin_w) {
#pragma unroll
                for (int r = 0; r < 16; ++r) {
                    int kvg = kvs + (r & 3) + 8 * (r >> 2) + 4 * hi;
                    p_[r] = (kvg > gq) ? -1e30f : sacc[r];
                }
            } else {
#pragma unroll
                for (int r = 0; r < 16; ++r) p_[r] = sacc[r];
            }

            float t8[8];
#pragma unroll
            for (int r = 0; r < 8; ++r) t8[r] = fmaxf(p_[r], p_[r + 8]);
#pragma unroll
            for (int r = 0; r < 4; ++r) t8[r] = fmaxf(t8[r], t8[r + 4]);
            float pm = fmaxf(fmaxf(t8[0], t8[1]), fmaxf(t8[2], t8[3]));
            pm = fmaxf(pm, __shfl_xor(pm, 32));

            if (!__all(pm <= m + THR)) {
                float mnew = fmaxf(m, pm);
                float sf = exp2f((m - mnew) * SC);
                m = mnew;
                l *= sf;
                oacc[0] *= sf;
                oacc[1] *= sf;
            }
            float mc = m * SC;
#pragma unroll
            for (int r = 0; r < 16; ++r) p_[r] = exp2f(fmaf(p_[r], SC, -mc));
#pragma unroll
            for (int r = 0; r < 8; ++r) t8[r] = p_[r] + p_[r + 8];
#pragma unroll
            for (int r = 0; r < 4; ++r) t8[r] = t8[r] + t8[r + 4];
            float rsum = (t8[0] + t8[1]) + (t8[2] + t8[3]);
            rsum += __shfl_xor(rsum, 32);
            l += rsum;

            bf16x8 pa[2];
#pragma unroll
            for (int k2 = 0; k2 < 2; ++k2) {
                unsigned int A0 = cvtpk(p_[8 * k2 + 0], p_[8 * k2 + 1]);
                unsigned int A1 = cvtpk(p_[8 * k2 + 2], p_[8 * k2 + 3]);
                unsigned int B0 = cvtpk(p_[8 * k2 + 4], p_[8 * k2 + 5]);
                unsigned int B1 = cvtpk(p_[8 * k2 + 6], p_[8 * k2 + 7]);
                unsigned int sA0 = __shfl_xor((int)A0, 32);
                unsigned int sA1 = __shfl_xor((int)A1, 32);
                unsigned int sB0 = __shfl_xor((int)B0, 32);
                unsigned int sB1 = __shfl_xor((int)B1, 32);
                union { int i[4]; bf16x8 h; } u;
                u.i[0] = hi ? (int)sB0 : (int)A0;
                u.i[1] = hi ? (int)sB1 : (int)A1;
                u.i[2] = hi ? (int)B0 : (int)sA0;
                u.i[3] = hi ? (int)B1 : (int)sA1;
                pa[k2] = u.h;
            }

            __builtin_amdgcn_s_setprio(1);
#pragma unroll
            for (int j2 = 0; j2 < 2; ++j2) {
                int row = 32 * j2 + q31;    // d row
                int swz = ((row ^ (row >> 3)) & 7) << 4;
#pragma unroll
                for (int k2 = 0; k2 < 2; ++k2) {
                    int off = row * 128 + ((64 * half + 32 * k2 + 16 * hi) ^ swz);
                    bf16x8 vf = *(const bf16x8*)(Vtc + off);
                    oacc[j2] = __builtin_amdgcn_mfma_f32_32x32x16_bf16(vf, pa[k2], oacc[j2], 0, 0, 0);
                }
            }
            __builtin_amdgcn_s_setprio(0);
        }

        if (pre) {
            char* Vtn = smem + 16384 + (c ^ 1) * 8192;
#pragma unroll
            for (int j = 0; j < 8; ++j) {
                int d = dblk + j;
                int swz = ((d ^ (d >> 3)) & 7) << 4;
                *(short*)(Vtn + d * 128 + ((2 * rV) ^ swz)) = vreg[j];
            }
        }
        __syncthreads();
    }

    // ---- merge kv-half partials (exact flash merge) ----
    mlm[(half * 4 + p) * 32 + q31] = m;
    mll[(half * 4 + p) * 32 + q31] = l;
    __syncthreads();
    float mo = mlm[((half ^ 1) * 4 + p) * 32 + q31];
    float lo = mll[((half ^ 1) * 4 + p) * 32 + q31];
    float M  = fmaxf(m, mo);
    float sf  = exp2f((m - M) * SC);
    float sfo = exp2f((mo - M) * SC);
    float invl = 1.0f / (l * sf + lo * sfo);

    if (half == 1) {
#pragma unroll
        for (int j2 = 0; j2 < 2; ++j2)
#pragma unroll
            for (int g = 0; g < 4; ++g) {
                float4 v4 = make_float4(oacc[j2][4 * g + 0] * sf, oacc[j2][4 * g + 1] * sf,
                                        oacc[j2][4 * g + 2] * sf, oacc[j2][4 * g + 3] * sf);
                *(float4*)&Os[p * 32 + q31][32 * j2 + 8 * g + 4 * hi] = v4;
            }
    }
    __syncthreads();
    if (half == 0) {
#pragma unroll
        for (int j2 = 0; j2 < 2; ++j2)
#pragma unroll
            for (int g = 0; g < 4; ++g) {
                float4 t = *(const float4*)&Os[p * 32 + q31][32 * j2 + 8 * g + 4 * hi];
                float4 v4;
                v4.x = (oacc[j2][4 * g + 0] * sf + t.x) * invl;
                v4.y = (oacc[j2][4 * g + 1] * sf + t.y) * invl;
                v4.z = (oacc[j2][4 * g + 2] * sf + t.z) * invl;
                v4.w = (oacc[j2][4 * g + 3] * sf + t.w) * invl;
                *(float4*)&Os[p * 32 + q31][32 * j2 + 8 * g + 4 * hi] = v4;
            }
    }
    __syncthreads();

    // ---- coalesced bf16 store: 512 threads x 4 passes over 128 rows ----
    const int r0 = tid >> 4;          // 0..31
    const int c4 = (tid & 15) * 4;
#pragma unroll
    for (int pass = 0; pass < 4; ++pass) {
        int row = pass * 32 + r0;
        float4 v = *(const float4*)&Os[row][c4];
        ushort4 o;
        o.x = f2b(v.x); o.y = f2b(v.y); o.z = f2b(v.z); o.w = f2b(v.w);
        *(ushort4*)(y + (size_t)(b * TDIM + q0 + row) * CDIM + hh * DH + c4) = o;
    }
}

// ---------------- launch ----------------
extern "C" void kernel_launch(void* const* d_in, const int* in_sizes, int n_in,
                              void* d_out, int out_size, void* d_ws, size_t ws_size,
                              hipStream_t stream) {
    const float* x      = (const float*)d_in[0];
    const float* ln1_w  = (const float*)d_in[1];
    const float* ln1_b  = (const float*)d_in[2];
    const float* W_attn = (const float*)d_in[3];
    const float* b_attn = (const float*)d_in[4];
    const float* W_o    = (const float*)d_in[5];
    const float* b_o    = (const float*)d_in[6];
    const float* ln2_w  = (const float*)d_in[7];
    const float* ln2_b  = (const float*)d_in[8];
    const float* W_fc   = (const float*)d_in[9];
    const float* b_fc   = (const float*)d_in[10];
    const float* W_proj = (const float*)d_in[11];
    const float* b_proj = (const float*)d_in[12];
    float* out = (float*)d_out;

    char* ws = (char*)d_ws;
    const size_t MB = 1024 * 1024;
    unsigned short* h_bf    = (unsigned short*)(ws);             // 8 MB  [4096,1024]
    unsigned short* big     = (unsigned short*)(ws + 8 * MB);    // 32 MB qkv / fcact
    unsigned short* Wt_attn = (unsigned short*)(ws + 40 * MB);   // 6 MB  [3072,1024]
    unsigned short* Wt_o    = (unsigned short*)(ws + 46 * MB);   // 2 MB  [1024,1024]
    unsigned short* Wt_fc   = (unsigned short*)(ws + 48 * MB);   // 8 MB  [4096,1024]
    unsigned short* Wt_proj = (unsigned short*)(ws + 56 * MB);   // 8 MB  [1024,4096]
    float* x1 = out;

    // 0. weight transpose + cast (W[K][N] -> Wt[N][K] bf16)
    hipLaunchKernelGGL(transpose_cast, dim3(96, 32),  dim3(256), 0, stream, W_attn, Wt_attn, CDIM, 3 * CDIM);
    hipLaunchKernelGGL(transpose_cast, dim3(32, 32),  dim3(256), 0, stream, W_o,    Wt_o,    CDIM, CDIM);
    hipLaunchKernelGGL(transpose_cast, dim3(128, 32), dim3(256), 0, stream, W_fc,   Wt_fc,   CDIM, 4 * CDIM);
    hipLaunchKernelGGL(transpose_cast, dim3(32, 128), dim3(256), 0, stream, W_proj, Wt_proj, 4 * CDIM, CDIM);

    // 1. h = LN1(x)  (bf16)
    hipLaunchKernelGGL(ln_kernel, dim3(MDIM), dim3(256), 0, stream, x, ln1_w, ln1_b, h_bf);
    // 2. qkv = h @ W_attn + b_attn  -> bf16 [4096, 3072]  (768 blocks, 3/CU)
    hipLaunchKernelGGL((gemm_bf16<0, 128>), dim3(3 * CDIM / 128, MDIM / 128), dim3(256), 0,
                       stream, h_bf, Wt_attn, b_attn, nullptr, big, MDIM, 3 * CDIM, CDIM);
    // 3. y = attention(qkv) -> h_bf (bf16)
    hipLaunchKernelGGL(attn_mfma, dim3(BDIM * HEADS, TDIM / 128), dim3(512), 0, stream,
                       big, h_bf);
    // 4. x1 = x + y @ W_o + b_o  (f32)   BN=64 -> 512 blocks, 2/CU
    hipLaunchKernelGGL((gemm_bf16<1, 64>), dim3(CDIM / 64, MDIM / 128), dim3(256), 0,
                       stream, h_bf, Wt_o, b_o, x, x1, MDIM, CDIM, CDIM);
    // 5. h = LN2(x1) (bf16)
    hipLaunchKernelGGL(ln_kernel, dim3(MDIM), dim3(256), 0, stream, x1, ln2_w, ln2_b, h_bf);
    // 6. fcact = gelu(h @ W_fc + b_fc) -> bf16 [4096, 4096]  (1024 blocks, 4/CU)
    hipLaunchKernelGGL((gemm_bf16<2, 128>), dim3(4 * CDIM / 128, MDIM / 128), dim3(256), 0,
                       stream, h_bf, Wt_fc, b_fc, nullptr, big, MDIM, 4 * CDIM, CDIM);
    // 7. out = x1 + fcact @ W_proj + b_proj (f32)   BN=64 -> 512 blocks, 2/CU
    hipLaunchKernelGGL((gemm_bf16<1, 64>), dim3(CDIM / 64, MDIM / 128), dim3(256), 0,
                       stream, big, Wt_proj, b_proj, x1, out, MDIM, CDIM, 4 * CDIM);
}

// Round 9
// 241.871 us; speedup vs baseline: 1.3282x; 1.1278x over previous
//
#include <hip/hip_runtime.h>
#include <math.h>

// GPT-2 block forward. bf16 MFMA GEMMs (double-buffered, counted-vmcnt pipeline) +
// bf16 MFMA flash attention (32x32 swapped-QK^T, split-KV wave pairs, dbuf K/V).
// B=2, T=2048, C=1024, H=16, Dh=64. M = B*T = 4096.
constexpr int TDIM = 2048;
constexpr int BDIM = 2;
constexpr int CDIM = 1024;
constexpr int HEADS = 16;
constexpr int DH = 64;
constexpr int MDIM = BDIM * TDIM; // 4096

typedef short bf16x8 __attribute__((ext_vector_type(8)));
typedef float f32x4 __attribute__((ext_vector_type(4)));
typedef float f32x16 __attribute__((ext_vector_type(16)));

__device__ __forceinline__ float b2f(unsigned short u) {
    union { float f; unsigned int i; } v; v.i = ((unsigned int)u) << 16; return v.f;
}
__device__ __forceinline__ unsigned short f2b(float f) {
    union { float f; unsigned int i; } v; v.f = f;
    unsigned int r = (v.i + 0x7FFFu + ((v.i >> 16) & 1u)) >> 16;
    return (unsigned short)r;
}
// HW packed f32x2 -> bf16x2 (RNE), single instruction; no builtin on gfx950.
__device__ __forceinline__ unsigned int cvtpk(float lo, float hi) {
    unsigned int r;
    asm("v_cvt_pk_bf16_f32 %0, %1, %2" : "=v"(r) : "v"(lo), "v"(hi));
    return r;
}
// gelu(x) = x * sigmoid(2*c0*(x + 0.044715 x^3)); one HW exp2 instead of tanhf libcall.
// -2*log2(e)*sqrt(2/pi) = -2.3022077
__device__ __forceinline__ float gelu_f(float x) {
    float z = -2.3022077f * (x + 0.044715f * x * x * x);
    return x / (1.0f + exp2f(z));
}
__device__ __forceinline__ void async_copy16(const void* g, void* l) {
    __builtin_amdgcn_global_load_lds(
        (const __attribute__((address_space(1))) unsigned int*)g,
        (__attribute__((address_space(3))) unsigned int*)l, 16, 0, 0);
}

// ---------------- weight transpose + cast: W[K][N] f32 -> Wt[N][K] bf16 ----------------
__global__ __launch_bounds__(256) void transpose_cast(
    const float* __restrict__ W, unsigned short* __restrict__ Wt, int K, int N) {
    __shared__ float tile[32][33];
    int n0 = blockIdx.x * 32, k0 = blockIdx.y * 32;
    int tx = threadIdx.x & 31, ty = threadIdx.x >> 5; // 32 x 8
#pragma unroll
    for (int i = 0; i < 32; i += 8)
        tile[ty + i][tx] = W[(size_t)(k0 + ty + i) * N + n0 + tx];
    __syncthreads();
#pragma unroll
    for (int i = 0; i < 32; i += 8)
        Wt[(size_t)(n0 + ty + i) * K + k0 + tx] = f2b(tile[tx][ty + i]);
}

// ---------------- LayerNorm: f32 in -> bf16 out, one block per row of 1024 ----------------
__global__ __launch_bounds__(256) void ln_kernel(
    const float* __restrict__ x, const float* __restrict__ w,
    const float* __restrict__ b, unsigned short* __restrict__ out) {
    int row = blockIdx.x;
    int tid = threadIdx.x;
    const float* xr = x + (size_t)row * CDIM;
    float4 v = *(const float4*)(xr + tid * 4);
    float s  = v.x + v.y + v.z + v.w;
    float ss = v.x * v.x + v.y * v.y + v.z * v.z + v.w * v.w;
#pragma unroll
    for (int off = 32; off >= 1; off >>= 1) {
        s  += __shfl_xor(s, off);
        ss += __shfl_xor(ss, off);
    }
    __shared__ float rs[4], rss[4];
    int wave = tid >> 6;
    if ((tid & 63) == 0) { rs[wave] = s; rss[wave] = ss; }
    __syncthreads();
    s  = rs[0] + rs[1] + rs[2] + rs[3];
    ss = rss[0] + rss[1] + rss[2] + rss[3];
    float mean = s * (1.0f / CDIM);
    float var  = ss * (1.0f / CDIM) - mean * mean;
    float rstd = rsqrtf(var + 1e-5f);
    float4 wv = *(const float4*)(w + tid * 4);
    float4 bv = *(const float4*)(b + tid * 4);
    ushort4 o;
    o.x = f2b((v.x - mean) * rstd * wv.x + bv.x);
    o.y = f2b((v.y - mean) * rstd * wv.y + bv.y);
    o.z = f2b((v.z - mean) * rstd * wv.z + bv.z);
    o.w = f2b((v.w - mean) * rstd * wv.w + bv.w);
    *(ushort4*)(out + (size_t)row * CDIM + tid * 4) = o;
}

// ---------------- bf16 MFMA GEMM, pipelined: C = A[M,K] @ Wt[N,K]^T ------------------
// 128 x BN tile, BK=64, 256 threads (4 waves, 2x2), wave tile 64 x BN/2.
// Double-buffered LDS; issue tile t+1's global_load_lds BEFORE compute(t); counted
// s_waitcnt vmcnt(INF) (INF = next tile's in-flight loads, never 0 mid-loop) + raw
// s_barrier (no compiler vmcnt(0) drain). Second barrier gates buffer overwrite.
template <int MODE, int BN>
__global__ __launch_bounds__(256) void gemm_bf16(
    const unsigned short* __restrict__ A, const unsigned short* __restrict__ Wt,
    const float* __restrict__ bias, const float* __restrict__ res,
    void* __restrict__ Cout, int M, int N, int K) {
    constexpr int JF = BN / 32;                 // B-frags per wave (4 or 2)
    constexpr int INF = 4 + JF;                 // staging insts in flight per wave/tile
    __shared__ __align__(16) short As[2][128 * 64];
    __shared__ __align__(16) short Bs[2][BN * 64];
    const int tid = threadIdx.x;
    const int lane = tid & 63, w = tid >> 6;
    const int wr = w >> 1, wc = w & 1;
    const int row0 = blockIdx.y * 128, col0 = blockIdx.x * BN;

    const int sr = lane >> 3;                   // 0..7: row within 8-row group
    const int sc = 8 * ((lane & 7) ^ sr);       // element col, pre-swizzled source
    const unsigned short* gA = A  + (size_t)(row0 + w * 8 + sr) * K + sc;
    const unsigned short* gB = Wt + (size_t)(col0 + w * 8 + sr) * K + sc;

    f32x4 acc[4][JF] = {};
    const int h = lane >> 4;                    // 0..3
    const int r15 = lane & 15;
    const int nt = K >> 6;

    // prologue: stage tile 0 into buffer 0
#pragma unroll
    for (int i = 0; i < 4; ++i)
        async_copy16(gA + (size_t)i * 32 * K, &As[0][(w * 8 + i * 32) * 64]);
#pragma unroll
    for (int i = 0; i < JF; ++i)
        async_copy16(gB + (size_t)i * 32 * K, &Bs[0][(w * 8 + i * 32) * 64]);

    for (int t = 0; t < nt; ++t) {
        const int c = t & 1;
        if (t + 1 < nt) {
            const int k1 = (t + 1) << 6;
#pragma unroll
            for (int i = 0; i < 4; ++i)
                async_copy16(gA + (size_t)i * 32 * K + k1, &As[c ^ 1][(w * 8 + i * 32) * 64]);
#pragma unroll
            for (int i = 0; i < JF; ++i)
                async_copy16(gB + (size_t)i * 32 * K + k1, &Bs[c ^ 1][(w * 8 + i * 32) * 64]);
            asm volatile("s_waitcnt vmcnt(%0)" :: "n"(INF) : "memory");
        } else {
            asm volatile("s_waitcnt vmcnt(0)" ::: "memory");
        }
        __builtin_amdgcn_s_barrier();
        asm volatile("" ::: "memory");

#pragma unroll
        for (int ks = 0; ks < 2; ++ks) {
            bf16x8 af[4], bfr[JF];
#pragma unroll
            for (int i = 0; i < 4; ++i) {
                int ra = wr * 64 + i * 16 + r15;
                int offa = ra * 128 + ((ks * 64 + h * 16) ^ ((ra & 7) << 4));
                af[i] = *(const bf16x8*)((const char*)As[c] + offa);
            }
#pragma unroll
            for (int j = 0; j < JF; ++j) {
                int rb = wc * (BN / 2) + j * 16 + r15;
                int offb = rb * 128 + ((ks * 64 + h * 16) ^ ((rb & 7) << 4));
                bfr[j] = *(const bf16x8*)((const char*)Bs[c] + offb);
            }
#pragma unroll
            for (int i = 0; i < 4; ++i)
#pragma unroll
                for (int j = 0; j < JF; ++j)
                    acc[i][j] = __builtin_amdgcn_mfma_f32_16x16x32_bf16(
                        af[i], bfr[j], acc[i][j], 0, 0, 0);
        }
        asm volatile("" ::: "memory");
        __builtin_amdgcn_s_barrier();   // all reads of buf c done before t+1 stages into it
    }

#pragma unroll
    for (int i = 0; i < 4; ++i) {
#pragma unroll
        for (int j = 0; j < JF; ++j) {
            int c = col0 + wc * (BN / 2) + j * 16 + r15;
            float bv = bias[c];
#pragma unroll
            for (int q = 0; q < 4; ++q) {
                int rr = row0 + wr * 64 + i * 16 + h * 4 + q;
                float v = acc[i][j][q] + bv;
                if (MODE == 2) v = gelu_f(v);
                if (MODE == 1) v += res[(size_t)rr * N + c];
                if (MODE == 1) ((float*)Cout)[(size_t)rr * N + c] = v;
                else ((unsigned short*)Cout)[(size_t)rr * N + c] = f2b(v);
            }
        }
    }
}

// ---------------- MFMA flash attention, split-KV wave pairs ----------------------------
// grid = (B*H, 16), block = 512 (8 waves). qy remap: by<8 ? 15-by : by-8.
// Wave w: q-group p=w&3 (rows q0+32p..+31), kv-half = w>>2. Pair shares staged K/V;
// each keeps private (m,l,O^T) = exact flash pass over its kv subset; merged via LDS.
__global__ __launch_bounds__(512, 4) void attn_mfma(
    const unsigned short* __restrict__ qkv, unsigned short* __restrict__ y) {
    const int bh = blockIdx.x;
    const int b = bh >> 4, hh = bh & 15;
    const int by = blockIdx.y;
    const int qy = (by < 8) ? (15 - by) : (by - 8);
    const int q0 = qy * 128;
    const int tid = threadIdx.x;
    const int lane = tid & 63, w = tid >> 6;
    const int p = w & 3, half = w >> 2;
    const int hi = lane >> 5, q31 = lane & 31;

    const float SC  = 0.1803368801111244f;  // 0.125 * log2(e)
    const float THR = 44.0f;                // ~8 in log2 domain after scaling

    __shared__ __align__(16) char smem[36864];
    float (*Os)[68] = (float (*)[68])smem;
    float* mlm = (float*)(smem + 34816);          // [2][4][32]
    float* mll = (float*)(smem + 34816 + 1024);

    const size_t base = (size_t)b * TDIM * (3 * CDIM);
    const unsigned short* qb = qkv + base + hh * DH;
    const unsigned short* kb = qkv + base + CDIM + hh * DH;
    const unsigned short* vb = qkv + base + 2 * CDIM + hh * DH;

    const int gq = q0 + p * 32 + q31;       // this lane's q row
    const int qmin_w = q0 + p * 32;
    const int qmax_w = qmin_w + 31;

    bf16x8 qf[4];
#pragma unroll
    for (int ks = 0; ks < 4; ++ks)
        qf[ks] = *(const bf16x8*)(qb + (size_t)gq * (3 * CDIM) + ks * 16 + hi * 8);

    const int sr = lane >> 3;
    const int scK = 8 * ((lane & 7) ^ sr);  // pre-swizzled source col (elems)
    const int rV = tid >> 3;                // 0..63 kv row
    const int dblk = (tid & 7) * 8;

    f32x16 oacc[2] = {};
    float m = -1e30f, l = 0.f;
    bf16x8 vreg;

    const int NT = 2 * qy + 2;

    // ---- prologue: stage tile 0 into buffer 0 ----
    {
        short* Ks0 = (short*)smem;
        int rowbase = w * 8;
        async_copy16(kb + (size_t)(rowbase + sr) * (3 * CDIM) + scK, Ks0 + rowbase * 64);
        vreg = *(const bf16x8*)(vb + (size_t)rV * (3 * CDIM) + dblk);
        char* Vt0 = smem + 16384;
#pragma unroll
        for (int j = 0; j < 8; ++j) {
            int d = dblk + j;
            int swz = ((d ^ (d >> 3)) & 7) << 4;
            *(short*)(Vt0 + d * 128 + ((2 * rV) ^ swz)) = vreg[j];
        }
    }
    __syncthreads();

    for (int kt = 0; kt < NT; ++kt) {
        const int c = kt & 1;
        const char* Ksc = smem + c * 8192;
        const char* Vtc = smem + 16384 + c * 8192;
        const bool pre = (kt + 1 < NT);

        if (pre) {
            const int kv1 = (kt + 1) * 64;
            short* Ksn = (short*)(smem + (c ^ 1) * 8192);
            int rowbase = w * 8;
            async_copy16(kb + (size_t)(kv1 + rowbase + sr) * (3 * CDIM) + scK,
                         Ksn + rowbase * 64);
            vreg = *(const bf16x8*)(vb + (size_t)(kv1 + rV) * (3 * CDIM) + dblk);
        }

        const int kvs = kt * 64 + half * 32;
        if (kvs <= qmax_w) {
            f32x16 sacc = {};
            __builtin_amdgcn_s_setprio(1);
#pragma unroll
            for (int ks = 0; ks < 4; ++ks) {
                int row = half * 32 + q31;
                int off = row * 128 + ((32 * ks + 16 * hi) ^ ((row & 7) << 4));
                bf16x8 kf = *(const bf16x8*)(Ksc + off);
                sacc = __builtin_amdgcn_mfma_f32_32x32x16_bf16(kf, qf[ks], sacc, 0, 0, 0);
            }
            __builtin_amdgcn_s_setprio(0);

            float p_[16];
            if (kvs + 31 > qmin_w) {
#pragma unroll
                for (int r = 0; r < 16; ++r) {
                    int kvg = kvs + (r & 3) + 8 * (r >> 2) + 4 * hi;
                    p_[r] = (kvg > gq) ? -1e30f : sacc[r];
                }
            } else {
#pragma unroll
                for (int r = 0; r < 16; ++r) p_[r] = sacc[r];
            }

            float t8[8];
#pragma unroll
            for (int r = 0; r < 8; ++r) t8[r] = fmaxf(p_[r], p_[r + 8]);
#pragma unroll
            for (int r = 0; r < 4; ++r) t8[r] = fmaxf(t8[r], t8[r + 4]);
            float pm = fmaxf(fmaxf(t8[0], t8[1]), fmaxf(t8[2], t8[3]));
            pm = fmaxf(pm, __shfl_xor(pm, 32));

            if (!__all(pm <= m + THR)) {
                float mnew = fmaxf(m, pm);
                float sf = exp2f((m - mnew) * SC);
                m = mnew;
                l *= sf;
                oacc[0] *= sf;
                oacc[1] *= sf;
            }
            float mc = m * SC;
#pragma unroll
            for (int r = 0; r < 16; ++r) p_[r] = exp2f(fmaf(p_[r], SC, -mc));
#pragma unroll
            for (int r = 0; r < 8; ++r) t8[r] = p_[r] + p_[r + 8];
#pragma unroll
            for (int r = 0; r < 4; ++r) t8[r] = t8[r] + t8[r + 4];
            float rsum = (t8[0] + t8[1]) + (t8[2] + t8[3]);
            rsum += __shfl_xor(rsum, 32);
            l += rsum;

            bf16x8 pa[2];
#pragma unroll
            for (int k2 = 0; k2 < 2; ++k2) {
                unsigned int A0 = cvtpk(p_[8 * k2 + 0], p_[8 * k2 + 1]);
                unsigned int A1 = cvtpk(p_[8 * k2 + 2], p_[8 * k2 + 3]);
                unsigned int B0 = cvtpk(p_[8 * k2 + 4], p_[8 * k2 + 5]);
                unsigned int B1 = cvtpk(p_[8 * k2 + 6], p_[8 * k2 + 7]);
                unsigned int sA0 = __shfl_xor((int)A0, 32);
                unsigned int sA1 = __shfl_xor((int)A1, 32);
                unsigned int sB0 = __shfl_xor((int)B0, 32);
                unsigned int sB1 = __shfl_xor((int)B1, 32);
                union { int i[4]; bf16x8 h; } u;
                u.i[0] = hi ? (int)sB0 : (int)A0;
                u.i[1] = hi ? (int)sB1 : (int)A1;
                u.i[2] = hi ? (int)B0 : (int)sA0;
                u.i[3] = hi ? (int)B1 : (int)sA1;
                pa[k2] = u.h;
            }

            __builtin_amdgcn_s_setprio(1);
#pragma unroll
            for (int j2 = 0; j2 < 2; ++j2) {
                int row = 32 * j2 + q31;    // d row
                int swz = ((row ^ (row >> 3)) & 7) << 4;
#pragma unroll
                for (int k2 = 0; k2 < 2; ++k2) {
                    int off = row * 128 + ((64 * half + 32 * k2 + 16 * hi) ^ swz);
                    bf16x8 vf = *(const bf16x8*)(Vtc + off);
                    oacc[j2] = __builtin_amdgcn_mfma_f32_32x32x16_bf16(vf, pa[k2], oacc[j2], 0, 0, 0);
                }
            }
            __builtin_amdgcn_s_setprio(0);
        }

        if (pre) {
            char* Vtn = smem + 16384 + (c ^ 1) * 8192;
#pragma unroll
            for (int j = 0; j < 8; ++j) {
                int d = dblk + j;
                int swz = ((d ^ (d >> 3)) & 7) << 4;
                *(short*)(Vtn + d * 128 + ((2 * rV) ^ swz)) = vreg[j];
            }
        }
        __syncthreads();
    }

    // ---- merge kv-half partials (exact flash merge) ----
    mlm[(half * 4 + p) * 32 + q31] = m;
    mll[(half * 4 + p) * 32 + q31] = l;
    __syncthreads();
    float mo = mlm[((half ^ 1) * 4 + p) * 32 + q31];
    float lo = mll[((half ^ 1) * 4 + p) * 32 + q31];
    float M  = fmaxf(m, mo);
    float sf  = exp2f((m - M) * SC);
    float sfo = exp2f((mo - M) * SC);
    float invl = 1.0f / (l * sf + lo * sfo);

    if (half == 1) {
#pragma unroll
        for (int j2 = 0; j2 < 2; ++j2)
#pragma unroll
            for (int g = 0; g < 4; ++g) {
                float4 v4 = make_float4(oacc[j2][4 * g + 0] * sf, oacc[j2][4 * g + 1] * sf,
                                        oacc[j2][4 * g + 2] * sf, oacc[j2][4 * g + 3] * sf);
                *(float4*)&Os[p * 32 + q31][32 * j2 + 8 * g + 4 * hi] = v4;
            }
    }
    __syncthreads();
    if (half == 0) {
#pragma unroll
        for (int j2 = 0; j2 < 2; ++j2)
#pragma unroll
            for (int g = 0; g < 4; ++g) {
                float4 t = *(const float4*)&Os[p * 32 + q31][32 * j2 + 8 * g + 4 * hi];
                float4 v4;
                v4.x = (oacc[j2][4 * g + 0] * sf + t.x) * invl;
                v4.y = (oacc[j2][4 * g + 1] * sf + t.y) * invl;
                v4.z = (oacc[j2][4 * g + 2] * sf + t.z) * invl;
                v4.w = (oacc[j2][4 * g + 3] * sf + t.w) * invl;
                *(float4*)&Os[p * 32 + q31][32 * j2 + 8 * g + 4 * hi] = v4;
            }
    }
    __syncthreads();

    // ---- coalesced bf16 store: 512 threads x 4 passes over 128 rows ----
    const int r0 = tid >> 4;          // 0..31
    const int c4 = (tid & 15) * 4;
#pragma unroll
    for (int pass = 0; pass < 4; ++pass) {
        int row = pass * 32 + r0;
        float4 v = *(const float4*)&Os[row][c4];
        ushort4 o;
        o.x = f2b(v.x); o.y = f2b(v.y); o.z = f2b(v.z); o.w = f2b(v.w);
        *(ushort4*)(y + (size_t)(b * TDIM + q0 + row) * CDIM + hh * DH + c4) = o;
    }
}

// ---------------- launch ----------------
extern "C" void kernel_launch(void* const* d_in, const int* in_sizes, int n_in,
                              void* d_out, int out_size, void* d_ws, size_t ws_size,
                              hipStream_t stream) {
    const float* x      = (const float*)d_in[0];
    const float* ln1_w  = (const float*)d_in[1];
    const float* ln1_b  = (const float*)d_in[2];
    const float* W_attn = (const float*)d_in[3];
    const float* b_attn = (const float*)d_in[4];
    const float* W_o    = (const float*)d_in[5];
    const float* b_o    = (const float*)d_in[6];
    const float* ln2_w  = (const float*)d_in[7];
    const float* ln2_b  = (const float*)d_in[8];
    const float* W_fc   = (const float*)d_in[9];
    const float* b_fc   = (const float*)d_in[10];
    const float* W_proj = (const float*)d_in[11];
    const float* b_proj = (const float*)d_in[12];
    float* out = (float*)d_out;

    char* ws = (char*)d_ws;
    const size_t MB = 1024 * 1024;
    unsigned short* h_bf    = (unsigned short*)(ws);             // 8 MB  [4096,1024]
    unsigned short* big     = (unsigned short*)(ws + 8 * MB);    // 32 MB qkv / fcact
    unsigned short* Wt_attn = (unsigned short*)(ws + 40 * MB);   // 6 MB  [3072,1024]
    unsigned short* Wt_o    = (unsigned short*)(ws + 46 * MB);   // 2 MB  [1024,1024]
    unsigned short* Wt_fc   = (unsigned short*)(ws + 48 * MB);   // 8 MB  [4096,1024]
    unsigned short* Wt_proj = (unsigned short*)(ws + 56 * MB);   // 8 MB  [1024,4096]
    float* x1 = out;

    // 0. weight transpose + cast (W[K][N] -> Wt[N][K] bf16)
    hipLaunchKernelGGL(transpose_cast, dim3(96, 32),  dim3(256), 0, stream, W_attn, Wt_attn, CDIM, 3 * CDIM);
    hipLaunchKernelGGL(transpose_cast, dim3(32, 32),  dim3(256), 0, stream, W_o,    Wt_o,    CDIM, CDIM);
    hipLaunchKernelGGL(transpose_cast, dim3(128, 32), dim3(256), 0, stream, W_fc,   Wt_fc,   CDIM, 4 * CDIM);
    hipLaunchKernelGGL(transpose_cast, dim3(32, 128), dim3(256), 0, stream, W_proj, Wt_proj, 4 * CDIM, CDIM);

    // 1. h = LN1(x)  (bf16)
    hipLaunchKernelGGL(ln_kernel, dim3(MDIM), dim3(256), 0, stream, x, ln1_w, ln1_b, h_bf);
    // 2. qkv = h @ W_attn + b_attn  -> bf16 [4096, 3072]  (768 blocks)
    hipLaunchKernelGGL((gemm_bf16<0, 128>), dim3(3 * CDIM / 128, MDIM / 128), dim3(256), 0,
                       stream, h_bf, Wt_attn, b_attn, nullptr, big, MDIM, 3 * CDIM, CDIM);
    // 3. y = attention(qkv) -> h_bf (bf16)
    hipLaunchKernelGGL(attn_mfma, dim3(BDIM * HEADS, TDIM / 128), dim3(512), 0, stream,
                       big, h_bf);
    // 4. x1 = x + y @ W_o + b_o  (f32)   BN=64 -> 512 blocks
    hipLaunchKernelGGL((gemm_bf16<1, 64>), dim3(CDIM / 64, MDIM / 128), dim3(256), 0,
                       stream, h_bf, Wt_o, b_o, x, x1, MDIM, CDIM, CDIM);
    // 5. h = LN2(x1) (bf16)
    hipLaunchKernelGGL(ln_kernel, dim3(MDIM), dim3(256), 0, stream, x1, ln2_w, ln2_b, h_bf);
    // 6. fcact = gelu(h @ W_fc + b_fc) -> bf16 [4096, 4096]  (1024 blocks)
    hipLaunchKernelGGL((gemm_bf16<2, 128>), dim3(4 * CDIM / 128, MDIM / 128), dim3(256), 0,
                       stream, h_bf, Wt_fc, b_fc, nullptr, big, MDIM, 4 * CDIM, CDIM);
    // 7. out = x1 + fcact @ W_proj + b_proj (f32)   BN=64 -> 512 blocks
    hipLaunchKernelGGL((gemm_bf16<1, 64>), dim3(CDIM / 64, MDIM / 128), dim3(256), 0,
                       stream, big, Wt_proj, b_proj, x1, out, MDIM, CDIM, 4 * CDIM);
}

// Round 10
// 241.428 us; speedup vs baseline: 1.3306x; 1.0018x over previous
//
#include <hip/hip_runtime.h>
#include <math.h>

// GPT-2 block forward. bf16 MFMA GEMMs (double-buffered counted-vmcnt pipeline,
// XCD-chunked block swizzle) + bf16 MFMA flash attention (32x32 swapped-QK^T,
// split-KV wave pairs, dbuf K/V). B=2, T=2048, C=1024, H=16, Dh=64. M = B*T = 4096.
constexpr int TDIM = 2048;
constexpr int BDIM = 2;
constexpr int CDIM = 1024;
constexpr int HEADS = 16;
constexpr int DH = 64;
constexpr int MDIM = BDIM * TDIM; // 4096

typedef short bf16x8 __attribute__((ext_vector_type(8)));
typedef float f32x4 __attribute__((ext_vector_type(4)));
typedef float f32x16 __attribute__((ext_vector_type(16)));

__device__ __forceinline__ float b2f(unsigned short u) {
    union { float f; unsigned int i; } v; v.i = ((unsigned int)u) << 16; return v.f;
}
__device__ __forceinline__ unsigned short f2b(float f) {
    union { float f; unsigned int i; } v; v.f = f;
    unsigned int r = (v.i + 0x7FFFu + ((v.i >> 16) & 1u)) >> 16;
    return (unsigned short)r;
}
// HW packed f32x2 -> bf16x2 (RNE), single instruction; no builtin on gfx950.
__device__ __forceinline__ unsigned int cvtpk(float lo, float hi) {
    unsigned int r;
    asm("v_cvt_pk_bf16_f32 %0, %1, %2" : "=v"(r) : "v"(lo), "v"(hi));
    return r;
}
// gelu(x) = x * sigmoid(2*c0*(x + 0.044715 x^3)); one HW exp2 instead of tanhf libcall.
__device__ __forceinline__ float gelu_f(float x) {
    float z = -2.3022077f * (x + 0.044715f * x * x * x);
    return x / (1.0f + exp2f(z));
}
__device__ __forceinline__ void async_copy16(const void* g, void* l) {
    __builtin_amdgcn_global_load_lds(
        (const __attribute__((address_space(1))) unsigned int*)g,
        (__attribute__((address_space(3))) unsigned int*)l, 16, 0, 0);
}

// ---------------- weight transpose + cast: W[K][N] f32 -> Wt[N][K] bf16 ----------------
__global__ __launch_bounds__(256) void transpose_cast(
    const float* __restrict__ W, unsigned short* __restrict__ Wt, int K, int N) {
    __shared__ float tile[32][33];
    int n0 = blockIdx.x * 32, k0 = blockIdx.y * 32;
    int tx = threadIdx.x & 31, ty = threadIdx.x >> 5; // 32 x 8
#pragma unroll
    for (int i = 0; i < 32; i += 8)
        tile[ty + i][tx] = W[(size_t)(k0 + ty + i) * N + n0 + tx];
    __syncthreads();
#pragma unroll
    for (int i = 0; i < 32; i += 8)
        Wt[(size_t)(n0 + ty + i) * K + k0 + tx] = f2b(tile[tx][ty + i]);
}

// ---------------- LayerNorm: f32 in -> bf16 out, one block per row of 1024 ----------------
__global__ __launch_bounds__(256) void ln_kernel(
    const float* __restrict__ x, const float* __restrict__ w,
    const float* __restrict__ b, unsigned short* __restrict__ out) {
    int row = blockIdx.x;
    int tid = threadIdx.x;
    const float* xr = x + (size_t)row * CDIM;
    float4 v = *(const float4*)(xr + tid * 4);
    float s  = v.x + v.y + v.z + v.w;
    float ss = v.x * v.x + v.y * v.y + v.z * v.z + v.w * v.w;
#pragma unroll
    for (int off = 32; off >= 1; off >>= 1) {
        s  += __shfl_xor(s, off);
        ss += __shfl_xor(ss, off);
    }
    __shared__ float rs[4], rss[4];
    int wave = tid >> 6;
    if ((tid & 63) == 0) { rs[wave] = s; rss[wave] = ss; }
    __syncthreads();
    s  = rs[0] + rs[1] + rs[2] + rs[3];
    ss = rss[0] + rss[1] + rss[2] + rss[3];
    float mean = s * (1.0f / CDIM);
    float var  = ss * (1.0f / CDIM) - mean * mean;
    float rstd = rsqrtf(var + 1e-5f);
    float4 wv = *(const float4*)(w + tid * 4);
    float4 bv = *(const float4*)(b + tid * 4);
    ushort4 o;
    o.x = f2b((v.x - mean) * rstd * wv.x + bv.x);
    o.y = f2b((v.y - mean) * rstd * wv.y + bv.y);
    o.z = f2b((v.z - mean) * rstd * wv.z + bv.z);
    o.w = f2b((v.w - mean) * rstd * wv.w + bv.w);
    *(ushort4*)(out + (size_t)row * CDIM + tid * 4) = o;
}

// ---------------- bf16 MFMA GEMM, pipelined + XCD-chunked: C = A @ Wt^T --------------
// 128 x BN tile, BK=64, 256 threads (4 waves, 2x2), wave tile 64 x BN/2.
// XCD swizzle: nbid = (bid&7)*(nwg/8) + bid>>3 (bijective, nwg%8==0) -> each XCD gets
// 4 contiguous grid-rows, so the col-blocks sharing an A-stripe fill ONE L2, not 8.
// Double-buffered LDS; counted s_waitcnt vmcnt(INF) + raw s_barrier (no vmcnt(0) drain).
template <int MODE, int BN>
__global__ __launch_bounds__(256) void gemm_bf16(
    const unsigned short* __restrict__ A, const unsigned short* __restrict__ Wt,
    const float* __restrict__ bias, const float* __restrict__ res,
    void* __restrict__ Cout, int M, int N, int K) {
    constexpr int JF = BN / 32;                 // B-frags per wave (4 or 2)
    constexpr int INF = 4 + JF;                 // staging insts in flight per wave/tile
    __shared__ __align__(16) short As[2][128 * 64];
    __shared__ __align__(16) short Bs[2][BN * 64];
    const int tid = threadIdx.x;
    const int lane = tid & 63, w = tid >> 6;
    const int wr = w >> 1, wc = w & 1;

    const int nwg = gridDim.x * gridDim.y;
    const int bid = blockIdx.y * gridDim.x + blockIdx.x;
    const int nbid = (bid & 7) * (nwg >> 3) + (bid >> 3);
    const int bx = nbid % gridDim.x;
    const int by = nbid / gridDim.x;
    const int row0 = by * 128, col0 = bx * BN;

    const int sr = lane >> 3;                   // 0..7: row within 8-row group
    const int sc = 8 * ((lane & 7) ^ sr);       // element col, pre-swizzled source
    const unsigned short* gA = A  + (size_t)(row0 + w * 8 + sr) * K + sc;
    const unsigned short* gB = Wt + (size_t)(col0 + w * 8 + sr) * K + sc;

    f32x4 acc[4][JF] = {};
    const int h = lane >> 4;                    // 0..3
    const int r15 = lane & 15;
    const int nt = K >> 6;

    // prologue: stage tile 0 into buffer 0
#pragma unroll
    for (int i = 0; i < 4; ++i)
        async_copy16(gA + (size_t)i * 32 * K, &As[0][(w * 8 + i * 32) * 64]);
#pragma unroll
    for (int i = 0; i < JF; ++i)
        async_copy16(gB + (size_t)i * 32 * K, &Bs[0][(w * 8 + i * 32) * 64]);

    for (int t = 0; t < nt; ++t) {
        const int c = t & 1;
        if (t + 1 < nt) {
            const int k1 = (t + 1) << 6;
#pragma unroll
            for (int i = 0; i < 4; ++i)
                async_copy16(gA + (size_t)i * 32 * K + k1, &As[c ^ 1][(w * 8 + i * 32) * 64]);
#pragma unroll
            for (int i = 0; i < JF; ++i)
                async_copy16(gB + (size_t)i * 32 * K + k1, &Bs[c ^ 1][(w * 8 + i * 32) * 64]);
            asm volatile("s_waitcnt vmcnt(%0)" :: "n"(INF) : "memory");
        } else {
            asm volatile("s_waitcnt vmcnt(0)" ::: "memory");
        }
        __builtin_amdgcn_s_barrier();
        asm volatile("" ::: "memory");

#pragma unroll
        for (int ks = 0; ks < 2; ++ks) {
            bf16x8 af[4], bfr[JF];
#pragma unroll
            for (int i = 0; i < 4; ++i) {
                int ra = wr * 64 + i * 16 + r15;
                int offa = ra * 128 + ((ks * 64 + h * 16) ^ ((ra & 7) << 4));
                af[i] = *(const bf16x8*)((const char*)As[c] + offa);
            }
#pragma unroll
            for (int j = 0; j < JF; ++j) {
                int rb = wc * (BN / 2) + j * 16 + r15;
                int offb = rb * 128 + ((ks * 64 + h * 16) ^ ((rb & 7) << 4));
                bfr[j] = *(const bf16x8*)((const char*)Bs[c] + offb);
            }
#pragma unroll
            for (int i = 0; i < 4; ++i)
#pragma unroll
                for (int j = 0; j < JF; ++j)
                    acc[i][j] = __builtin_amdgcn_mfma_f32_16x16x32_bf16(
                        af[i], bfr[j], acc[i][j], 0, 0, 0);
        }
        asm volatile("" ::: "memory");
        __builtin_amdgcn_s_barrier();   // all reads of buf c done before t+1 stages into it
    }

#pragma unroll
    for (int i = 0; i < 4; ++i) {
#pragma unroll
        for (int j = 0; j < JF; ++j) {
            int c = col0 + wc * (BN / 2) + j * 16 + r15;
            float bv = bias[c];
#pragma unroll
            for (int q = 0; q < 4; ++q) {
                int rr = row0 + wr * 64 + i * 16 + h * 4 + q;
                float v = acc[i][j][q] + bv;
                if (MODE == 2) v = gelu_f(v);
                if (MODE == 1) v += res[(size_t)rr * N + c];
                if (MODE == 1) ((float*)Cout)[(size_t)rr * N + c] = v;
                else ((unsigned short*)Cout)[(size_t)rr * N + c] = f2b(v);
            }
        }
    }
}

// ---------------- MFMA flash attention, split-KV wave pairs ----------------------------
// grid = (B*H, 16), block = 512 (8 waves). qy remap: by<8 ? 15-by : by-8.
// Wave w: q-group p=w&3 (rows q0+32p..+31), kv-half = w>>2. Pair shares staged K/V;
// each keeps private (m,l,O^T) = exact flash pass over its kv subset; merged via LDS.
__global__ __launch_bounds__(512, 4) void attn_mfma(
    const unsigned short* __restrict__ qkv, unsigned short* __restrict__ y) {
    const int bh = blockIdx.x;
    const int b = bh >> 4, hh = bh & 15;
    const int by = blockIdx.y;
    const int qy = (by < 8) ? (15 - by) : (by - 8);
    const int q0 = qy * 128;
    const int tid = threadIdx.x;
    const int lane = tid & 63, w = tid >> 6;
    const int p = w & 3, half = w >> 2;
    const int hi = lane >> 5, q31 = lane & 31;

    const float SC  = 0.1803368801111244f;  // 0.125 * log2(e)
    const float THR = 44.0f;                // ~8 in log2 domain after scaling

    __shared__ __align__(16) char smem[36864];
    float (*Os)[68] = (float (*)[68])smem;
    float* mlm = (float*)(smem + 34816);          // [2][4][32]
    float* mll = (float*)(smem + 34816 + 1024);

    const size_t base = (size_t)b * TDIM * (3 * CDIM);
    const unsigned short* qb = qkv + base + hh * DH;
    const unsigned short* kb = qkv + base + CDIM + hh * DH;
    const unsigned short* vb = qkv + base + 2 * CDIM + hh * DH;

    const int gq = q0 + p * 32 + q31;       // this lane's q row
    const int qmin_w = q0 + p * 32;
    const int qmax_w = qmin_w + 31;

    bf16x8 qf[4];
#pragma unroll
    for (int ks = 0; ks < 4; ++ks)
        qf[ks] = *(const bf16x8*)(qb + (size_t)gq * (3 * CDIM) + ks * 16 + hi * 8);

    const int sr = lane >> 3;
    const int scK = 8 * ((lane & 7) ^ sr);  // pre-swizzled source col (elems)
    const int rV = tid >> 3;                // 0..63 kv row
    const int dblk = (tid & 7) * 8;

    f32x16 oacc[2] = {};
    float m = -1e30f, l = 0.f;
    bf16x8 vreg;

    const int NT = 2 * qy + 2;

    // ---- prologue: stage tile 0 into buffer 0 ----
    {
        short* Ks0 = (short*)smem;
        int rowbase = w * 8;
        async_copy16(kb + (size_t)(rowbase + sr) * (3 * CDIM) + scK, Ks0 + rowbase * 64);
        vreg = *(const bf16x8*)(vb + (size_t)rV * (3 * CDIM) + dblk);
        char* Vt0 = smem + 16384;
#pragma unroll
        for (int j = 0; j < 8; ++j) {
            int d = dblk + j;
            int swz = ((d ^ (d >> 3)) & 7) << 4;
            *(short*)(Vt0 + d * 128 + ((2 * rV) ^ swz)) = vreg[j];
        }
    }
    __syncthreads();

    for (int kt = 0; kt < NT; ++kt) {
        const int c = kt & 1;
        const char* Ksc = smem + c * 8192;
        const char* Vtc = smem + 16384 + c * 8192;
        const bool pre = (kt + 1 < NT);

        if (pre) {
            const int kv1 = (kt + 1) * 64;
            short* Ksn = (short*)(smem + (c ^ 1) * 8192);
            int rowbase = w * 8;
            async_copy16(kb + (size_t)(kv1 + rowbase + sr) * (3 * CDIM) + scK,
                         Ksn + rowbase * 64);
            vreg = *(const bf16x8*)(vb + (size_t)(kv1 + rV) * (3 * CDIM) + dblk);
        }

        const int kvs = kt * 64 + half * 32;
        if (kvs <= qmax_w) {
            f32x16 sacc = {};
            __builtin_amdgcn_s_setprio(1);
#pragma unroll
            for (int ks = 0; ks < 4; ++ks) {
                int row = half * 32 + q31;
                int off = row * 128 + ((32 * ks + 16 * hi) ^ ((row & 7) << 4));
                bf16x8 kf = *(const bf16x8*)(Ksc + off);
                sacc = __builtin_amdgcn_mfma_f32_32x32x16_bf16(kf, qf[ks], sacc, 0, 0, 0);
            }
            __builtin_amdgcn_s_setprio(0);

            float p_[16];
            if (kvs + 31 > qmin_w) {
#pragma unroll
                for (int r = 0; r < 16; ++r) {
                    int kvg = kvs + (r & 3) + 8 * (r >> 2) + 4 * hi;
                    p_[r] = (kvg > gq) ? -1e30f : sacc[r];
                }
            } else {
#pragma unroll
                for (int r = 0; r < 16; ++r) p_[r] = sacc[r];
            }

            float t8[8];
#pragma unroll
            for (int r = 0; r < 8; ++r) t8[r] = fmaxf(p_[r], p_[r + 8]);
#pragma unroll
            for (int r = 0; r < 4; ++r) t8[r] = fmaxf(t8[r], t8[r + 4]);
            float pm = fmaxf(fmaxf(t8[0], t8[1]), fmaxf(t8[2], t8[3]));
            pm = fmaxf(pm, __shfl_xor(pm, 32));

            if (!__all(pm <= m + THR)) {
                float mnew = fmaxf(m, pm);
                float sf = exp2f((m - mnew) * SC);
                m = mnew;
                l *= sf;
                oacc[0] *= sf;
                oacc[1] *= sf;
            }
            float mc = m * SC;
#pragma unroll
            for (int r = 0; r < 16; ++r) p_[r] = exp2f(fmaf(p_[r], SC, -mc));
#pragma unroll
            for (int r = 0; r < 8; ++r) t8[r] = p_[r] + p_[r + 8];
#pragma unroll
            for (int r = 0; r < 4; ++r) t8[r] = t8[r] + t8[r + 4];
            float rsum = (t8[0] + t8[1]) + (t8[2] + t8[3]);
            rsum += __shfl_xor(rsum, 32);
            l += rsum;

            bf16x8 pa[2];
#pragma unroll
            for (int k2 = 0; k2 < 2; ++k2) {
                unsigned int A0 = cvtpk(p_[8 * k2 + 0], p_[8 * k2 + 1]);
                unsigned int A1 = cvtpk(p_[8 * k2 + 2], p_[8 * k2 + 3]);
                unsigned int B0 = cvtpk(p_[8 * k2 + 4], p_[8 * k2 + 5]);
                unsigned int B1 = cvtpk(p_[8 * k2 + 6], p_[8 * k2 + 7]);
                unsigned int sA0 = __shfl_xor((int)A0, 32);
                unsigned int sA1 = __shfl_xor((int)A1, 32);
                unsigned int sB0 = __shfl_xor((int)B0, 32);
                unsigned int sB1 = __shfl_xor((int)B1, 32);
                union { int i[4]; bf16x8 h; } u;
                u.i[0] = hi ? (int)sB0 : (int)A0;
                u.i[1] = hi ? (int)sB1 : (int)A1;
                u.i[2] = hi ? (int)B0 : (int)sA0;
                u.i[3] = hi ? (int)B1 : (int)sA1;
                pa[k2] = u.h;
            }

            __builtin_amdgcn_s_setprio(1);
#pragma unroll
            for (int j2 = 0; j2 < 2; ++j2) {
                int row = 32 * j2 + q31;    // d row
                int swz = ((row ^ (row >> 3)) & 7) << 4;
#pragma unroll
                for (int k2 = 0; k2 < 2; ++k2) {
                    int off = row * 128 + ((64 * half + 32 * k2 + 16 * hi) ^ swz);
                    bf16x8 vf = *(const bf16x8*)(Vtc + off);
                    oacc[j2] = __builtin_amdgcn_mfma_f32_32x32x16_bf16(vf, pa[k2], oacc[j2], 0, 0, 0);
                }
            }
            __builtin_amdgcn_s_setprio(0);
        }

        if (pre) {
            char* Vtn = smem + 16384 + (c ^ 1) * 8192;
#pragma unroll
            for (int j = 0; j < 8; ++j) {
                int d = dblk + j;
                int swz = ((d ^ (d >> 3)) & 7) << 4;
                *(short*)(Vtn + d * 128 + ((2 * rV) ^ swz)) = vreg[j];
            }
        }
        __syncthreads();
    }

    // ---- merge kv-half partials (exact flash merge) ----
    mlm[(half * 4 + p) * 32 + q31] = m;
    mll[(half * 4 + p) * 32 + q31] = l;
    __syncthreads();
    float mo = mlm[((half ^ 1) * 4 + p) * 32 + q31];
    float lo = mll[((half ^ 1) * 4 + p) * 32 + q31];
    float M  = fmaxf(m, mo);
    float sf  = exp2f((m - M) * SC);
    float sfo = exp2f((mo - M) * SC);
    float invl = 1.0f / (l * sf + lo * sfo);

    if (half == 1) {
#pragma unroll
        for (int j2 = 0; j2 < 2; ++j2)
#pragma unroll
            for (int g = 0; g < 4; ++g) {
                float4 v4 = make_float4(oacc[j2][4 * g + 0] * sf, oacc[j2][4 * g + 1] * sf,
                                        oacc[j2][4 * g + 2] * sf, oacc[j2][4 * g + 3] * sf);
                *(float4*)&Os[p * 32 + q31][32 * j2 + 8 * g + 4 * hi] = v4;
            }
    }
    __syncthreads();
    if (half == 0) {
#pragma unroll
        for (int j2 = 0; j2 < 2; ++j2)
#pragma unroll
            for (int g = 0; g < 4; ++g) {
                float4 t = *(const float4*)&Os[p * 32 + q31][32 * j2 + 8 * g + 4 * hi];
                float4 v4;
                v4.x = (oacc[j2][4 * g + 0] * sf + t.x) * invl;
                v4.y = (oacc[j2][4 * g + 1] * sf + t.y) * invl;
                v4.z = (oacc[j2][4 * g + 2] * sf + t.z) * invl;
                v4.w = (oacc[j2][4 * g + 3] * sf + t.w) * invl;
                *(float4*)&Os[p * 32 + q31][32 * j2 + 8 * g + 4 * hi] = v4;
            }
    }
    __syncthreads();

    // ---- coalesced bf16 store: 512 threads x 4 passes over 128 rows ----
    const int r0 = tid >> 4;          // 0..31
    const int c4 = (tid & 15) * 4;
#pragma unroll
    for (int pass = 0; pass < 4; ++pass) {
        int row = pass * 32 + r0;
        float4 v = *(const float4*)&Os[row][c4];
        ushort4 o;
        o.x = f2b(v.x); o.y = f2b(v.y); o.z = f2b(v.z); o.w = f2b(v.w);
        *(ushort4*)(y + (size_t)(b * TDIM + q0 + row) * CDIM + hh * DH + c4) = o;
    }
}

// ---------------- launch ----------------
extern "C" void kernel_launch(void* const* d_in, const int* in_sizes, int n_in,
                              void* d_out, int out_size, void* d_ws, size_t ws_size,
                              hipStream_t stream) {
    const float* x      = (const float*)d_in[0];
    const float* ln1_w  = (const float*)d_in[1];
    const float* ln1_b  = (const float*)d_in[2];
    const float* W_attn = (const float*)d_in[3];
    const float* b_attn = (const float*)d_in[4];
    const float* W_o    = (const float*)d_in[5];
    const float* b_o    = (const float*)d_in[6];
    const float* ln2_w  = (const float*)d_in[7];
    const float* ln2_b  = (const float*)d_in[8];
    const float* W_fc   = (const float*)d_in[9];
    const float* b_fc   = (const float*)d_in[10];
    const float* W_proj = (const float*)d_in[11];
    const float* b_proj = (const float*)d_in[12];
    float* out = (float*)d_out;

    char* ws = (char*)d_ws;
    const size_t MB = 1024 * 1024;
    unsigned short* h_bf    = (unsigned short*)(ws);             // 8 MB  [4096,1024]
    unsigned short* big     = (unsigned short*)(ws + 8 * MB);    // 32 MB qkv / fcact
    unsigned short* Wt_attn = (unsigned short*)(ws + 40 * MB);   // 6 MB  [3072,1024]
    unsigned short* Wt_o    = (unsigned short*)(ws + 46 * MB);   // 2 MB  [1024,1024]
    unsigned short* Wt_fc   = (unsigned short*)(ws + 48 * MB);   // 8 MB  [4096,1024]
    unsigned short* Wt_proj = (unsigned short*)(ws + 56 * MB);   // 8 MB  [1024,4096]
    float* x1 = out;

    // 0. weight transpose + cast (W[K][N] -> Wt[N][K] bf16)
    hipLaunchKernelGGL(transpose_cast, dim3(96, 32),  dim3(256), 0, stream, W_attn, Wt_attn, CDIM, 3 * CDIM);
    hipLaunchKernelGGL(transpose_cast, dim3(32, 32),  dim3(256), 0, stream, W_o,    Wt_o,    CDIM, CDIM);
    hipLaunchKernelGGL(transpose_cast, dim3(128, 32), dim3(256), 0, stream, W_fc,   Wt_fc,   CDIM, 4 * CDIM);
    hipLaunchKernelGGL(transpose_cast, dim3(32, 128), dim3(256), 0, stream, W_proj, Wt_proj, 4 * CDIM, CDIM);

    // 1. h = LN1(x)  (bf16)
    hipLaunchKernelGGL(ln_kernel, dim3(MDIM), dim3(256), 0, stream, x, ln1_w, ln1_b, h_bf);
    // 2. qkv = h @ W_attn + b_attn  -> bf16 [4096, 3072]  (768 blocks)
    hipLaunchKernelGGL((gemm_bf16<0, 128>), dim3(3 * CDIM / 128, MDIM / 128), dim3(256), 0,
                       stream, h_bf, Wt_attn, b_attn, nullptr, big, MDIM, 3 * CDIM, CDIM);
    // 3. y = attention(qkv) -> h_bf (bf16)
    hipLaunchKernelGGL(attn_mfma, dim3(BDIM * HEADS, TDIM / 128), dim3(512), 0, stream,
                       big, h_bf);
    // 4. x1 = x + y @ W_o + b_o  (f32)   BN=64 -> 512 blocks
    hipLaunchKernelGGL((gemm_bf16<1, 64>), dim3(CDIM / 64, MDIM / 128), dim3(256), 0,
                       stream, h_bf, Wt_o, b_o, x, x1, MDIM, CDIM, CDIM);
    // 5. h = LN2(x1) (bf16)
    hipLaunchKernelGGL(ln_kernel, dim3(MDIM), dim3(256), 0, stream, x1, ln2_w, ln2_b, h_bf);
    // 6. fcact = gelu(h @ W_fc + b_fc) -> bf16 [4096, 4096]  (1024 blocks)
    hipLaunchKernelGGL((gemm_bf16<2, 128>), dim3(4 * CDIM / 128, MDIM / 128), dim3(256), 0,
                       stream, h_bf, Wt_fc, b_fc, nullptr, big, MDIM, 4 * CDIM, CDIM);
    // 7. out = x1 + fcact @ W_proj + b_proj (f32)   BN=64 -> 512 blocks
    hipLaunchKernelGGL((gemm_bf16<1, 64>), dim3(CDIM / 64, MDIM / 128), dim3(256), 0,
                       stream, big, Wt_proj, b_proj, x1, out, MDIM, CDIM, 4 * CDIM);
}

// Round 11
// 239.442 us; speedup vs baseline: 1.3417x; 1.0083x over previous
//
#include <hip/hip_runtime.h>
#include <math.h>

// GPT-2 block forward. bf16 MFMA GEMMs (multi-buffered counted-vmcnt pipeline,
// XCD-chunked block swizzle) + bf16 MFMA flash attention (32x32 swapped-QK^T,
// split-KV wave pairs, dbuf K/V). B=2, T=2048, C=1024, H=16, Dh=64. M = B*T = 4096.
constexpr int TDIM = 2048;
constexpr int BDIM = 2;
constexpr int CDIM = 1024;
constexpr int HEADS = 16;
constexpr int DH = 64;
constexpr int MDIM = BDIM * TDIM; // 4096

typedef short bf16x8 __attribute__((ext_vector_type(8)));
typedef float f32x4 __attribute__((ext_vector_type(4)));
typedef float f32x16 __attribute__((ext_vector_type(16)));

__device__ __forceinline__ float b2f(unsigned short u) {
    union { float f; unsigned int i; } v; v.i = ((unsigned int)u) << 16; return v.f;
}
__device__ __forceinline__ unsigned short f2b(float f) {
    union { float f; unsigned int i; } v; v.f = f;
    unsigned int r = (v.i + 0x7FFFu + ((v.i >> 16) & 1u)) >> 16;
    return (unsigned short)r;
}
// HW packed f32x2 -> bf16x2 (RNE), single instruction; no builtin on gfx950.
__device__ __forceinline__ unsigned int cvtpk(float lo, float hi) {
    unsigned int r;
    asm("v_cvt_pk_bf16_f32 %0, %1, %2" : "=v"(r) : "v"(lo), "v"(hi));
    return r;
}
// gelu(x) = x * sigmoid(2*c0*(x + 0.044715 x^3)); one HW exp2 instead of tanhf libcall.
__device__ __forceinline__ float gelu_f(float x) {
    float z = -2.3022077f * (x + 0.044715f * x * x * x);
    return x / (1.0f + exp2f(z));
}
__device__ __forceinline__ void async_copy16(const void* g, void* l) {
    __builtin_amdgcn_global_load_lds(
        (const __attribute__((address_space(1))) unsigned int*)g,
        (__attribute__((address_space(3))) unsigned int*)l, 16, 0, 0);
}

// ---------------- weight transpose + cast: W[K][N] f32 -> Wt[N][K] bf16 ----------------
__global__ __launch_bounds__(256) void transpose_cast(
    const float* __restrict__ W, unsigned short* __restrict__ Wt, int K, int N) {
    __shared__ float tile[32][33];
    int n0 = blockIdx.x * 32, k0 = blockIdx.y * 32;
    int tx = threadIdx.x & 31, ty = threadIdx.x >> 5; // 32 x 8
#pragma unroll
    for (int i = 0; i < 32; i += 8)
        tile[ty + i][tx] = W[(size_t)(k0 + ty + i) * N + n0 + tx];
    __syncthreads();
#pragma unroll
    for (int i = 0; i < 32; i += 8)
        Wt[(size_t)(n0 + ty + i) * K + k0 + tx] = f2b(tile[tx][ty + i]);
}

// ---------------- LayerNorm: f32 in -> bf16 out, one block per row of 1024 ----------------
__global__ __launch_bounds__(256) void ln_kernel(
    const float* __restrict__ x, const float* __restrict__ w,
    const float* __restrict__ b, unsigned short* __restrict__ out) {
    int row = blockIdx.x;
    int tid = threadIdx.x;
    const float* xr = x + (size_t)row * CDIM;
    float4 v = *(const float4*)(xr + tid * 4);
    float s  = v.x + v.y + v.z + v.w;
    float ss = v.x * v.x + v.y * v.y + v.z * v.z + v.w * v.w;
#pragma unroll
    for (int off = 32; off >= 1; off >>= 1) {
        s  += __shfl_xor(s, off);
        ss += __shfl_xor(ss, off);
    }
    __shared__ float rs[4], rss[4];
    int wave = tid >> 6;
    if ((tid & 63) == 0) { rs[wave] = s; rss[wave] = ss; }
    __syncthreads();
    s  = rs[0] + rs[1] + rs[2] + rs[3];
    ss = rss[0] + rss[1] + rss[2] + rss[3];
    float mean = s * (1.0f / CDIM);
    float var  = ss * (1.0f / CDIM) - mean * mean;
    float rstd = rsqrtf(var + 1e-5f);
    float4 wv = *(const float4*)(w + tid * 4);
    float4 bv = *(const float4*)(b + tid * 4);
    ushort4 o;
    o.x = f2b((v.x - mean) * rstd * wv.x + bv.x);
    o.y = f2b((v.y - mean) * rstd * wv.y + bv.y);
    o.z = f2b((v.z - mean) * rstd * wv.z + bv.z);
    o.w = f2b((v.w - mean) * rstd * wv.w + bv.w);
    *(ushort4*)(out + (size_t)row * CDIM + tid * 4) = o;
}

// ---------------- bf16 MFMA GEMM, NBUF-pipelined + XCD-chunked: C = A @ Wt^T ----------
// 128 x BN tile, BK=64, 256 threads (4 waves, 2x2), wave tile 64 x BN/2.
// XCD swizzle: nbid = (bid&7)*(nwg/8) + bid>>3 (bijective, nwg%8==0).
// NBUF-deep LDS rotation: at iter t issue tile t+NBUF-1's global_load_lds, then
// s_waitcnt vmcnt((NBUF-1)*INF) -> tile t landed, NBUF-1 tiles stay in flight
// (2 iterations of latency hiding at NBUF=3). Raw s_barrier, no vmcnt(0) drain.
// NBUF=2 reduces to the previously verified double-buffer schedule.
template <int MODE, int BN, int NBUF>
__global__ __launch_bounds__(256) void gemm_bf16(
    const unsigned short* __restrict__ A, const unsigned short* __restrict__ Wt,
    const float* __restrict__ bias, const float* __restrict__ res,
    void* __restrict__ Cout, int M, int N, int K) {
    constexpr int JF = BN / 32;                 // B-frags per wave (4 or 2)
    constexpr int INF = 4 + JF;                 // staging insts in flight per wave/tile
    __shared__ __align__(16) short As[NBUF][128 * 64];
    __shared__ __align__(16) short Bs[NBUF][BN * 64];
    const int tid = threadIdx.x;
    const int lane = tid & 63, w = tid >> 6;
    const int wr = w >> 1, wc = w & 1;

    const int nwg = gridDim.x * gridDim.y;
    const int bid = blockIdx.y * gridDim.x + blockIdx.x;
    const int nbid = (bid & 7) * (nwg >> 3) + (bid >> 3);
    const int bx = nbid % gridDim.x;
    const int by = nbid / gridDim.x;
    const int row0 = by * 128, col0 = bx * BN;

    const int sr = lane >> 3;                   // 0..7: row within 8-row group
    const int sc = 8 * ((lane & 7) ^ sr);       // element col, pre-swizzled source
    const unsigned short* gA = A  + (size_t)(row0 + w * 8 + sr) * K + sc;
    const unsigned short* gB = Wt + (size_t)(col0 + w * 8 + sr) * K + sc;

    f32x4 acc[4][JF] = {};
    const int h = lane >> 4;                    // 0..3
    const int r15 = lane & 15;
    const int nt = K >> 6;

    // prologue: stage tiles 0..NBUF-2
#pragma unroll
    for (int pt = 0; pt < NBUF - 1; ++pt) {
        const int kp = pt << 6;
#pragma unroll
        for (int i = 0; i < 4; ++i)
            async_copy16(gA + (size_t)i * 32 * K + kp, &As[pt][(w * 8 + i * 32) * 64]);
#pragma unroll
        for (int i = 0; i < JF; ++i)
            async_copy16(gB + (size_t)i * 32 * K + kp, &Bs[pt][(w * 8 + i * 32) * 64]);
    }

    for (int t = 0; t < nt; ++t) {
        const int cur = t % NBUF;
        const int tp = t + NBUF - 1;            // tile to prefetch this iter
        if (tp < nt) {
            const int bufp = tp % NBUF;
            const int kp = tp << 6;
#pragma unroll
            for (int i = 0; i < 4; ++i)
                async_copy16(gA + (size_t)i * 32 * K + kp, &As[bufp][(w * 8 + i * 32) * 64]);
#pragma unroll
            for (int i = 0; i < JF; ++i)
                async_copy16(gB + (size_t)i * 32 * K + kp, &Bs[bufp][(w * 8 + i * 32) * 64]);
            asm volatile("s_waitcnt vmcnt(%0)" :: "n"((NBUF - 1) * INF) : "memory");
        } else {
            // tail: no new stage; early-wait is correct (only last NBUF-1 iters)
            asm volatile("s_waitcnt vmcnt(0)" ::: "memory");
        }
        __builtin_amdgcn_s_barrier();
        asm volatile("" ::: "memory");

#pragma unroll
        for (int ks = 0; ks < 2; ++ks) {
            bf16x8 af[4], bfr[JF];
#pragma unroll
            for (int i = 0; i < 4; ++i) {
                int ra = wr * 64 + i * 16 + r15;
                int offa = ra * 128 + ((ks * 64 + h * 16) ^ ((ra & 7) << 4));
                af[i] = *(const bf16x8*)((const char*)As[cur] + offa);
            }
#pragma unroll
            for (int j = 0; j < JF; ++j) {
                int rb = wc * (BN / 2) + j * 16 + r15;
                int offb = rb * 128 + ((ks * 64 + h * 16) ^ ((rb & 7) << 4));
                bfr[j] = *(const bf16x8*)((const char*)Bs[cur] + offb);
            }
#pragma unroll
            for (int i = 0; i < 4; ++i)
#pragma unroll
                for (int j = 0; j < JF; ++j)
                    acc[i][j] = __builtin_amdgcn_mfma_f32_16x16x32_bf16(
                        af[i], bfr[j], acc[i][j], 0, 0, 0);
        }
        asm volatile("" ::: "memory");
        __builtin_amdgcn_s_barrier();   // all reads of buf cur done before it is restaged
    }

#pragma unroll
    for (int i = 0; i < 4; ++i) {
#pragma unroll
        for (int j = 0; j < JF; ++j) {
            int c = col0 + wc * (BN / 2) + j * 16 + r15;
            float bv = bias[c];
#pragma unroll
            for (int q = 0; q < 4; ++q) {
                int rr = row0 + wr * 64 + i * 16 + h * 4 + q;
                float v = acc[i][j][q] + bv;
                if (MODE == 2) v = gelu_f(v);
                if (MODE == 1) v += res[(size_t)rr * N + c];
                if (MODE == 1) ((float*)Cout)[(size_t)rr * N + c] = v;
                else ((unsigned short*)Cout)[(size_t)rr * N + c] = f2b(v);
            }
        }
    }
}

// ---------------- MFMA flash attention, split-KV wave pairs ----------------------------
// grid = (B*H, 16), block = 512 (8 waves). qy remap: by<8 ? 15-by : by-8.
// Wave w: q-group p=w&3 (rows q0+32p..+31), kv-half = w>>2. Pair shares staged K/V;
// each keeps private (m,l,O^T) = exact flash pass over its kv subset; merged via LDS.
__global__ __launch_bounds__(512, 4) void attn_mfma(
    const unsigned short* __restrict__ qkv, unsigned short* __restrict__ y) {
    const int bh = blockIdx.x;
    const int b = bh >> 4, hh = bh & 15;
    const int by = blockIdx.y;
    const int qy = (by < 8) ? (15 - by) : (by - 8);
    const int q0 = qy * 128;
    const int tid = threadIdx.x;
    const int lane = tid & 63, w = tid >> 6;
    const int p = w & 3, half = w >> 2;
    const int hi = lane >> 5, q31 = lane & 31;

    const float SC  = 0.1803368801111244f;  // 0.125 * log2(e)
    const float THR = 44.0f;                // ~8 in log2 domain after scaling

    __shared__ __align__(16) char smem[36864];
    float (*Os)[68] = (float (*)[68])smem;
    float* mlm = (float*)(smem + 34816);          // [2][4][32]
    float* mll = (float*)(smem + 34816 + 1024);

    const size_t base = (size_t)b * TDIM * (3 * CDIM);
    const unsigned short* qb = qkv + base + hh * DH;
    const unsigned short* kb = qkv + base + CDIM + hh * DH;
    const unsigned short* vb = qkv + base + 2 * CDIM + hh * DH;

    const int gq = q0 + p * 32 + q31;       // this lane's q row
    const int qmin_w = q0 + p * 32;
    const int qmax_w = qmin_w + 31;

    bf16x8 qf[4];
#pragma unroll
    for (int ks = 0; ks < 4; ++ks)
        qf[ks] = *(const bf16x8*)(qb + (size_t)gq * (3 * CDIM) + ks * 16 + hi * 8);

    const int sr = lane >> 3;
    const int scK = 8 * ((lane & 7) ^ sr);  // pre-swizzled source col (elems)
    const int rV = tid >> 3;                // 0..63 kv row
    const int dblk = (tid & 7) * 8;

    f32x16 oacc[2] = {};
    float m = -1e30f, l = 0.f;
    bf16x8 vreg;

    const int NT = 2 * qy + 2;

    // ---- prologue: stage tile 0 into buffer 0 ----
    {
        short* Ks0 = (short*)smem;
        int rowbase = w * 8;
        async_copy16(kb + (size_t)(rowbase + sr) * (3 * CDIM) + scK, Ks0 + rowbase * 64);
        vreg = *(const bf16x8*)(vb + (size_t)rV * (3 * CDIM) + dblk);
        char* Vt0 = smem + 16384;
#pragma unroll
        for (int j = 0; j < 8; ++j) {
            int d = dblk + j;
            int swz = ((d ^ (d >> 3)) & 7) << 4;
            *(short*)(Vt0 + d * 128 + ((2 * rV) ^ swz)) = vreg[j];
        }
    }
    __syncthreads();

    for (int kt = 0; kt < NT; ++kt) {
        const int c = kt & 1;
        const char* Ksc = smem + c * 8192;
        const char* Vtc = smem + 16384 + c * 8192;
        const bool pre = (kt + 1 < NT);

        if (pre) {
            const int kv1 = (kt + 1) * 64;
            short* Ksn = (short*)(smem + (c ^ 1) * 8192);
            int rowbase = w * 8;
            async_copy16(kb + (size_t)(kv1 + rowbase + sr) * (3 * CDIM) + scK,
                         Ksn + rowbase * 64);
            vreg = *(const bf16x8*)(vb + (size_t)(kv1 + rV) * (3 * CDIM) + dblk);
        }

        const int kvs = kt * 64 + half * 32;
        if (kvs <= qmax_w) {
            f32x16 sacc = {};
            __builtin_amdgcn_s_setprio(1);
#pragma unroll
            for (int ks = 0; ks < 4; ++ks) {
                int row = half * 32 + q31;
                int off = row * 128 + ((32 * ks + 16 * hi) ^ ((row & 7) << 4));
                bf16x8 kf = *(const bf16x8*)(Ksc + off);
                sacc = __builtin_amdgcn_mfma_f32_32x32x16_bf16(kf, qf[ks], sacc, 0, 0, 0);
            }
            __builtin_amdgcn_s_setprio(0);

            float p_[16];
            if (kvs + 31 > qmin_w) {
#pragma unroll
                for (int r = 0; r < 16; ++r) {
                    int kvg = kvs + (r & 3) + 8 * (r >> 2) + 4 * hi;
                    p_[r] = (kvg > gq) ? -1e30f : sacc[r];
                }
            } else {
#pragma unroll
                for (int r = 0; r < 16; ++r) p_[r] = sacc[r];
            }

            float t8[8];
#pragma unroll
            for (int r = 0; r < 8; ++r) t8[r] = fmaxf(p_[r], p_[r + 8]);
#pragma unroll
            for (int r = 0; r < 4; ++r) t8[r] = fmaxf(t8[r], t8[r + 4]);
            float pm = fmaxf(fmaxf(t8[0], t8[1]), fmaxf(t8[2], t8[3]));
            pm = fmaxf(pm, __shfl_xor(pm, 32));

            if (!__all(pm <= m + THR)) {
                float mnew = fmaxf(m, pm);
                float sf = exp2f((m - mnew) * SC);
                m = mnew;
                l *= sf;
                oacc[0] *= sf;
                oacc[1] *= sf;
            }
            float mc = m * SC;
#pragma unroll
            for (int r = 0; r < 16; ++r) p_[r] = exp2f(fmaf(p_[r], SC, -mc));
#pragma unroll
            for (int r = 0; r < 8; ++r) t8[r] = p_[r] + p_[r + 8];
#pragma unroll
            for (int r = 0; r < 4; ++r) t8[r] = t8[r] + t8[r + 4];
            float rsum = (t8[0] + t8[1]) + (t8[2] + t8[3]);
            rsum += __shfl_xor(rsum, 32);
            l += rsum;

            bf16x8 pa[2];
#pragma unroll
            for (int k2 = 0; k2 < 2; ++k2) {
                unsigned int A0 = cvtpk(p_[8 * k2 + 0], p_[8 * k2 + 1]);
                unsigned int A1 = cvtpk(p_[8 * k2 + 2], p_[8 * k2 + 3]);
                unsigned int B0 = cvtpk(p_[8 * k2 + 4], p_[8 * k2 + 5]);
                unsigned int B1 = cvtpk(p_[8 * k2 + 6], p_[8 * k2 + 7]);
                unsigned int sA0 = __shfl_xor((int)A0, 32);
                unsigned int sA1 = __shfl_xor((int)A1, 32);
                unsigned int sB0 = __shfl_xor((int)B0, 32);
                unsigned int sB1 = __shfl_xor((int)B1, 32);
                union { int i[4]; bf16x8 h; } u;
                u.i[0] = hi ? (int)sB0 : (int)A0;
                u.i[1] = hi ? (int)sB1 : (int)A1;
                u.i[2] = hi ? (int)B0 : (int)sA0;
                u.i[3] = hi ? (int)B1 : (int)sA1;
                pa[k2] = u.h;
            }

            __builtin_amdgcn_s_setprio(1);
#pragma unroll
            for (int j2 = 0; j2 < 2; ++j2) {
                int row = 32 * j2 + q31;    // d row
                int swz = ((row ^ (row >> 3)) & 7) << 4;
#pragma unroll
                for (int k2 = 0; k2 < 2; ++k2) {
                    int off = row * 128 + ((64 * half + 32 * k2 + 16 * hi) ^ swz);
                    bf16x8 vf = *(const bf16x8*)(Vtc + off);
                    oacc[j2] = __builtin_amdgcn_mfma_f32_32x32x16_bf16(vf, pa[k2], oacc[j2], 0, 0, 0);
                }
            }
            __builtin_amdgcn_s_setprio(0);
        }

        if (pre) {
            char* Vtn = smem + 16384 + (c ^ 1) * 8192;
#pragma unroll
            for (int j = 0; j < 8; ++j) {
                int d = dblk + j;
                int swz = ((d ^ (d >> 3)) & 7) << 4;
                *(short*)(Vtn + d * 128 + ((2 * rV) ^ swz)) = vreg[j];
            }
        }
        __syncthreads();
    }

    // ---- merge kv-half partials (exact flash merge) ----
    mlm[(half * 4 + p) * 32 + q31] = m;
    mll[(half * 4 + p) * 32 + q31] = l;
    __syncthreads();
    float mo = mlm[((half ^ 1) * 4 + p) * 32 + q31];
    float lo = mll[((half ^ 1) * 4 + p) * 32 + q31];
    float M  = fmaxf(m, mo);
    float sf  = exp2f((m - M) * SC);
    float sfo = exp2f((mo - M) * SC);
    float invl = 1.0f / (l * sf + lo * sfo);

    if (half == 1) {
#pragma unroll
        for (int j2 = 0; j2 < 2; ++j2)
#pragma unroll
            for (int g = 0; g < 4; ++g) {
                float4 v4 = make_float4(oacc[j2][4 * g + 0] * sf, oacc[j2][4 * g + 1] * sf,
                                        oacc[j2][4 * g + 2] * sf, oacc[j2][4 * g + 3] * sf);
                *(float4*)&Os[p * 32 + q31][32 * j2 + 8 * g + 4 * hi] = v4;
            }
    }
    __syncthreads();
    if (half == 0) {
#pragma unroll
        for (int j2 = 0; j2 < 2; ++j2)
#pragma unroll
            for (int g = 0; g < 4; ++g) {
                float4 t = *(const float4*)&Os[p * 32 + q31][32 * j2 + 8 * g + 4 * hi];
                float4 v4;
                v4.x = (oacc[j2][4 * g + 0] * sf + t.x) * invl;
                v4.y = (oacc[j2][4 * g + 1] * sf + t.y) * invl;
                v4.z = (oacc[j2][4 * g + 2] * sf + t.z) * invl;
                v4.w = (oacc[j2][4 * g + 3] * sf + t.w) * invl;
                *(float4*)&Os[p * 32 + q31][32 * j2 + 8 * g + 4 * hi] = v4;
            }
    }
    __syncthreads();

    // ---- coalesced bf16 store: 512 threads x 4 passes over 128 rows ----
    const int r0 = tid >> 4;          // 0..31
    const int c4 = (tid & 15) * 4;
#pragma unroll
    for (int pass = 0; pass < 4; ++pass) {
        int row = pass * 32 + r0;
        float4 v = *(const float4*)&Os[row][c4];
        ushort4 o;
        o.x = f2b(v.x); o.y = f2b(v.y); o.z = f2b(v.z); o.w = f2b(v.w);
        *(ushort4*)(y + (size_t)(b * TDIM + q0 + row) * CDIM + hh * DH + c4) = o;
    }
}

// ---------------- launch ----------------
extern "C" void kernel_launch(void* const* d_in, const int* in_sizes, int n_in,
                              void* d_out, int out_size, void* d_ws, size_t ws_size,
                              hipStream_t stream) {
    const float* x      = (const float*)d_in[0];
    const float* ln1_w  = (const float*)d_in[1];
    const float* ln1_b  = (const float*)d_in[2];
    const float* W_attn = (const float*)d_in[3];
    const float* b_attn = (const float*)d_in[4];
    const float* W_o    = (const float*)d_in[5];
    const float* b_o    = (const float*)d_in[6];
    const float* ln2_w  = (const float*)d_in[7];
    const float* ln2_b  = (const float*)d_in[8];
    const float* W_fc   = (const float*)d_in[9];
    const float* b_fc   = (const float*)d_in[10];
    const float* W_proj = (const float*)d_in[11];
    const float* b_proj = (const float*)d_in[12];
    float* out = (float*)d_out;

    char* ws = (char*)d_ws;
    const size_t MB = 1024 * 1024;
    unsigned short* h_bf    = (unsigned short*)(ws);             // 8 MB  [4096,1024]
    unsigned short* big     = (unsigned short*)(ws + 8 * MB);    // 32 MB qkv / fcact
    unsigned short* Wt_attn = (unsigned short*)(ws + 40 * MB);   // 6 MB  [3072,1024]
    unsigned short* Wt_o    = (unsigned short*)(ws + 46 * MB);   // 2 MB  [1024,1024]
    unsigned short* Wt_fc   = (unsigned short*)(ws + 48 * MB);   // 8 MB  [4096,1024]
    unsigned short* Wt_proj = (unsigned short*)(ws + 56 * MB);   // 8 MB  [1024,4096]
    float* x1 = out;

    // 0. weight transpose + cast (W[K][N] -> Wt[N][K] bf16)
    hipLaunchKernelGGL(transpose_cast, dim3(96, 32),  dim3(256), 0, stream, W_attn, Wt_attn, CDIM, 3 * CDIM);
    hipLaunchKernelGGL(transpose_cast, dim3(32, 32),  dim3(256), 0, stream, W_o,    Wt_o,    CDIM, CDIM);
    hipLaunchKernelGGL(transpose_cast, dim3(128, 32), dim3(256), 0, stream, W_fc,   Wt_fc,   CDIM, 4 * CDIM);
    hipLaunchKernelGGL(transpose_cast, dim3(32, 128), dim3(256), 0, stream, W_proj, Wt_proj, 4 * CDIM, CDIM);

    // 1. h = LN1(x)  (bf16)
    hipLaunchKernelGGL(ln_kernel, dim3(MDIM), dim3(256), 0, stream, x, ln1_w, ln1_b, h_bf);
    // 2. qkv = h @ W_attn + b_attn  -> bf16 [4096, 3072]  (768 blocks, depth-2)
    hipLaunchKernelGGL((gemm_bf16<0, 128, 2>), dim3(3 * CDIM / 128, MDIM / 128), dim3(256), 0,
                       stream, h_bf, Wt_attn, b_attn, nullptr, big, MDIM, 3 * CDIM, CDIM);
    // 3. y = attention(qkv) -> h_bf (bf16)
    hipLaunchKernelGGL(attn_mfma, dim3(BDIM * HEADS, TDIM / 128), dim3(512), 0, stream,
                       big, h_bf);
    // 4. x1 = x + y @ W_o + b_o  (f32)   BN=64, depth-3
    hipLaunchKernelGGL((gemm_bf16<1, 64, 3>), dim3(CDIM / 64, MDIM / 128), dim3(256), 0,
                       stream, h_bf, Wt_o, b_o, x, x1, MDIM, CDIM, CDIM);
    // 5. h = LN2(x1) (bf16)
    hipLaunchKernelGGL(ln_kernel, dim3(MDIM), dim3(256), 0, stream, x1, ln2_w, ln2_b, h_bf);
    // 6. fcact = gelu(h @ W_fc + b_fc) -> bf16 [4096, 4096]  (1024 blocks, depth-2)
    hipLaunchKernelGGL((gemm_bf16<2, 128, 2>), dim3(4 * CDIM / 128, MDIM / 128), dim3(256), 0,
                       stream, h_bf, Wt_fc, b_fc, nullptr, big, MDIM, 4 * CDIM, CDIM);
    // 7. out = x1 + fcact @ W_proj + b_proj (f32)   BN=64, depth-3
    hipLaunchKernelGGL((gemm_bf16<1, 64, 3>), dim3(CDIM / 64, MDIM / 128), dim3(256), 0,
                       stream, big, Wt_proj, b_proj, x1, out, MDIM, CDIM, 4 * CDIM);
}

// Round 13
// 236.086 us; speedup vs baseline: 1.3607x; 1.0142x over previous
//
#include <hip/hip_runtime.h>
#include <math.h>

// GPT-2 block forward. bf16 MFMA GEMMs: 256x256 8-phase pipelined kernel (fc, qkv) +
// 128xBN 2-phase kernel (Wo, proj); bf16 MFMA flash attention (split-KV wave pairs).
// B=2, T=2048, C=1024, H=16, Dh=64. M = B*T = 4096.
constexpr int TDIM = 2048;
constexpr int BDIM = 2;
constexpr int CDIM = 1024;
constexpr int HEADS = 16;
constexpr int DH = 64;
constexpr int MDIM = BDIM * TDIM; // 4096

typedef short bf16x8 __attribute__((ext_vector_type(8)));
typedef float f32x4 __attribute__((ext_vector_type(4)));
typedef float f32x16 __attribute__((ext_vector_type(16)));

__device__ __forceinline__ float b2f(unsigned short u) {
    union { float f; unsigned int i; } v; v.i = ((unsigned int)u) << 16; return v.f;
}
__device__ __forceinline__ unsigned short f2b(float f) {
    union { float f; unsigned int i; } v; v.f = f;
    unsigned int r = (v.i + 0x7FFFu + ((v.i >> 16) & 1u)) >> 16;
    return (unsigned short)r;
}
__device__ __forceinline__ unsigned int cvtpk(float lo, float hi) {
    unsigned int r;
    asm("v_cvt_pk_bf16_f32 %0, %1, %2" : "=v"(r) : "v"(lo), "v"(hi));
    return r;
}
// gelu(x) = x * sigmoid(2*c0*(x + 0.044715 x^3)); one HW exp2 instead of tanhf libcall.
__device__ __forceinline__ float gelu_f(float x) {
    float z = -2.3022077f * (x + 0.044715f * x * x * x);
    return x / (1.0f + exp2f(z));
}
__device__ __forceinline__ void async_copy16(const void* g, void* l) {
    __builtin_amdgcn_global_load_lds(
        (const __attribute__((address_space(1))) unsigned int*)g,
        (__attribute__((address_space(3))) unsigned int*)l, 16, 0, 0);
}

#define PBAR do { asm volatile("" ::: "memory"); __builtin_amdgcn_s_barrier(); \
                  asm volatile("" ::: "memory"); } while (0)
#define LGKM0 asm volatile("s_waitcnt lgkmcnt(0)" ::: "memory")

// ---------------- weight transpose + cast: W[K][N] f32 -> Wt[N][K] bf16 ----------------
__global__ __launch_bounds__(256) void transpose_cast(
    const float* __restrict__ W, unsigned short* __restrict__ Wt, int K, int N) {
    __shared__ float tile[32][33];
    int n0 = blockIdx.x * 32, k0 = blockIdx.y * 32;
    int tx = threadIdx.x & 31, ty = threadIdx.x >> 5; // 32 x 8
#pragma unroll
    for (int i = 0; i < 32; i += 8)
        tile[ty + i][tx] = W[(size_t)(k0 + ty + i) * N + n0 + tx];
    __syncthreads();
#pragma unroll
    for (int i = 0; i < 32; i += 8)
        Wt[(size_t)(n0 + ty + i) * K + k0 + tx] = f2b(tile[tx][ty + i]);
}

// ---------------- LayerNorm: f32 in -> bf16 out, one block per row of 1024 ----------------
__global__ __launch_bounds__(256) void ln_kernel(
    const float* __restrict__ x, const float* __restrict__ w,
    const float* __restrict__ b, unsigned short* __restrict__ out) {
    int row = blockIdx.x;
    int tid = threadIdx.x;
    const float* xr = x + (size_t)row * CDIM;
    float4 v = *(const float4*)(xr + tid * 4);
    float s  = v.x + v.y + v.z + v.w;
    float ss = v.x * v.x + v.y * v.y + v.z * v.z + v.w * v.w;
#pragma unroll
    for (int off = 32; off >= 1; off >>= 1) {
        s  += __shfl_xor(s, off);
        ss += __shfl_xor(ss, off);
    }
    __shared__ float rs[4], rss[4];
    int wave = tid >> 6;
    if ((tid & 63) == 0) { rs[wave] = s; rss[wave] = ss; }
    __syncthreads();
    s  = rs[0] + rs[1] + rs[2] + rs[3];
    ss = rss[0] + rss[1] + rss[2] + rss[3];
    float mean = s * (1.0f / CDIM);
    float var  = ss * (1.0f / CDIM) - mean * mean;
    float rstd = rsqrtf(var + 1e-5f);
    float4 wv = *(const float4*)(w + tid * 4);
    float4 bv = *(const float4*)(b + tid * 4);
    ushort4 o;
    o.x = f2b((v.x - mean) * rstd * wv.x + bv.x);
    o.y = f2b((v.y - mean) * rstd * wv.y + bv.y);
    o.z = f2b((v.z - mean) * rstd * wv.z + bv.z);
    o.w = f2b((v.w - mean) * rstd * wv.w + bv.w);
    *(ushort4*)(out + (size_t)row * CDIM + tid * 4) = o;
}

// ---------------- 256x256 8-phase bf16 GEMM (T3+T4): C = A[M,K] @ Wt[N,K]^T ----------
// 512 threads (8 waves, 2M x 4N), BK=64, 2 K-tiles per iter (even->slot0, odd->slot1).
// Read phases: As[0]@{ph0,ph2} Bs[0]@{ph0,ph1} As[1]@{ph4,ph6} Bs[1]@{ph4,ph5}.
// Overwrite-after-last-read constraints (stage-half h = 128 rows spans BOTH read
// phases of its slot): As[0]>=ph3, Bs[0]>=ph2, As[1]>=ph7 (or next ph0), Bs[1]>=ph6.
// Stage placement: ph0: A_b_h1 | ph2: B_a'_h0 | ph3: B_a'_h1 + A_a'_h0 | ph4: A_a'_h1
// | ph6: B_b'_h0 | ph7: B_b'_h1 + A_b'_h0.  vmcnt(6) at ph3/ph7: queue<=14, oldest 8
// (tiles needed next read-phase) forced landed; never 0 mid-loop; 0 on last iter.
template <int MODE>
__global__ __launch_bounds__(512, 2) void gemm256(
    const unsigned short* __restrict__ A, const unsigned short* __restrict__ Wt,
    const float* __restrict__ bias, void* __restrict__ Cout, int M, int N, int K) {
    __shared__ __align__(16) short As[2][256 * 64];
    __shared__ __align__(16) short Bs[2][256 * 64];
    const int tid = threadIdx.x;
    const int lane = tid & 63, w = tid >> 6;
    const int wm = w >> 2, wn = w & 3;
    const int h = lane >> 4, r15 = lane & 15;
    const int sr = lane >> 3;
    const int sc = 8 * ((lane & 7) ^ sr);       // pre-swizzled source col (elems)

    const int nwg = gridDim.x * gridDim.y;
    const int bid = blockIdx.y * gridDim.x + blockIdx.x;
    const int nbid = (bid & 7) * (nwg >> 3) + (bid >> 3);
    const int bx = nbid % gridDim.x;
    const int by = nbid / gridDim.x;
    const int row0 = by * 256, col0 = bx * 256;

    const unsigned short* gA = A  + (size_t)(row0 + w * 8 + sr) * K + sc;
    const unsigned short* gB = Wt + (size_t)(col0 + w * 8 + sr) * K + sc;

    f32x4 acc[8][4] = {};
    bf16x8 aA[4][2], bB[4][2];

    // stage half hh (128 rows) of K-tile kt into slot kt&1 (2 insts/wave)
    auto stA = [&](int kt, int hh) {
        short* dst = &As[kt & 1][(hh * 128 + w * 8) * 64];
        const unsigned short* src = gA + (size_t)(hh * 128) * K + (size_t)kt * 64;
        async_copy16(src, dst);
        async_copy16(src + (size_t)64 * K, dst + 64 * 64);
    };
    auto stB = [&](int kt, int hh) {
        short* dst = &Bs[kt & 1][(hh * 128 + w * 8) * 64];
        const unsigned short* src = gB + (size_t)(hh * 128) * K + (size_t)kt * 64;
        async_copy16(src, dst);
        async_copy16(src + (size_t)64 * K, dst + 64 * 64);
    };
    auto rdA = [&](const short* S, int rh) {
#pragma unroll
        for (int ii = 0; ii < 4; ++ii)
#pragma unroll
            for (int ks = 0; ks < 2; ++ks) {
                int ra = wm * 128 + rh * 64 + ii * 16 + r15;
                int off = ra * 128 + ((ks * 64 + h * 16) ^ ((ra & 7) << 4));
                aA[ii][ks] = *(const bf16x8*)((const char*)S + off);
            }
    };
    auto rdB = [&](const short* S, int J0) {
#pragma unroll
        for (int dj = 0; dj < 2; ++dj)
#pragma unroll
            for (int ks = 0; ks < 2; ++ks) {
                int rb = wn * 64 + (J0 + dj) * 16 + r15;
                int off = rb * 128 + ((ks * 64 + h * 16) ^ ((rb & 7) << 4));
                bB[J0 + dj][ks] = *(const bf16x8*)((const char*)S + off);
            }
    };
    auto mm = [&](int rh, int ch) {
        __builtin_amdgcn_s_setprio(1);
#pragma unroll
        for (int ii = 0; ii < 4; ++ii)
#pragma unroll
            for (int jj = 0; jj < 2; ++jj)
#pragma unroll
                for (int ks = 0; ks < 2; ++ks)
                    acc[rh * 4 + ii][ch * 2 + jj] = __builtin_amdgcn_mfma_f32_16x16x32_bf16(
                        aA[ii][ks], bB[ch * 2 + jj][ks], acc[rh * 4 + ii][ch * 2 + jj], 0, 0, 0);
        __builtin_amdgcn_s_setprio(0);
    };

    const int niter = K >> 7;                   // 2 K-tiles per iter

    // prologue: tile0 all halves first (vmcnt(6) covers them), then tile1 minus A_h1
    stA(0, 0); stB(0, 0); stB(0, 1); stA(0, 1);
    stA(1, 0); stB(1, 0); stB(1, 1);
    asm volatile("s_waitcnt vmcnt(6)" ::: "memory");
    PBAR;

    for (int t = 0; t < niter; ++t) {
        const bool st = (t + 1 < niter);
        const int t2 = 2 * t + 2, t3 = 2 * t + 3;
        // ---- K-tile 2t (slot 0) ----
        // ph0: A_b_h1 (tile 2t+1, read at ph6; As[1] free since prev ph6)
        rdA(As[0], 0); rdB(Bs[0], 0);
        stA(2 * t + 1, 1);
        PBAR; LGKM0; mm(0, 0); PBAR;
        // ph1: no stage (As[0] still read at ph2; Bs[0] still read here)
        rdB(Bs[0], 2);
        PBAR; LGKM0; mm(0, 1); PBAR;
        // ph2: B_a'_h0 (Bs[0] last read was ph1)
        rdA(As[0], 1);
        if (st) stB(t2, 0);
        PBAR; LGKM0; mm(1, 0); PBAR;
        // ph3: B_a'_h1 + A_a'_h0 (As[0] last read was ph2) + counted vmcnt
        if (st) {
            stB(t2, 1);
            stA(t2, 0);
            asm volatile("s_waitcnt vmcnt(6)" ::: "memory");
        } else {
            asm volatile("s_waitcnt vmcnt(0)" ::: "memory");
        }
        PBAR; LGKM0; mm(1, 1); PBAR;
        // ---- K-tile 2t+1 (slot 1) ----
        // ph4: A_a'_h1
        rdA(As[1], 0); rdB(Bs[1], 0);
        if (st) stA(t2, 1);
        PBAR; LGKM0; mm(0, 0); PBAR;
        // ph5: no stage (As[1] still read at ph6; Bs[1] still read here)
        rdB(Bs[1], 2);
        PBAR; LGKM0; mm(0, 1); PBAR;
        // ph6: B_b'_h0 (Bs[1] last read was ph5)
        rdA(As[1], 1);
        if (st) stB(t3, 0);
        PBAR; LGKM0; mm(1, 0); PBAR;
        // ph7: B_b'_h1 + A_b'_h0 (As[1] last read was ph6; A_b'_h1 goes at next ph0)
        if (st) {
            stB(t3, 1);
            stA(t3, 0);
            asm volatile("s_waitcnt vmcnt(6)" ::: "memory");
        } else {
            asm volatile("s_waitcnt vmcnt(0)" ::: "memory");
        }
        PBAR; LGKM0; mm(1, 1); PBAR;
    }

    // epilogue
#pragma unroll
    for (int I = 0; I < 8; ++I) {
#pragma unroll
        for (int J = 0; J < 4; ++J) {
            int cc = col0 + wn * 64 + J * 16 + r15;
            float bv = bias[cc];
#pragma unroll
            for (int q = 0; q < 4; ++q) {
                int rr = row0 + wm * 128 + I * 16 + h * 4 + q;
                float v = acc[I][J][q] + bv;
                if (MODE == 2) v = gelu_f(v);
                ((unsigned short*)Cout)[(size_t)rr * N + cc] = f2b(v);
            }
        }
    }
}

// ---------------- 128xBN 2-phase GEMM (Wo, proj): C = A @ Wt^T (+bias,+res) ----------
template <int MODE, int BN, int NBUF>
__global__ __launch_bounds__(256) void gemm_bf16(
    const unsigned short* __restrict__ A, const unsigned short* __restrict__ Wt,
    const float* __restrict__ bias, const float* __restrict__ res,
    void* __restrict__ Cout, int M, int N, int K) {
    constexpr int JF = BN / 32;                 // B-frags per wave (4 or 2)
    constexpr int INF = 4 + JF;                 // staging insts in flight per wave/tile
    __shared__ __align__(16) short As[NBUF][128 * 64];
    __shared__ __align__(16) short Bs[NBUF][BN * 64];
    const int tid = threadIdx.x;
    const int lane = tid & 63, w = tid >> 6;
    const int wr = w >> 1, wc = w & 1;

    const int nwg = gridDim.x * gridDim.y;
    const int bid = blockIdx.y * gridDim.x + blockIdx.x;
    const int nbid = (bid & 7) * (nwg >> 3) + (bid >> 3);
    const int bx = nbid % gridDim.x;
    const int by = nbid / gridDim.x;
    const int row0 = by * 128, col0 = bx * BN;

    const int sr = lane >> 3;                   // 0..7: row within 8-row group
    const int sc = 8 * ((lane & 7) ^ sr);       // element col, pre-swizzled source
    const unsigned short* gA = A  + (size_t)(row0 + w * 8 + sr) * K + sc;
    const unsigned short* gB = Wt + (size_t)(col0 + w * 8 + sr) * K + sc;

    f32x4 acc[4][JF] = {};
    const int h = lane >> 4;                    // 0..3
    const int r15 = lane & 15;
    const int nt = K >> 6;

    // prologue: stage tiles 0..NBUF-2
#pragma unroll
    for (int pt = 0; pt < NBUF - 1; ++pt) {
        const int kp = pt << 6;
#pragma unroll
        for (int i = 0; i < 4; ++i)
            async_copy16(gA + (size_t)i * 32 * K + kp, &As[pt][(w * 8 + i * 32) * 64]);
#pragma unroll
        for (int i = 0; i < JF; ++i)
            async_copy16(gB + (size_t)i * 32 * K + kp, &Bs[pt][(w * 8 + i * 32) * 64]);
    }

    for (int t = 0; t < nt; ++t) {
        const int cur = t % NBUF;
        const int tp = t + NBUF - 1;            // tile to prefetch this iter
        if (tp < nt) {
            const int bufp = tp % NBUF;
            const int kp = tp << 6;
#pragma unroll
            for (int i = 0; i < 4; ++i)
                async_copy16(gA + (size_t)i * 32 * K + kp, &As[bufp][(w * 8 + i * 32) * 64]);
#pragma unroll
            for (int i = 0; i < JF; ++i)
                async_copy16(gB + (size_t)i * 32 * K + kp, &Bs[bufp][(w * 8 + i * 32) * 64]);
            asm volatile("s_waitcnt vmcnt(%0)" :: "n"((NBUF - 1) * INF) : "memory");
        } else {
            asm volatile("s_waitcnt vmcnt(0)" ::: "memory");
        }
        __builtin_amdgcn_s_barrier();
        asm volatile("" ::: "memory");

#pragma unroll
        for (int ks = 0; ks < 2; ++ks) {
            bf16x8 af[4], bfr[JF];
#pragma unroll
            for (int i = 0; i < 4; ++i) {
                int ra = wr * 64 + i * 16 + r15;
                int offa = ra * 128 + ((ks * 64 + h * 16) ^ ((ra & 7) << 4));
                af[i] = *(const bf16x8*)((const char*)As[cur] + offa);
            }
#pragma unroll
            for (int j = 0; j < JF; ++j) {
                int rb = wc * (BN / 2) + j * 16 + r15;
                int offb = rb * 128 + ((ks * 64 + h * 16) ^ ((rb & 7) << 4));
                bfr[j] = *(const bf16x8*)((const char*)Bs[cur] + offb);
            }
#pragma unroll
            for (int i = 0; i < 4; ++i)
#pragma unroll
                for (int j = 0; j < JF; ++j)
                    acc[i][j] = __builtin_amdgcn_mfma_f32_16x16x32_bf16(
                        af[i], bfr[j], acc[i][j], 0, 0, 0);
        }
        asm volatile("" ::: "memory");
        __builtin_amdgcn_s_barrier();   // all reads of buf cur done before it is restaged
    }

#pragma unroll
    for (int i = 0; i < 4; ++i) {
#pragma unroll
        for (int j = 0; j < JF; ++j) {
            int c = col0 + wc * (BN / 2) + j * 16 + r15;
            float bv = bias[c];
#pragma unroll
            for (int q = 0; q < 4; ++q) {
                int rr = row0 + wr * 64 + i * 16 + h * 4 + q;
                float v = acc[i][j][q] + bv;
                if (MODE == 2) v = gelu_f(v);
                if (MODE == 1) v += res[(size_t)rr * N + c];
                if (MODE == 1) ((float*)Cout)[(size_t)rr * N + c] = v;
                else ((unsigned short*)Cout)[(size_t)rr * N + c] = f2b(v);
            }
        }
    }
}

// ---------------- MFMA flash attention, split-KV wave pairs ----------------------------
__global__ __launch_bounds__(512, 4) void attn_mfma(
    const unsigned short* __restrict__ qkv, unsigned short* __restrict__ y) {
    const int bh = blockIdx.x;
    const int b = bh >> 4, hh = bh & 15;
    const int by = blockIdx.y;
    const int qy = (by < 8) ? (15 - by) : (by - 8);
    const int q0 = qy * 128;
    const int tid = threadIdx.x;
    const int lane = tid & 63, w = tid >> 6;
    const int p = w & 3, half = w >> 2;
    const int hi = lane >> 5, q31 = lane & 31;

    const float SC  = 0.1803368801111244f;  // 0.125 * log2(e)
    const float THR = 44.0f;                // ~8 in log2 domain after scaling

    __shared__ __align__(16) char smem[36864];
    float (*Os)[68] = (float (*)[68])smem;
    float* mlm = (float*)(smem + 34816);          // [2][4][32]
    float* mll = (float*)(smem + 34816 + 1024);

    const size_t base = (size_t)b * TDIM * (3 * CDIM);
    const unsigned short* qb = qkv + base + hh * DH;
    const unsigned short* kb = qkv + base + CDIM + hh * DH;
    const unsigned short* vb = qkv + base + 2 * CDIM + hh * DH;

    const int gq = q0 + p * 32 + q31;       // this lane's q row
    const int qmin_w = q0 + p * 32;
    const int qmax_w = qmin_w + 31;

    bf16x8 qf[4];
#pragma unroll
    for (int ks = 0; ks < 4; ++ks)
        qf[ks] = *(const bf16x8*)(qb + (size_t)gq * (3 * CDIM) + ks * 16 + hi * 8);

    const int sr = lane >> 3;
    const int scK = 8 * ((lane & 7) ^ sr);  // pre-swizzled source col (elems)
    const int rV = tid >> 3;                // 0..63 kv row
    const int dblk = (tid & 7) * 8;

    f32x16 oacc[2] = {};
    float m = -1e30f, l = 0.f;
    bf16x8 vreg;

    const int NT = 2 * qy + 2;

    // ---- prologue: stage tile 0 into buffer 0 ----
    {
        short* Ks0 = (short*)smem;
        int rowbase = w * 8;
        async_copy16(kb + (size_t)(rowbase + sr) * (3 * CDIM) + scK, Ks0 + rowbase * 64);
        vreg = *(const bf16x8*)(vb + (size_t)rV * (3 * CDIM) + dblk);
        char* Vt0 = smem + 16384;
#pragma unroll
        for (int j = 0; j < 8; ++j) {
            int d = dblk + j;
            int swz = ((d ^ (d >> 3)) & 7) << 4;
            *(short*)(Vt0 + d * 128 + ((2 * rV) ^ swz)) = vreg[j];
        }
    }
    __syncthreads();

    for (int kt = 0; kt < NT; ++kt) {
        const int c = kt & 1;
        const char* Ksc = smem + c * 8192;
        const char* Vtc = smem + 16384 + c * 8192;
        const bool pre = (kt + 1 < NT);

        if (pre) {
            const int kv1 = (kt + 1) * 64;
            short* Ksn = (short*)(smem + (c ^ 1) * 8192);
            int rowbase = w * 8;
            async_copy16(kb + (size_t)(kv1 + rowbase + sr) * (3 * CDIM) + scK,
                         Ksn + rowbase * 64);
            vreg = *(const bf16x8*)(vb + (size_t)(kv1 + rV) * (3 * CDIM) + dblk);
        }

        const int kvs = kt * 64 + half * 32;
        if (kvs <= qmax_w) {
            f32x16 sacc = {};
            __builtin_amdgcn_s_setprio(1);
#pragma unroll
            for (int ks = 0; ks < 4; ++ks) {
                int row = half * 32 + q31;
                int off = row * 128 + ((32 * ks + 16 * hi) ^ ((row & 7) << 4));
                bf16x8 kf = *(const bf16x8*)(Ksc + off);
                sacc = __builtin_amdgcn_mfma_f32_32x32x16_bf16(kf, qf[ks], sacc, 0, 0, 0);
            }
            __builtin_amdgcn_s_setprio(0);

            float p_[16];
            if (kvs + 31 > qmin_w) {
#pragma unroll
                for (int r = 0; r < 16; ++r) {
                    int kvg = kvs + (r & 3) + 8 * (r >> 2) + 4 * hi;
                    p_[r] = (kvg > gq) ? -1e30f : sacc[r];
                }
            } else {
#pragma unroll
                for (int r = 0; r < 16; ++r) p_[r] = sacc[r];
            }

            float t8[8];
#pragma unroll
            for (int r = 0; r < 8; ++r) t8[r] = fmaxf(p_[r], p_[r + 8]);
#pragma unroll
            for (int r = 0; r < 4; ++r) t8[r] = fmaxf(t8[r], t8[r + 4]);
            float pm = fmaxf(fmaxf(t8[0], t8[1]), fmaxf(t8[2], t8[3]));
            pm = fmaxf(pm, __shfl_xor(pm, 32));

            if (!__all(pm <= m + THR)) {
                float mnew = fmaxf(m, pm);
                float sf = exp2f((m - mnew) * SC);
                m = mnew;
                l *= sf;
                oacc[0] *= sf;
                oacc[1] *= sf;
            }
            float mc = m * SC;
#pragma unroll
            for (int r = 0; r < 16; ++r) p_[r] = exp2f(fmaf(p_[r], SC, -mc));
#pragma unroll
            for (int r = 0; r < 8; ++r) t8[r] = p_[r] + p_[r + 8];
#pragma unroll
            for (int r = 0; r < 4; ++r) t8[r] = t8[r] + t8[r + 4];
            float rsum = (t8[0] + t8[1]) + (t8[2] + t8[3]);
            rsum += __shfl_xor(rsum, 32);
            l += rsum;

            bf16x8 pa[2];
#pragma unroll
            for (int k2 = 0; k2 < 2; ++k2) {
                unsigned int A0 = cvtpk(p_[8 * k2 + 0], p_[8 * k2 + 1]);
                unsigned int A1 = cvtpk(p_[8 * k2 + 2], p_[8 * k2 + 3]);
                unsigned int B0 = cvtpk(p_[8 * k2 + 4], p_[8 * k2 + 5]);
                unsigned int B1 = cvtpk(p_[8 * k2 + 6], p_[8 * k2 + 7]);
                unsigned int sA0 = __shfl_xor((int)A0, 32);
                unsigned int sA1 = __shfl_xor((int)A1, 32);
                unsigned int sB0 = __shfl_xor((int)B0, 32);
                unsigned int sB1 = __shfl_xor((int)B1, 32);
                union { int i[4]; bf16x8 h; } u;
                u.i[0] = hi ? (int)sB0 : (int)A0;
                u.i[1] = hi ? (int)sB1 : (int)A1;
                u.i[2] = hi ? (int)B0 : (int)sA0;
                u.i[3] = hi ? (int)B1 : (int)sA1;
                pa[k2] = u.h;
            }

            __builtin_amdgcn_s_setprio(1);
#pragma unroll
            for (int j2 = 0; j2 < 2; ++j2) {
                int row = 32 * j2 + q31;    // d row
                int swz = ((row ^ (row >> 3)) & 7) << 4;
#pragma unroll
                for (int k2 = 0; k2 < 2; ++k2) {
                    int off = row * 128 + ((64 * half + 32 * k2 + 16 * hi) ^ swz);
                    bf16x8 vf = *(const bf16x8*)(Vtc + off);
                    oacc[j2] = __builtin_amdgcn_mfma_f32_32x32x16_bf16(vf, pa[k2], oacc[j2], 0, 0, 0);
                }
            }
            __builtin_amdgcn_s_setprio(0);
        }

        if (pre) {
            char* Vtn = smem + 16384 + (c ^ 1) * 8192;
#pragma unroll
            for (int j = 0; j < 8; ++j) {
                int d = dblk + j;
                int swz = ((d ^ (d >> 3)) & 7) << 4;
                *(short*)(Vtn + d * 128 + ((2 * rV) ^ swz)) = vreg[j];
            }
        }
        __syncthreads();
    }

    // ---- merge kv-half partials (exact flash merge) ----
    mlm[(half * 4 + p) * 32 + q31] = m;
    mll[(half * 4 + p) * 32 + q31] = l;
    __syncthreads();
    float mo = mlm[((half ^ 1) * 4 + p) * 32 + q31];
    float lo = mll[((half ^ 1) * 4 + p) * 32 + q31];
    float M  = fmaxf(m, mo);
    float sf  = exp2f((m - M) * SC);
    float sfo = exp2f((mo - M) * SC);
    float invl = 1.0f / (l * sf + lo * sfo);

    if (half == 1) {
#pragma unroll
        for (int j2 = 0; j2 < 2; ++j2)
#pragma unroll
            for (int g = 0; g < 4; ++g) {
                float4 v4 = make_float4(oacc[j2][4 * g + 0] * sf, oacc[j2][4 * g + 1] * sf,
                                        oacc[j2][4 * g + 2] * sf, oacc[j2][4 * g + 3] * sf);
                *(float4*)&Os[p * 32 + q31][32 * j2 + 8 * g + 4 * hi] = v4;
            }
    }
    __syncthreads();
    if (half == 0) {
#pragma unroll
        for (int j2 = 0; j2 < 2; ++j2)
#pragma unroll
            for (int g = 0; g < 4; ++g) {
                float4 t = *(const float4*)&Os[p * 32 + q31][32 * j2 + 8 * g + 4 * hi];
                float4 v4;
                v4.x = (oacc[j2][4 * g + 0] * sf + t.x) * invl;
                v4.y = (oacc[j2][4 * g + 1] * sf + t.y) * invl;
                v4.z = (oacc[j2][4 * g + 2] * sf + t.z) * invl;
                v4.w = (oacc[j2][4 * g + 3] * sf + t.w) * invl;
                *(float4*)&Os[p * 32 + q31][32 * j2 + 8 * g + 4 * hi] = v4;
            }
    }
    __syncthreads();

    // ---- coalesced bf16 store: 512 threads x 4 passes over 128 rows ----
    const int r0 = tid >> 4;          // 0..31
    const int c4 = (tid & 15) * 4;
#pragma unroll
    for (int pass = 0; pass < 4; ++pass) {
        int row = pass * 32 + r0;
        float4 v = *(const float4*)&Os[row][c4];
        ushort4 o;
        o.x = f2b(v.x); o.y = f2b(v.y); o.z = f2b(v.z); o.w = f2b(v.w);
        *(ushort4*)(y + (size_t)(b * TDIM + q0 + row) * CDIM + hh * DH + c4) = o;
    }
}

// ---------------- launch ----------------
extern "C" void kernel_launch(void* const* d_in, const int* in_sizes, int n_in,
                              void* d_out, int out_size, void* d_ws, size_t ws_size,
                              hipStream_t stream) {
    const float* x      = (const float*)d_in[0];
    const float* ln1_w  = (const float*)d_in[1];
    const float* ln1_b  = (const float*)d_in[2];
    const float* W_attn = (const float*)d_in[3];
    const float* b_attn = (const float*)d_in[4];
    const float* W_o    = (const float*)d_in[5];
    const float* b_o    = (const float*)d_in[6];
    const float* ln2_w  = (const float*)d_in[7];
    const float* ln2_b  = (const float*)d_in[8];
    const float* W_fc   = (const float*)d_in[9];
    const float* b_fc   = (const float*)d_in[10];
    const float* W_proj = (const float*)d_in[11];
    const float* b_proj = (const float*)d_in[12];
    float* out = (float*)d_out;

    char* ws = (char*)d_ws;
    const size_t MB = 1024 * 1024;
    unsigned short* h_bf    = (unsigned short*)(ws);             // 8 MB  [4096,1024]
    unsigned short* big     = (unsigned short*)(ws + 8 * MB);    // 32 MB qkv / fcact
    unsigned short* Wt_attn = (unsigned short*)(ws + 40 * MB);   // 6 MB  [3072,1024]
    unsigned short* Wt_o    = (unsigned short*)(ws + 46 * MB);   // 2 MB  [1024,1024]
    unsigned short* Wt_fc   = (unsigned short*)(ws + 48 * MB);   // 8 MB  [4096,1024]
    unsigned short* Wt_proj = (unsigned short*)(ws + 56 * MB);   // 8 MB  [1024,4096]
    float* x1 = out;

    // 0. weight transpose + cast (W[K][N] -> Wt[N][K] bf16)
    hipLaunchKernelGGL(transpose_cast, dim3(96, 32),  dim3(256), 0, stream, W_attn, Wt_attn, CDIM, 3 * CDIM);
    hipLaunchKernelGGL(transpose_cast, dim3(32, 32),  dim3(256), 0, stream, W_o,    Wt_o,    CDIM, CDIM);
    hipLaunchKernelGGL(transpose_cast, dim3(128, 32), dim3(256), 0, stream, W_fc,   Wt_fc,   CDIM, 4 * CDIM);
    hipLaunchKernelGGL(transpose_cast, dim3(32, 128), dim3(256), 0, stream, W_proj, Wt_proj, 4 * CDIM, CDIM);

    // 1. h = LN1(x)  (bf16)
    hipLaunchKernelGGL(ln_kernel, dim3(MDIM), dim3(256), 0, stream, x, ln1_w, ln1_b, h_bf);
    // 2. qkv = h @ W_attn + b_attn  -> bf16 [4096, 3072]  (8-phase 256², 192 blocks)
    hipLaunchKernelGGL((gemm256<0>), dim3(3 * CDIM / 256, MDIM / 256), dim3(512), 0,
                       stream, h_bf, Wt_attn, b_attn, big, MDIM, 3 * CDIM, CDIM);
    // 3. y = attention(qkv) -> h_bf (bf16)
    hipLaunchKernelGGL(attn_mfma, dim3(BDIM * HEADS, TDIM / 128), dim3(512), 0, stream,
                       big, h_bf);
    // 4. x1 = x + y @ W_o + b_o  (f32)   BN=64, depth-3
    hipLaunchKernelGGL((gemm_bf16<1, 64, 3>), dim3(CDIM / 64, MDIM / 128), dim3(256), 0,
                       stream, h_bf, Wt_o, b_o, x, x1, MDIM, CDIM, CDIM);
    // 5. h = LN2(x1) (bf16)
    hipLaunchKernelGGL(ln_kernel, dim3(MDIM), dim3(256), 0, stream, x1, ln2_w, ln2_b, h_bf);
    // 6. fcact = gelu(h @ W_fc + b_fc) -> bf16 [4096, 4096]  (8-phase 256², 256 blocks)
    hipLaunchKernelGGL((gemm256<2>), dim3(4 * CDIM / 256, MDIM / 256), dim3(512), 0,
                       stream, h_bf, Wt_fc, b_fc, big, MDIM, 4 * CDIM, CDIM);
    // 7. out = x1 + fcact @ W_proj + b_proj (f32)   BN=64, depth-3
    hipLaunchKernelGGL((gemm_bf16<1, 64, 3>), dim3(CDIM / 64, MDIM / 128), dim3(256), 0,
                       stream, big, Wt_proj, b_proj, x1, out, MDIM, CDIM, 4 * CDIM);
}

// Round 14
// 232.937 us; speedup vs baseline: 1.3791x; 1.0135x over previous
//
#include <hip/hip_runtime.h>
#include <math.h>

// GPT-2 block forward. bf16 MFMA GEMMs: 256x256 8-phase (fc, qkv, split-K proj partials) +
// 128xBN 2-phase (Wo); bf16 MFMA flash attention (split-KV wave pairs); reduce kernel
// for proj. B=2, T=2048, C=1024, H=16, Dh=64. M = B*T = 4096.
constexpr int TDIM = 2048;
constexpr int BDIM = 2;
constexpr int CDIM = 1024;
constexpr int HEADS = 16;
constexpr int DH = 64;
constexpr int MDIM = BDIM * TDIM; // 4096

typedef short bf16x8 __attribute__((ext_vector_type(8)));
typedef float f32x4 __attribute__((ext_vector_type(4)));
typedef float f32x16 __attribute__((ext_vector_type(16)));

__device__ __forceinline__ float b2f(unsigned short u) {
    union { float f; unsigned int i; } v; v.i = ((unsigned int)u) << 16; return v.f;
}
__device__ __forceinline__ unsigned short f2b(float f) {
    union { float f; unsigned int i; } v; v.f = f;
    unsigned int r = (v.i + 0x7FFFu + ((v.i >> 16) & 1u)) >> 16;
    return (unsigned short)r;
}
__device__ __forceinline__ unsigned int cvtpk(float lo, float hi) {
    unsigned int r;
    asm("v_cvt_pk_bf16_f32 %0, %1, %2" : "=v"(r) : "v"(lo), "v"(hi));
    return r;
}
// gelu(x) = x * sigmoid(2*c0*(x + 0.044715 x^3)); one HW exp2 instead of tanhf libcall.
__device__ __forceinline__ float gelu_f(float x) {
    float z = -2.3022077f * (x + 0.044715f * x * x * x);
    return x / (1.0f + exp2f(z));
}
__device__ __forceinline__ void async_copy16(const void* g, void* l) {
    __builtin_amdgcn_global_load_lds(
        (const __attribute__((address_space(1))) unsigned int*)g,
        (__attribute__((address_space(3))) unsigned int*)l, 16, 0, 0);
}

#define PBAR do { asm volatile("" ::: "memory"); __builtin_amdgcn_s_barrier(); \
                  asm volatile("" ::: "memory"); } while (0)
#define LGKM0 asm volatile("s_waitcnt lgkmcnt(0)" ::: "memory")

// ---------------- weight transpose + cast: W[K][N] f32 -> Wt[N][K] bf16 ----------------
__global__ __launch_bounds__(256) void transpose_cast(
    const float* __restrict__ W, unsigned short* __restrict__ Wt, int K, int N) {
    __shared__ float tile[32][33];
    int n0 = blockIdx.x * 32, k0 = blockIdx.y * 32;
    int tx = threadIdx.x & 31, ty = threadIdx.x >> 5; // 32 x 8
#pragma unroll
    for (int i = 0; i < 32; i += 8)
        tile[ty + i][tx] = W[(size_t)(k0 + ty + i) * N + n0 + tx];
    __syncthreads();
#pragma unroll
    for (int i = 0; i < 32; i += 8)
        Wt[(size_t)(n0 + ty + i) * K + k0 + tx] = f2b(tile[tx][ty + i]);
}

// ---------------- LayerNorm: f32 in -> bf16 out, one block per row of 1024 ----------------
__global__ __launch_bounds__(256) void ln_kernel(
    const float* __restrict__ x, const float* __restrict__ w,
    const float* __restrict__ b, unsigned short* __restrict__ out) {
    int row = blockIdx.x;
    int tid = threadIdx.x;
    const float* xr = x + (size_t)row * CDIM;
    float4 v = *(const float4*)(xr + tid * 4);
    float s  = v.x + v.y + v.z + v.w;
    float ss = v.x * v.x + v.y * v.y + v.z * v.z + v.w * v.w;
#pragma unroll
    for (int off = 32; off >= 1; off >>= 1) {
        s  += __shfl_xor(s, off);
        ss += __shfl_xor(ss, off);
    }
    __shared__ float rs[4], rss[4];
    int wave = tid >> 6;
    if ((tid & 63) == 0) { rs[wave] = s; rss[wave] = ss; }
    __syncthreads();
    s  = rs[0] + rs[1] + rs[2] + rs[3];
    ss = rss[0] + rss[1] + rss[2] + rss[3];
    float mean = s * (1.0f / CDIM);
    float var  = ss * (1.0f / CDIM) - mean * mean;
    float rstd = rsqrtf(var + 1e-5f);
    float4 wv = *(const float4*)(w + tid * 4);
    float4 bv = *(const float4*)(b + tid * 4);
    ushort4 o;
    o.x = f2b((v.x - mean) * rstd * wv.x + bv.x);
    o.y = f2b((v.y - mean) * rstd * wv.y + bv.y);
    o.z = f2b((v.z - mean) * rstd * wv.z + bv.z);
    o.w = f2b((v.w - mean) * rstd * wv.w + bv.w);
    *(ushort4*)(out + (size_t)row * CDIM + tid * 4) = o;
}

// ---------------- 256x256 8-phase bf16 GEMM (T3+T4): C = A[M,Kfull] @ Wt[N,Kfull]^T ----
// MODE 0: bias->bf16. MODE 2: bias+gelu->bf16. MODE 3: split-K partial (no bias) ->
// bf16 partial at Cout + blockIdx.z*M*N, K-range [blockIdx.z*Klen, +Klen).
// Schedule verified in round 13 (stage placement honors overwrite-after-last-read;
// vmcnt(6) at ph3/ph7; never drains mid-loop). Only addressing parametrized here.
template <int MODE>
__global__ __launch_bounds__(512, 2) void gemm256(
    const unsigned short* __restrict__ A, const unsigned short* __restrict__ Wt,
    const float* __restrict__ bias, void* __restrict__ Cout, int M, int N,
    int Kfull, int Klen) {
    __shared__ __align__(16) short As[2][256 * 64];
    __shared__ __align__(16) short Bs[2][256 * 64];
    const int tid = threadIdx.x;
    const int lane = tid & 63, w = tid >> 6;
    const int wm = w >> 2, wn = w & 3;
    const int h = lane >> 4, r15 = lane & 15;
    const int sr = lane >> 3;
    const int sc = 8 * ((lane & 7) ^ sr);       // pre-swizzled source col (elems)
    const int k0 = (MODE == 3) ? (int)blockIdx.z * Klen : 0;

    const int nwg = gridDim.x * gridDim.y;
    const int bid = blockIdx.y * gridDim.x + blockIdx.x;
    const int nbid = (bid & 7) * (nwg >> 3) + (bid >> 3);
    const int bx = nbid % gridDim.x;
    const int by = nbid / gridDim.x;
    const int row0 = by * 256, col0 = bx * 256;

    const unsigned short* gA = A  + (size_t)(row0 + w * 8 + sr) * Kfull + k0 + sc;
    const unsigned short* gB = Wt + (size_t)(col0 + w * 8 + sr) * Kfull + k0 + sc;

    f32x4 acc[8][4] = {};
    bf16x8 aA[4][2], bB[4][2];

    auto stA = [&](int kt, int hh) {
        short* dst = &As[kt & 1][(hh * 128 + w * 8) * 64];
        const unsigned short* src = gA + (size_t)(hh * 128) * Kfull + (size_t)kt * 64;
        async_copy16(src, dst);
        async_copy16(src + (size_t)64 * Kfull, dst + 64 * 64);
    };
    auto stB = [&](int kt, int hh) {
        short* dst = &Bs[kt & 1][(hh * 128 + w * 8) * 64];
        const unsigned short* src = gB + (size_t)(hh * 128) * Kfull + (size_t)kt * 64;
        async_copy16(src, dst);
        async_copy16(src + (size_t)64 * Kfull, dst + 64 * 64);
    };
    auto rdA = [&](const short* S, int rh) {
#pragma unroll
        for (int ii = 0; ii < 4; ++ii)
#pragma unroll
            for (int ks = 0; ks < 2; ++ks) {
                int ra = wm * 128 + rh * 64 + ii * 16 + r15;
                int off = ra * 128 + ((ks * 64 + h * 16) ^ ((ra & 7) << 4));
                aA[ii][ks] = *(const bf16x8*)((const char*)S + off);
            }
    };
    auto rdB = [&](const short* S, int J0) {
#pragma unroll
        for (int dj = 0; dj < 2; ++dj)
#pragma unroll
            for (int ks = 0; ks < 2; ++ks) {
                int rb = wn * 64 + (J0 + dj) * 16 + r15;
                int off = rb * 128 + ((ks * 64 + h * 16) ^ ((rb & 7) << 4));
                bB[J0 + dj][ks] = *(const bf16x8*)((const char*)S + off);
            }
    };
    auto mm = [&](int rh, int ch) {
        __builtin_amdgcn_s_setprio(1);
#pragma unroll
        for (int ii = 0; ii < 4; ++ii)
#pragma unroll
            for (int jj = 0; jj < 2; ++jj)
#pragma unroll
                for (int ks = 0; ks < 2; ++ks)
                    acc[rh * 4 + ii][ch * 2 + jj] = __builtin_amdgcn_mfma_f32_16x16x32_bf16(
                        aA[ii][ks], bB[ch * 2 + jj][ks], acc[rh * 4 + ii][ch * 2 + jj], 0, 0, 0);
        __builtin_amdgcn_s_setprio(0);
    };

    const int niter = Klen >> 7;                // 2 K-tiles per iter

    // prologue: tile0 all halves first (vmcnt(6) covers them), then tile1 minus A_h1
    stA(0, 0); stB(0, 0); stB(0, 1); stA(0, 1);
    stA(1, 0); stB(1, 0); stB(1, 1);
    asm volatile("s_waitcnt vmcnt(6)" ::: "memory");
    PBAR;

    for (int t = 0; t < niter; ++t) {
        const bool st = (t + 1 < niter);
        const int t2 = 2 * t + 2, t3 = 2 * t + 3;
        // ---- K-tile 2t (slot 0) ----
        rdA(As[0], 0); rdB(Bs[0], 0);
        stA(2 * t + 1, 1);
        PBAR; LGKM0; mm(0, 0); PBAR;
        rdB(Bs[0], 2);
        PBAR; LGKM0; mm(0, 1); PBAR;
        rdA(As[0], 1);
        if (st) stB(t2, 0);
        PBAR; LGKM0; mm(1, 0); PBAR;
        if (st) {
            stB(t2, 1);
            stA(t2, 0);
            asm volatile("s_waitcnt vmcnt(6)" ::: "memory");
        } else {
            asm volatile("s_waitcnt vmcnt(0)" ::: "memory");
        }
        PBAR; LGKM0; mm(1, 1); PBAR;
        // ---- K-tile 2t+1 (slot 1) ----
        rdA(As[1], 0); rdB(Bs[1], 0);
        if (st) stA(t2, 1);
        PBAR; LGKM0; mm(0, 0); PBAR;
        rdB(Bs[1], 2);
        PBAR; LGKM0; mm(0, 1); PBAR;
        rdA(As[1], 1);
        if (st) stB(t3, 0);
        PBAR; LGKM0; mm(1, 0); PBAR;
        if (st) {
            stB(t3, 1);
            stA(t3, 0);
            asm volatile("s_waitcnt vmcnt(6)" ::: "memory");
        } else {
            asm volatile("s_waitcnt vmcnt(0)" ::: "memory");
        }
        PBAR; LGKM0; mm(1, 1); PBAR;
    }

    // epilogue
    unsigned short* Cp = (unsigned short*)Cout;
    if (MODE == 3) Cp += (size_t)blockIdx.z * M * N;
#pragma unroll
    for (int I = 0; I < 8; ++I) {
#pragma unroll
        for (int J = 0; J < 4; ++J) {
            int cc = col0 + wn * 64 + J * 16 + r15;
            float bv = (MODE == 3) ? 0.0f : bias[cc];
#pragma unroll
            for (int q = 0; q < 4; ++q) {
                int rr = row0 + wm * 128 + I * 16 + h * 4 + q;
                float v = acc[I][J][q] + bv;
                if (MODE == 2) v = gelu_f(v);
                Cp[(size_t)rr * N + cc] = f2b(v);
            }
        }
    }
}

// ---------------- split-K reduce: out = sum_s P_s + bias + res (f32) ----------------
__global__ __launch_bounds__(256) void reduce4(
    const unsigned short* __restrict__ P, const float* __restrict__ bias,
    const float* __restrict__ res, float* __restrict__ out) {
    const size_t eb = ((size_t)blockIdx.x * 256 + threadIdx.x) * 4; // elem base
    const int n = (int)(eb & (CDIM - 1));
    float4 a = make_float4(0.f, 0.f, 0.f, 0.f);
    const size_t stride = (size_t)MDIM * CDIM;
#pragma unroll
    for (int s = 0; s < 4; ++s) {
        ushort4 p = *(const ushort4*)(P + s * stride + eb);
        a.x += b2f(p.x); a.y += b2f(p.y); a.z += b2f(p.z); a.w += b2f(p.w);
    }
    float4 bv = *(const float4*)(bias + n);
    float4 rv = *(const float4*)(res + eb);
    a.x += bv.x + rv.x; a.y += bv.y + rv.y;
    a.z += bv.z + rv.z; a.w += bv.w + rv.w;
    *(float4*)(out + eb) = a;
}

// ---------------- 128xBN 2-phase GEMM (Wo): C = A @ Wt^T (+bias,+res) ----------------
template <int MODE, int BN, int NBUF>
__global__ __launch_bounds__(256) void gemm_bf16(
    const unsigned short* __restrict__ A, const unsigned short* __restrict__ Wt,
    const float* __restrict__ bias, const float* __restrict__ res,
    void* __restrict__ Cout, int M, int N, int K) {
    constexpr int JF = BN / 32;
    constexpr int INF = 4 + JF;
    __shared__ __align__(16) short As[NBUF][128 * 64];
    __shared__ __align__(16) short Bs[NBUF][BN * 64];
    const int tid = threadIdx.x;
    const int lane = tid & 63, w = tid >> 6;
    const int wr = w >> 1, wc = w & 1;

    const int nwg = gridDim.x * gridDim.y;
    const int bid = blockIdx.y * gridDim.x + blockIdx.x;
    const int nbid = (bid & 7) * (nwg >> 3) + (bid >> 3);
    const int bx = nbid % gridDim.x;
    const int by = nbid / gridDim.x;
    const int row0 = by * 128, col0 = bx * BN;

    const int sr = lane >> 3;
    const int sc = 8 * ((lane & 7) ^ sr);
    const unsigned short* gA = A  + (size_t)(row0 + w * 8 + sr) * K + sc;
    const unsigned short* gB = Wt + (size_t)(col0 + w * 8 + sr) * K + sc;

    f32x4 acc[4][JF] = {};
    const int h = lane >> 4;
    const int r15 = lane & 15;
    const int nt = K >> 6;

#pragma unroll
    for (int pt = 0; pt < NBUF - 1; ++pt) {
        const int kp = pt << 6;
#pragma unroll
        for (int i = 0; i < 4; ++i)
            async_copy16(gA + (size_t)i * 32 * K + kp, &As[pt][(w * 8 + i * 32) * 64]);
#pragma unroll
        for (int i = 0; i < JF; ++i)
            async_copy16(gB + (size_t)i * 32 * K + kp, &Bs[pt][(w * 8 + i * 32) * 64]);
    }

    for (int t = 0; t < nt; ++t) {
        const int cur = t % NBUF;
        const int tp = t + NBUF - 1;
        if (tp < nt) {
            const int bufp = tp % NBUF;
            const int kp = tp << 6;
#pragma unroll
            for (int i = 0; i < 4; ++i)
                async_copy16(gA + (size_t)i * 32 * K + kp, &As[bufp][(w * 8 + i * 32) * 64]);
#pragma unroll
            for (int i = 0; i < JF; ++i)
                async_copy16(gB + (size_t)i * 32 * K + kp, &Bs[bufp][(w * 8 + i * 32) * 64]);
            asm volatile("s_waitcnt vmcnt(%0)" :: "n"((NBUF - 1) * INF) : "memory");
        } else {
            asm volatile("s_waitcnt vmcnt(0)" ::: "memory");
        }
        __builtin_amdgcn_s_barrier();
        asm volatile("" ::: "memory");

#pragma unroll
        for (int ks = 0; ks < 2; ++ks) {
            bf16x8 af[4], bfr[JF];
#pragma unroll
            for (int i = 0; i < 4; ++i) {
                int ra = wr * 64 + i * 16 + r15;
                int offa = ra * 128 + ((ks * 64 + h * 16) ^ ((ra & 7) << 4));
                af[i] = *(const bf16x8*)((const char*)As[cur] + offa);
            }
#pragma unroll
            for (int j = 0; j < JF; ++j) {
                int rb = wc * (BN / 2) + j * 16 + r15;
                int offb = rb * 128 + ((ks * 64 + h * 16) ^ ((rb & 7) << 4));
                bfr[j] = *(const bf16x8*)((const char*)Bs[cur] + offb);
            }
#pragma unroll
            for (int i = 0; i < 4; ++i)
#pragma unroll
                for (int j = 0; j < JF; ++j)
                    acc[i][j] = __builtin_amdgcn_mfma_f32_16x16x32_bf16(
                        af[i], bfr[j], acc[i][j], 0, 0, 0);
        }
        asm volatile("" ::: "memory");
        __builtin_amdgcn_s_barrier();
    }

#pragma unroll
    for (int i = 0; i < 4; ++i) {
#pragma unroll
        for (int j = 0; j < JF; ++j) {
            int c = col0 + wc * (BN / 2) + j * 16 + r15;
            float bv = bias[c];
#pragma unroll
            for (int q = 0; q < 4; ++q) {
                int rr = row0 + wr * 64 + i * 16 + h * 4 + q;
                float v = acc[i][j][q] + bv;
                if (MODE == 2) v = gelu_f(v);
                if (MODE == 1) v += res[(size_t)rr * N + c];
                if (MODE == 1) ((float*)Cout)[(size_t)rr * N + c] = v;
                else ((unsigned short*)Cout)[(size_t)rr * N + c] = f2b(v);
            }
        }
    }
}

// ---------------- MFMA flash attention, split-KV wave pairs ----------------------------
__global__ __launch_bounds__(512, 4) void attn_mfma(
    const unsigned short* __restrict__ qkv, unsigned short* __restrict__ y) {
    const int bh = blockIdx.x;
    const int b = bh >> 4, hh = bh & 15;
    const int by = blockIdx.y;
    const int qy = (by < 8) ? (15 - by) : (by - 8);
    const int q0 = qy * 128;
    const int tid = threadIdx.x;
    const int lane = tid & 63, w = tid >> 6;
    const int p = w & 3, half = w >> 2;
    const int hi = lane >> 5, q31 = lane & 31;

    const float SC  = 0.1803368801111244f;
    const float THR = 44.0f;

    __shared__ __align__(16) char smem[36864];
    float (*Os)[68] = (float (*)[68])smem;
    float* mlm = (float*)(smem + 34816);
    float* mll = (float*)(smem + 34816 + 1024);

    const size_t base = (size_t)b * TDIM * (3 * CDIM);
    const unsigned short* qb = qkv + base + hh * DH;
    const unsigned short* kb = qkv + base + CDIM + hh * DH;
    const unsigned short* vb = qkv + base + 2 * CDIM + hh * DH;

    const int gq = q0 + p * 32 + q31;
    const int qmin_w = q0 + p * 32;
    const int qmax_w = qmin_w + 31;

    bf16x8 qf[4];
#pragma unroll
    for (int ks = 0; ks < 4; ++ks)
        qf[ks] = *(const bf16x8*)(qb + (size_t)gq * (3 * CDIM) + ks * 16 + hi * 8);

    const int sr = lane >> 3;
    const int scK = 8 * ((lane & 7) ^ sr);
    const int rV = tid >> 3;
    const int dblk = (tid & 7) * 8;

    f32x16 oacc[2] = {};
    float m = -1e30f, l = 0.f;
    bf16x8 vreg;

    const int NT = 2 * qy + 2;

    {
        short* Ks0 = (short*)smem;
        int rowbase = w * 8;
        async_copy16(kb + (size_t)(rowbase + sr) * (3 * CDIM) + scK, Ks0 + rowbase * 64);
        vreg = *(const bf16x8*)(vb + (size_t)rV * (3 * CDIM) + dblk);
        char* Vt0 = smem + 16384;
#pragma unroll
        for (int j = 0; j < 8; ++j) {
            int d = dblk + j;
            int swz = ((d ^ (d >> 3)) & 7) << 4;
            *(short*)(Vt0 + d * 128 + ((2 * rV) ^ swz)) = vreg[j];
        }
    }
    __syncthreads();

    for (int kt = 0; kt < NT; ++kt) {
        const int c = kt & 1;
        const char* Ksc = smem + c * 8192;
        const char* Vtc = smem + 16384 + c * 8192;
        const bool pre = (kt + 1 < NT);

        if (pre) {
            const int kv1 = (kt + 1) * 64;
            short* Ksn = (short*)(smem + (c ^ 1) * 8192);
            int rowbase = w * 8;
            async_copy16(kb + (size_t)(kv1 + rowbase + sr) * (3 * CDIM) + scK,
                         Ksn + rowbase * 64);
            vreg = *(const bf16x8*)(vb + (size_t)(kv1 + rV) * (3 * CDIM) + dblk);
        }

        const int kvs = kt * 64 + half * 32;
        if (kvs <= qmax_w) {
            f32x16 sacc = {};
            __builtin_amdgcn_s_setprio(1);
#pragma unroll
            for (int ks = 0; ks < 4; ++ks) {
                int row = half * 32 + q31;
                int off = row * 128 + ((32 * ks + 16 * hi) ^ ((row & 7) << 4));
                bf16x8 kf = *(const bf16x8*)(Ksc + off);
                sacc = __builtin_amdgcn_mfma_f32_32x32x16_bf16(kf, qf[ks], sacc, 0, 0, 0);
            }
            __builtin_amdgcn_s_setprio(0);

            float p_[16];
            if (kvs + 31 > qmin_w) {
#pragma unroll
                for (int r = 0; r < 16; ++r) {
                    int kvg = kvs + (r & 3) + 8 * (r >> 2) + 4 * hi;
                    p_[r] = (kvg > gq) ? -1e30f : sacc[r];
                }
            } else {
#pragma unroll
                for (int r = 0; r < 16; ++r) p_[r] = sacc[r];
            }

            float t8[8];
#pragma unroll
            for (int r = 0; r < 8; ++r) t8[r] = fmaxf(p_[r], p_[r + 8]);
#pragma unroll
            for (int r = 0; r < 4; ++r) t8[r] = fmaxf(t8[r], t8[r + 4]);
            float pm = fmaxf(fmaxf(t8[0], t8[1]), fmaxf(t8[2], t8[3]));
            pm = fmaxf(pm, __shfl_xor(pm, 32));

            if (!__all(pm <= m + THR)) {
                float mnew = fmaxf(m, pm);
                float sf = exp2f((m - mnew) * SC);
                m = mnew;
                l *= sf;
                oacc[0] *= sf;
                oacc[1] *= sf;
            }
            float mc = m * SC;
#pragma unroll
            for (int r = 0; r < 16; ++r) p_[r] = exp2f(fmaf(p_[r], SC, -mc));
#pragma unroll
            for (int r = 0; r < 8; ++r) t8[r] = p_[r] + p_[r + 8];
#pragma unroll
            for (int r = 0; r < 4; ++r) t8[r] = t8[r] + t8[r + 4];
            float rsum = (t8[0] + t8[1]) + (t8[2] + t8[3]);
            rsum += __shfl_xor(rsum, 32);
            l += rsum;

            bf16x8 pa[2];
#pragma unroll
            for (int k2 = 0; k2 < 2; ++k2) {
                unsigned int A0 = cvtpk(p_[8 * k2 + 0], p_[8 * k2 + 1]);
                unsigned int A1 = cvtpk(p_[8 * k2 + 2], p_[8 * k2 + 3]);
                unsigned int B0 = cvtpk(p_[8 * k2 + 4], p_[8 * k2 + 5]);
                unsigned int B1 = cvtpk(p_[8 * k2 + 6], p_[8 * k2 + 7]);
                unsigned int sA0 = __shfl_xor((int)A0, 32);
                unsigned int sA1 = __shfl_xor((int)A1, 32);
                unsigned int sB0 = __shfl_xor((int)B0, 32);
                unsigned int sB1 = __shfl_xor((int)B1, 32);
                union { int i[4]; bf16x8 h; } u;
                u.i[0] = hi ? (int)sB0 : (int)A0;
                u.i[1] = hi ? (int)sB1 : (int)A1;
                u.i[2] = hi ? (int)B0 : (int)sA0;
                u.i[3] = hi ? (int)B1 : (int)sA1;
                pa[k2] = u.h;
            }

            __builtin_amdgcn_s_setprio(1);
#pragma unroll
            for (int j2 = 0; j2 < 2; ++j2) {
                int row = 32 * j2 + q31;
                int swz = ((row ^ (row >> 3)) & 7) << 4;
#pragma unroll
                for (int k2 = 0; k2 < 2; ++k2) {
                    int off = row * 128 + ((64 * half + 32 * k2 + 16 * hi) ^ swz);
                    bf16x8 vf = *(const bf16x8*)(Vtc + off);
                    oacc[j2] = __builtin_amdgcn_mfma_f32_32x32x16_bf16(vf, pa[k2], oacc[j2], 0, 0, 0);
                }
            }
            __builtin_amdgcn_s_setprio(0);
        }

        if (pre) {
            char* Vtn = smem + 16384 + (c ^ 1) * 8192;
#pragma unroll
            for (int j = 0; j < 8; ++j) {
                int d = dblk + j;
                int swz = ((d ^ (d >> 3)) & 7) << 4;
                *(short*)(Vtn + d * 128 + ((2 * rV) ^ swz)) = vreg[j];
            }
        }
        __syncthreads();
    }

    mlm[(half * 4 + p) * 32 + q31] = m;
    mll[(half * 4 + p) * 32 + q31] = l;
    __syncthreads();
    float mo = mlm[((half ^ 1) * 4 + p) * 32 + q31];
    float lo = mll[((half ^ 1) * 4 + p) * 32 + q31];
    float M  = fmaxf(m, mo);
    float sf  = exp2f((m - M) * SC);
    float sfo = exp2f((mo - M) * SC);
    float invl = 1.0f / (l * sf + lo * sfo);

    if (half == 1) {
#pragma unroll
        for (int j2 = 0; j2 < 2; ++j2)
#pragma unroll
            for (int g = 0; g < 4; ++g) {
                float4 v4 = make_float4(oacc[j2][4 * g + 0] * sf, oacc[j2][4 * g + 1] * sf,
                                        oacc[j2][4 * g + 2] * sf, oacc[j2][4 * g + 3] * sf);
                *(float4*)&Os[p * 32 + q31][32 * j2 + 8 * g + 4 * hi] = v4;
            }
    }
    __syncthreads();
    if (half == 0) {
#pragma unroll
        for (int j2 = 0; j2 < 2; ++j2)
#pragma unroll
            for (int g = 0; g < 4; ++g) {
                float4 t = *(const float4*)&Os[p * 32 + q31][32 * j2 + 8 * g + 4 * hi];
                float4 v4;
                v4.x = (oacc[j2][4 * g + 0] * sf + t.x) * invl;
                v4.y = (oacc[j2][4 * g + 1] * sf + t.y) * invl;
                v4.z = (oacc[j2][4 * g + 2] * sf + t.z) * invl;
                v4.w = (oacc[j2][4 * g + 3] * sf + t.w) * invl;
                *(float4*)&Os[p * 32 + q31][32 * j2 + 8 * g + 4 * hi] = v4;
            }
    }
    __syncthreads();

    const int r0 = tid >> 4;
    const int c4 = (tid & 15) * 4;
#pragma unroll
    for (int pass = 0; pass < 4; ++pass) {
        int row = pass * 32 + r0;
        float4 v = *(const float4*)&Os[row][c4];
        ushort4 o;
        o.x = f2b(v.x); o.y = f2b(v.y); o.z = f2b(v.z); o.w = f2b(v.w);
        *(ushort4*)(y + (size_t)(b * TDIM + q0 + row) * CDIM + hh * DH + c4) = o;
    }
}

// ---------------- launch ----------------
extern "C" void kernel_launch(void* const* d_in, const int* in_sizes, int n_in,
                              void* d_out, int out_size, void* d_ws, size_t ws_size,
                              hipStream_t stream) {
    const float* x      = (const float*)d_in[0];
    const float* ln1_w  = (const float*)d_in[1];
    const float* ln1_b  = (const float*)d_in[2];
    const float* W_attn = (const float*)d_in[3];
    const float* b_attn = (const float*)d_in[4];
    const float* W_o    = (const float*)d_in[5];
    const float* b_o    = (const float*)d_in[6];
    const float* ln2_w  = (const float*)d_in[7];
    const float* ln2_b  = (const float*)d_in[8];
    const float* W_fc   = (const float*)d_in[9];
    const float* b_fc   = (const float*)d_in[10];
    const float* W_proj = (const float*)d_in[11];
    const float* b_proj = (const float*)d_in[12];
    float* out = (float*)d_out;

    char* ws = (char*)d_ws;
    const size_t MB = 1024 * 1024;
    // Layout (72 MB peak, lifetimes disjoint where overlapped):
    // [0,32)  big: qkv 24 MB (steps 2-3) / fcact 32 MB (steps 6-8)
    // [32,40) Wt_proj (step 0 -> step 8)
    // [40,46) Wt_attn (step 0 -> step 2)   } all dead by step 8,
    // [46,48) Wt_o    (step 0 -> step 4)   } overlapped by proj
    // [48,56) Wt_fc   (step 0 -> step 6)   } partials [40,72)
    // [56,64) h_bf    (steps 1-6)          }
    // [40,72) Ppart: 4x bf16 [4096][1024] proj partials (steps 8-9)
    unsigned short* big     = (unsigned short*)(ws);
    unsigned short* Wt_proj = (unsigned short*)(ws + 32 * MB);
    unsigned short* Wt_attn = (unsigned short*)(ws + 40 * MB);
    unsigned short* Wt_o    = (unsigned short*)(ws + 46 * MB);
    unsigned short* Wt_fc   = (unsigned short*)(ws + 48 * MB);
    unsigned short* h_bf    = (unsigned short*)(ws + 56 * MB);
    unsigned short* Ppart   = (unsigned short*)(ws + 40 * MB);
    float* x1 = out;

    // 0. weight transpose + cast (W[K][N] -> Wt[N][K] bf16)
    hipLaunchKernelGGL(transpose_cast, dim3(96, 32),  dim3(256), 0, stream, W_attn, Wt_attn, CDIM, 3 * CDIM);
    hipLaunchKernelGGL(transpose_cast, dim3(32, 32),  dim3(256), 0, stream, W_o,    Wt_o,    CDIM, CDIM);
    hipLaunchKernelGGL(transpose_cast, dim3(128, 32), dim3(256), 0, stream, W_fc,   Wt_fc,   CDIM, 4 * CDIM);
    hipLaunchKernelGGL(transpose_cast, dim3(32, 128), dim3(256), 0, stream, W_proj, Wt_proj, 4 * CDIM, CDIM);

    // 1. h = LN1(x)  (bf16)
    hipLaunchKernelGGL(ln_kernel, dim3(MDIM), dim3(256), 0, stream, x, ln1_w, ln1_b, h_bf);
    // 2. qkv = h @ W_attn + b_attn  -> bf16 [4096, 3072]  (8-phase 256²)
    hipLaunchKernelGGL((gemm256<0>), dim3(3 * CDIM / 256, MDIM / 256, 1), dim3(512), 0,
                       stream, h_bf, Wt_attn, b_attn, big, MDIM, 3 * CDIM, CDIM, CDIM);
    // 3. y = attention(qkv) -> h_bf (bf16)
    hipLaunchKernelGGL(attn_mfma, dim3(BDIM * HEADS, TDIM / 128), dim3(512), 0, stream,
                       big, h_bf);
    // 4. x1 = x + y @ W_o + b_o  (f32)   BN=64, depth-3
    hipLaunchKernelGGL((gemm_bf16<1, 64, 3>), dim3(CDIM / 64, MDIM / 128), dim3(256), 0,
                       stream, h_bf, Wt_o, b_o, x, x1, MDIM, CDIM, CDIM);
    // 5. h = LN2(x1) (bf16)
    hipLaunchKernelGGL(ln_kernel, dim3(MDIM), dim3(256), 0, stream, x1, ln2_w, ln2_b, h_bf);
    // 6. fcact = gelu(h @ W_fc + b_fc) -> bf16 [4096, 4096]  (8-phase 256²)
    hipLaunchKernelGGL((gemm256<2>), dim3(4 * CDIM / 256, MDIM / 256, 1), dim3(512), 0,
                       stream, h_bf, Wt_fc, b_fc, big, MDIM, 4 * CDIM, CDIM, CDIM);
    // 7. proj partials: P_s = fcact @ W_proj^T over K-chunk s*1024..+1024 (8-phase, 256 blocks)
    hipLaunchKernelGGL((gemm256<3>), dim3(CDIM / 256, MDIM / 256, 4), dim3(512), 0,
                       stream, big, Wt_proj, b_proj, Ppart, MDIM, CDIM, 4 * CDIM, CDIM);
    // 8. out = sum_s P_s + b_proj + x1  (f32)
    hipLaunchKernelGGL(reduce4, dim3(MDIM * CDIM / 4 / 256), dim3(256), 0, stream,
                       Ppart, b_proj, x1, out);
}